// Round 1
// 189.966 us; speedup vs baseline: 1.0205x; 1.0205x over previous
//
#include <hip/hip_runtime.h>
#include <hip/hip_bf16.h>
#include <math.h>

// Problem: B=1, N=1024, D=1024, H=16, C=64, TOPK=2, HD=64, G=16
//
// This version replaces the VALU dot2 attention (44.5us, MfmaUtil=0) with an
// MFMA flash-style attention: one workgroup per (chunk g, head h), 4 waves x
// 16 queries, K/V staged in LDS, 16x16x32 bf16 MFMA for QK^T and PV.
// Inter path: online softmax over the (exactly 2) selected blocks per query,
// iterating only the per-workgroup union of selected blocks. Intra path:
// single causal tile, separate softmax, separate accumulator. Gated blend in
// the epilogue. Epilogue layout changes in qkv_score: Q,K now plain bf16
// [n][D]; V written pre-transposed Vt[f][n] (LDS transpose) so PV B-operand
// stages exactly like GEMM tiles (2-way-free bank pattern).

typedef __attribute__((ext_vector_type(8))) short short8;   // 8 bf16 = 4 VGPRs
typedef __attribute__((ext_vector_type(4))) float f32x4;

#define NTOK 1024
#define DMODEL 1024
#define NHEAD 16
#define HDIM 64
#define CHUNK 64
#define NBLK 16

__device__ __forceinline__ float qmax16(float v)
{
    #pragma unroll
    for (int off = 1; off < 16; off <<= 1) v = fmaxf(v, __shfl_xor(v, off));
    return v;
}

__device__ __forceinline__ float qsum16(float v)
{
    #pragma unroll
    for (int off = 1; off < 16; off <<= 1) v += __shfl_xor(v, off);
    return v;
}

// ---------------------------------------------------------------------------
// A: prep. blockIdx roles: [0,5120) casts (which = bid>>10: 0 x split,
// 1 Wq hi, 2 Wk hi, 3 Wv hi, 4 Wo split), [5120,5184) xm, [5184,6208) gate.
// ---------------------------------------------------------------------------
__global__ __launch_bounds__(256) void prep_kernel(
    const float* __restrict__ x,  const float* __restrict__ Wq,
    const float* __restrict__ Wk, const float* __restrict__ Wv,
    const float* __restrict__ Wo, const float* __restrict__ Wg,
    __hip_bfloat16* __restrict__ xh,  __hip_bfloat16* __restrict__ xl,
    __hip_bfloat16* __restrict__ Wqh,
    __hip_bfloat16* __restrict__ Wkh, __hip_bfloat16* __restrict__ Wvh,
    __hip_bfloat16* __restrict__ Woh, __hip_bfloat16* __restrict__ Wol,
    float* __restrict__ xm, float2* __restrict__ gate)
{
    __shared__ float gs[32];
    const int bid = blockIdx.x;
    if (bid < 5120) {
        const int which = bid >> 10;
        const int b = bid & 1023;
        const int i = (b * 256 + threadIdx.x) * 4;
        const float* in; __hip_bfloat16 *hi, *lo = nullptr;
        if (which == 0)      { in = x;  hi = xh;  lo = xl; }
        else if (which == 1) { in = Wq; hi = Wqh; }
        else if (which == 2) { in = Wk; hi = Wkh; }
        else if (which == 3) { in = Wv; hi = Wvh; }
        else                 { in = Wo; hi = Woh; lo = Wol; }
        float4 v = *(const float4*)(in + i);
        float vv[4] = {v.x, v.y, v.z, v.w};
        __hip_bfloat16 h[4], l[4];
        #pragma unroll
        for (int j = 0; j < 4; j++) {
            h[j] = __float2bfloat16(vv[j]);
            l[j] = __float2bfloat16(vv[j] - __bfloat162float(h[j]));
        }
        *(uint2*)(hi + i) = *(uint2*)h;
        if (lo) *(uint2*)(lo + i) = *(uint2*)l;
    } else if (bid < 5184) {
        const int b = bid - 5120;
        const int g = b >> 2;
        const int f = (b & 3) * 256 + threadIdx.x;
        float s = 0.f;
        #pragma unroll 8
        for (int c = 0; c < CHUNK; c++) s += x[(size_t)(g * CHUNK + c) * DMODEL + f];
        xm[g * DMODEL + f] = s * (1.0f / CHUNK);
    } else {
        const int n = bid - 5184;
        const int wave = threadIdx.x >> 6, lane = threadIdx.x & 63;
        #pragma unroll
        for (int jj = 0; jj < 8; jj++) {
            int j = wave * 8 + jj;
            float s = 0.f;
            #pragma unroll
            for (int t = 0; t < 16; t++) {
                int d = lane + (t << 6);
                s += x[n * DMODEL + d] * Wg[j * DMODEL + d];
            }
            #pragma unroll
            for (int off = 32; off; off >>= 1) s += __shfl_xor(s, off);
            if (lane == 0) gs[j] = s;
        }
        __syncthreads();
        if (threadIdx.x < NHEAD) {
            int h = threadIdx.x;
            float a = gs[2 * h], b = gs[2 * h + 1];
            float m = fmaxf(a, b);
            float ea = expf(a - m), eb = expf(b - m);
            float inv = 1.f / (ea + eb);
            gate[n * NHEAD + h] = make_float2(ea * inv, eb * inv);
        }
    }
}

// ---------------------------------------------------------------------------
// B: kc = xm @ Wk^T (exact f32). One block per f; (g = tid>>4, sub = tid&15).
// ---------------------------------------------------------------------------
__global__ __launch_bounds__(256) void kc_gemm_kernel(
    const float* __restrict__ xm, const float* __restrict__ Wk,
    float* __restrict__ kc)
{
    const int f = blockIdx.x;
    const int g = threadIdx.x >> 4;
    const int sub = threadIdx.x & 15;
    const float* wrow = Wk + (size_t)f * DMODEL;
    float s = 0.f;
    #pragma unroll 16
    for (int i = 0; i < 64; i++) {
        int e = i * 16 + sub;
        s += xm[g * DMODEL + e] * wrow[e];
    }
    #pragma unroll
    for (int off = 8; off; off >>= 1) s += __shfl_xor(s, off);
    if (sub == 0) kc[g * DMODEL + f] = s;
}

// ---------------------------------------------------------------------------
// C: U[(h<<4)|g][f] = sum_d kc[g][h*64+d] * Wq[h*64+d][f]  (exact f32),
// then split to bf16 hi/lo rows Uh/Ul [256][1024].
// ---------------------------------------------------------------------------
__global__ __launch_bounds__(256) void u_kernel(
    const float* __restrict__ kc, const float* __restrict__ Wq,
    __hip_bfloat16* __restrict__ Uh, __hip_bfloat16* __restrict__ Ul)
{
    __shared__ float kcs[64];
    const int h = blockIdx.x >> 4, g = blockIdx.x & 15;
    if (threadIdx.x < 64) kcs[threadIdx.x] = kc[g * DMODEL + h * HDIM + threadIdx.x];
    __syncthreads();
    const int col = (h << 4) | g;
    for (int f = threadIdx.x; f < DMODEL; f += 256) {
        float s = 0.f;
        #pragma unroll 16
        for (int d = 0; d < 64; d++)
            s += kcs[d] * Wq[(size_t)(h * HDIM + d) * DMODEL + f];
        __hip_bfloat16 hv = __float2bfloat16(s);
        Uh[(size_t)col * DMODEL + f] = hv;
        Ul[(size_t)col * DMODEL + f] = __float2bfloat16(s - __bfloat162float(hv));
    }
}

// ---------------------------------------------------------------------------
// D: qkv GEMMs (blocks [0,768), BK=64, plain bf16) + score GEMM (blocks
// [768,832): S[1024][256] = (xh+xl) @ (Uh+Ul)^T, 3-term split, ~1e-5 rel).
// Epilogues: Q,K -> bf16 [n][D]; V -> bf16 transposed Vt[f][n] via LDS.
// ---------------------------------------------------------------------------
__global__ __launch_bounds__(256) void qkv_score_kernel(
    const __hip_bfloat16* __restrict__ xh, const __hip_bfloat16* __restrict__ xl,
    const __hip_bfloat16* __restrict__ Wqh, const __hip_bfloat16* __restrict__ Wkh,
    const __hip_bfloat16* __restrict__ Wvh,
    const __hip_bfloat16* __restrict__ Uh, const __hip_bfloat16* __restrict__ Ul,
    __hip_bfloat16* __restrict__ Qb, __hip_bfloat16* __restrict__ Kb,
    __hip_bfloat16* __restrict__ Vt, float* __restrict__ S)
{
    __shared__ uint4 smem4[36864 / 16];     // 36 KB shared scratch, 16B-aligned
    char* smem = (char*)smem4;
    const int b = blockIdx.x;

    const int tid  = threadIdx.x;
    const int wave = tid >> 6;
    const int lane = tid & 63;
    const int lr = tid >> 2;
    const int lc = (tid & 3) * 16;
    const int wm = (wave >> 1) * 32;
    const int wn = (wave & 1) * 32;
    const int fr = lane & 15;
    const int quad = lane >> 4;

    if (b < 768) {
        // ---- QKV GEMM (plain bf16) ----
        __hip_bfloat16 (*Ash)[72] = (__hip_bfloat16(*)[72])smem;
        __hip_bfloat16 (*Bsh)[72] = (__hip_bfloat16(*)[72])(smem + 9216);

        const int widx = b >> 8;
        const int t = b & 255;
        const __hip_bfloat16* __restrict__ Bh =
            (widx == 0) ? Wqh : (widx == 1) ? Wkh : Wvh;
        const int n0 = (t & 15) * 64;
        const int m0 = (t >> 4) * 64;

        f32x4 acc[2][2] = {};

        for (int k0 = 0; k0 < DMODEL; k0 += 64) {
            const size_t aoff = (size_t)(m0 + lr) * DMODEL + k0 + lc;
            const size_t boff = (size_t)(n0 + lr) * DMODEL + k0 + lc;
            *(uint4*)(&Ash[lr][lc])     = *(const uint4*)(xh + aoff);
            *(uint4*)(&Ash[lr][lc + 8]) = *(const uint4*)(xh + aoff + 8);
            *(uint4*)(&Bsh[lr][lc])     = *(const uint4*)(Bh + boff);
            *(uint4*)(&Bsh[lr][lc + 8]) = *(const uint4*)(Bh + boff + 8);
            __syncthreads();

            #pragma unroll
            for (int hk = 0; hk < 2; hk++) {
                const int kc0 = hk * 32 + quad * 8;
                short8 a0 = *(const short8*)(&Ash[wm + fr][kc0]);
                short8 a1 = *(const short8*)(&Ash[wm + 16 + fr][kc0]);
                short8 b0 = *(const short8*)(&Bsh[wn + fr][kc0]);
                short8 b1 = *(const short8*)(&Bsh[wn + 16 + fr][kc0]);
                acc[0][0] = __builtin_amdgcn_mfma_f32_16x16x32_bf16(a0, b0, acc[0][0], 0, 0, 0);
                acc[0][1] = __builtin_amdgcn_mfma_f32_16x16x32_bf16(a0, b1, acc[0][1], 0, 0, 0);
                acc[1][0] = __builtin_amdgcn_mfma_f32_16x16x32_bf16(a1, b0, acc[1][0], 0, 0, 0);
                acc[1][1] = __builtin_amdgcn_mfma_f32_16x16x32_bf16(a1, b1, acc[1][1], 0, 0, 0);
            }
            __syncthreads();
        }

        if (widx == 0) {
            #pragma unroll
            for (int tm = 0; tm < 2; tm++)
            #pragma unroll
            for (int tn = 0; tn < 2; tn++)
            #pragma unroll
            for (int r = 0; r < 4; r++) {
                int row = m0 + wm + tm * 16 + quad * 4 + r;
                int col = n0 + wn + tn * 16 + fr;
                Qb[(size_t)row * DMODEL + col] = __float2bfloat16(acc[tm][tn][r]);
            }
        } else if (widx == 1) {
            #pragma unroll
            for (int tm = 0; tm < 2; tm++)
            #pragma unroll
            for (int tn = 0; tn < 2; tn++)
            #pragma unroll
            for (int r = 0; r < 4; r++) {
                int row = m0 + wm + tm * 16 + quad * 4 + r;
                int col = n0 + wn + tn * 16 + fr;
                Kb[(size_t)row * DMODEL + col] = __float2bfloat16(acc[tm][tn][r]);
            }
        } else {
            // V: transpose 64x64 tile through LDS, store Vt[f][n] coalesced.
            __hip_bfloat16 (*T)[72] = (__hip_bfloat16(*)[72])smem;
            #pragma unroll
            for (int tm = 0; tm < 2; tm++)
            #pragma unroll
            for (int tn = 0; tn < 2; tn++)
            #pragma unroll
            for (int r = 0; r < 4; r++) {
                int nloc = wm + tm * 16 + quad * 4 + r;
                int floc = wn + tn * 16 + fr;
                T[floc][nloc] = __float2bfloat16(acc[tm][tn][r]);
            }
            __syncthreads();
            const size_t o = (size_t)(n0 + lr) * NTOK + m0 + lc;
            *(uint4*)(Vt + o)     = *(uint4*)(&T[lr][lc]);
            *(uint4*)(Vt + o + 8) = *(uint4*)(&T[lr][lc + 8]);
        }
    } else {
        // ---- score GEMM: S = (xh+xl) @ (Uh+Ul)^T, 3-term split ----
        __hip_bfloat16 (*Ash)[72] = (__hip_bfloat16(*)[72])smem;
        __hip_bfloat16 (*Asl)[72] = (__hip_bfloat16(*)[72])(smem + 9216);
        __hip_bfloat16 (*Bsh)[72] = (__hip_bfloat16(*)[72])(smem + 18432);
        __hip_bfloat16 (*Bsl)[72] = (__hip_bfloat16(*)[72])(smem + 27648);

        const int bb = b - 768;                 // [0,64)
        const int m0 = (bb >> 2) * 64;          // 16 token tiles
        const int n0 = (bb & 3) * 64;           // 4 col tiles (256 cols)

        f32x4 acc[2][2] = {};

        for (int k0 = 0; k0 < DMODEL; k0 += 64) {
            const size_t aoff = (size_t)(m0 + lr) * DMODEL + k0 + lc;
            const size_t boff = (size_t)(n0 + lr) * DMODEL + k0 + lc;
            *(uint4*)(&Ash[lr][lc])     = *(const uint4*)(xh + aoff);
            *(uint4*)(&Ash[lr][lc + 8]) = *(const uint4*)(xh + aoff + 8);
            *(uint4*)(&Asl[lr][lc])     = *(const uint4*)(xl + aoff);
            *(uint4*)(&Asl[lr][lc + 8]) = *(const uint4*)(xl + aoff + 8);
            *(uint4*)(&Bsh[lr][lc])     = *(const uint4*)(Uh + boff);
            *(uint4*)(&Bsh[lr][lc + 8]) = *(const uint4*)(Uh + boff + 8);
            *(uint4*)(&Bsl[lr][lc])     = *(const uint4*)(Ul + boff);
            *(uint4*)(&Bsl[lr][lc + 8]) = *(const uint4*)(Ul + boff + 8);
            __syncthreads();

            #pragma unroll
            for (int hk = 0; hk < 2; hk++) {
                const int kc0 = hk * 32 + quad * 8;
                short8 a0h = *(const short8*)(&Ash[wm + fr][kc0]);
                short8 a1h = *(const short8*)(&Ash[wm + 16 + fr][kc0]);
                short8 a0l = *(const short8*)(&Asl[wm + fr][kc0]);
                short8 a1l = *(const short8*)(&Asl[wm + 16 + fr][kc0]);
                short8 b0h = *(const short8*)(&Bsh[wn + fr][kc0]);
                short8 b1h = *(const short8*)(&Bsh[wn + 16 + fr][kc0]);
                short8 b0l = *(const short8*)(&Bsl[wn + fr][kc0]);
                short8 b1l = *(const short8*)(&Bsl[wn + 16 + fr][kc0]);
                acc[0][0] = __builtin_amdgcn_mfma_f32_16x16x32_bf16(a0l, b0h, acc[0][0], 0, 0, 0);
                acc[0][1] = __builtin_amdgcn_mfma_f32_16x16x32_bf16(a0l, b1h, acc[0][1], 0, 0, 0);
                acc[1][0] = __builtin_amdgcn_mfma_f32_16x16x32_bf16(a1l, b0h, acc[1][0], 0, 0, 0);
                acc[1][1] = __builtin_amdgcn_mfma_f32_16x16x32_bf16(a1l, b1h, acc[1][1], 0, 0, 0);
                acc[0][0] = __builtin_amdgcn_mfma_f32_16x16x32_bf16(a0h, b0l, acc[0][0], 0, 0, 0);
                acc[0][1] = __builtin_amdgcn_mfma_f32_16x16x32_bf16(a0h, b1l, acc[0][1], 0, 0, 0);
                acc[1][0] = __builtin_amdgcn_mfma_f32_16x16x32_bf16(a1h, b0l, acc[1][0], 0, 0, 0);
                acc[1][1] = __builtin_amdgcn_mfma_f32_16x16x32_bf16(a1h, b1l, acc[1][1], 0, 0, 0);
                acc[0][0] = __builtin_amdgcn_mfma_f32_16x16x32_bf16(a0h, b0h, acc[0][0], 0, 0, 0);
                acc[0][1] = __builtin_amdgcn_mfma_f32_16x16x32_bf16(a0h, b1h, acc[0][1], 0, 0, 0);
                acc[1][0] = __builtin_amdgcn_mfma_f32_16x16x32_bf16(a1h, b0h, acc[1][0], 0, 0, 0);
                acc[1][1] = __builtin_amdgcn_mfma_f32_16x16x32_bf16(a1h, b1h, acc[1][1], 0, 0, 0);
            }
            __syncthreads();
        }

        #pragma unroll
        for (int tm = 0; tm < 2; tm++)
        #pragma unroll
        for (int tn = 0; tn < 2; tn++)
        #pragma unroll
        for (int r = 0; r < 4; r++) {
            int row = m0 + wm + tm * 16 + quad * 4 + r;
            int col = n0 + wn + tn * 16 + fr;
            S[(size_t)row * 256 + col] = acc[tm][tn][r];
        }
    }
}

// ---------------------------------------------------------------------------
// E: MFMA flash attention. One workgroup per (g,h); 4 waves x 16 queries.
// Inter: online softmax over union-of-selected blocks (exactly 2 per query,
// skip-gated per query quad). Intra: single causal tile (kb==g), separate
// accumulator. P goes through per-wave LDS (C-layout -> A-frag layout;
// same-wave DS ops are in-order, no barrier needed).
// ---------------------------------------------------------------------------
__global__ __launch_bounds__(256) void attn_mfma_kernel(
    const __hip_bfloat16* __restrict__ Qb, const __hip_bfloat16* __restrict__ Kb,
    const __hip_bfloat16* __restrict__ Vt, const float* __restrict__ S,
    const float2* __restrict__ gate, __hip_bfloat16* __restrict__ oh)
{
    __shared__ alignas(16) __hip_bfloat16 Qs[64][72];
    __shared__ alignas(16) __hip_bfloat16 Ks[64][72];
    __shared__ alignas(16) __hip_bfloat16 Vts[64][72];
    __shared__ alignas(16) __hip_bfloat16 Ps[4][16][72];
    __shared__ int i1s[64], i2s[64];
    __shared__ float2 sgate[64];
    __shared__ unsigned unions;

    const int g = blockIdx.x >> 4, h = blockIdx.x & 15;
    const int tid = threadIdx.x;
    const int wave = tid >> 6, lane = tid & 63;
    const int fr = lane & 15, quad = lane >> 4;
    const int lr = tid >> 2, lc = (tid & 3) * 16;

    // ---- prologue: per-query top-2 (exact tie semantics), gate, union ----
    if (tid < 64) {
        const int n = g * 64 + tid;
        const float* Sn = S + (size_t)n * 256 + h * 16;
        float s[NBLK];
        #pragma unroll
        for (int gg = 0; gg < NBLK; gg++)
            s[gg] = (n >= (gg << 6)) ? -INFINITY : Sn[gg];
        int i1 = -1, i2 = -1;
        float b1 = -INFINITY;
        #pragma unroll
        for (int gg = 0; gg < NBLK; gg++) if (i1 < 0 || s[gg] > b1) { b1 = s[gg]; i1 = gg; }
        float b2 = -INFINITY;
        #pragma unroll
        for (int gg = 0; gg < NBLK; gg++) { if (gg == i1) continue; if (i2 < 0 || s[gg] > b2) { b2 = s[gg]; i2 = gg; } }
        i1s[tid] = i1; i2s[tid] = i2;
        sgate[tid] = gate[(size_t)n * NHEAD + h];
        unsigned m = (1u << i1) | (1u << i2);
        #pragma unroll
        for (int off = 32; off; off >>= 1) m |= (unsigned)__shfl_xor((int)m, off);
        if (tid == 0) unions = m | (1u << g);
    }
    // ---- stage Q tile (once) ----
    {
        const size_t qoff = (size_t)(g * 64 + lr) * DMODEL + h * HDIM + lc;
        *(uint4*)(&Qs[lr][lc])     = *(const uint4*)(Qb + qoff);
        *(uint4*)(&Qs[lr][lc + 8]) = *(const uint4*)(Qb + qoff + 8);
    }
    __syncthreads();

    const unsigned um = unions;

    // Q A-fragments (constant across blocks)
    short8 qa0 = *(const short8*)(&Qs[wave * 16 + fr][quad * 8]);
    short8 qa1 = *(const short8*)(&Qs[wave * 16 + fr][32 + quad * 8]);

    // per-lane copies of top-2 / gate for this quad's 4 query rows
    int qi1[4], qi2[4]; float gx[4], gy[4];
    #pragma unroll
    for (int r = 0; r < 4; r++) {
        int q = wave * 16 + quad * 4 + r;
        qi1[r] = i1s[q]; qi2[r] = i2s[q];
        float2 gg = sgate[q]; gx[r] = gg.x; gy[r] = gg.y;
    }

    f32x4 Oint[4] = {};        // inter accumulator (q x 64d)
    f32x4 Ointr[4] = {};       // intra accumulator
    float mrun[4] = {-INFINITY, -INFINITY, -INFINITY, -INFINITY};
    float lrun[4] = {0.f, 0.f, 0.f, 0.f};
    float li[4]   = {1.f, 1.f, 1.f, 1.f};

    for (int kb = 0; kb < NBLK; kb++) {
        if (!((um >> kb) & 1u)) continue;
        __syncthreads();   // prev iteration's LDS reads done before restage

        // stage K[kb] rows (64k x 64d) and Vt[kb] rows (64d x 64k)
        {
            const size_t koff = (size_t)(kb * 64 + lr) * DMODEL + h * HDIM + lc;
            *(uint4*)(&Ks[lr][lc])     = *(const uint4*)(Kb + koff);
            *(uint4*)(&Ks[lr][lc + 8]) = *(const uint4*)(Kb + koff + 8);
            const size_t voff = (size_t)(h * HDIM + lr) * NTOK + kb * 64 + lc;
            *(uint4*)(&Vts[lr][lc])     = *(const uint4*)(Vt + voff);
            *(uint4*)(&Vts[lr][lc + 8]) = *(const uint4*)(Vt + voff + 8);
        }
        __syncthreads();

        // ---- QK^T: 16q x 64k ----
        f32x4 sacc[4] = {};
        #pragma unroll
        for (int t = 0; t < 4; t++) {
            short8 kb0 = *(const short8*)(&Ks[t * 16 + fr][quad * 8]);
            short8 kb1 = *(const short8*)(&Ks[t * 16 + fr][32 + quad * 8]);
            sacc[t] = __builtin_amdgcn_mfma_f32_16x16x32_bf16(qa0, kb0, sacc[t], 0, 0, 0);
            sacc[t] = __builtin_amdgcn_mfma_f32_16x16x32_bf16(qa1, kb1, sacc[t], 0, 0, 0);
        }

        if (kb != g) {
            // ---- inter: online softmax, per-query selected-block gating ----
            #pragma unroll
            for (int r = 0; r < 4; r++) {
                const bool sel = (kb == qi1[r]) | (kb == qi2[r]);   // quad-uniform
                float v0 = sacc[0][r] * 0.125f, v1 = sacc[1][r] * 0.125f;
                float v2 = sacc[2][r] * 0.125f, v3 = sacc[3][r] * 0.125f;
                float mx = qmax16(fmaxf(fmaxf(v0, v1), fmaxf(v2, v3)));
                float mnew = sel ? fmaxf(mrun[r], mx) : mrun[r];
                float f = sel ? __expf(mrun[r] - mnew) : 1.0f;
                float e0 = sel ? __expf(v0 - mnew) : 0.f;
                float e1 = sel ? __expf(v1 - mnew) : 0.f;
                float e2 = sel ? __expf(v2 - mnew) : 0.f;
                float e3 = sel ? __expf(v3 - mnew) : 0.f;
                float es = qsum16(e0 + e1 + e2 + e3);
                lrun[r] = lrun[r] * f + es;
                mrun[r] = mnew;
                #pragma unroll
                for (int dn = 0; dn < 4; dn++) Oint[dn][r] *= f;
                const int prow = quad * 4 + r;
                Ps[wave][prow][ 0 + fr] = __float2bfloat16(e0);
                Ps[wave][prow][16 + fr] = __float2bfloat16(e1);
                Ps[wave][prow][32 + fr] = __float2bfloat16(e2);
                Ps[wave][prow][48 + fr] = __float2bfloat16(e3);
            }
        } else {
            // ---- intra: single causal tile, full softmax here ----
            #pragma unroll
            for (int r = 0; r < 4; r++) {
                const int qloc = wave * 16 + quad * 4 + r;   // query row in chunk
                float vv[4];
                #pragma unroll
                for (int t = 0; t < 4; t++) {
                    const int col = t * 16 + fr;
                    float v = sacc[t][r] * 0.125f;
                    vv[t] = (col <= qloc) ? v : -INFINITY;
                }
                float mx = qmax16(fmaxf(fmaxf(vv[0], vv[1]), fmaxf(vv[2], vv[3])));
                float e0 = __expf(vv[0] - mx), e1 = __expf(vv[1] - mx);
                float e2 = __expf(vv[2] - mx), e3 = __expf(vv[3] - mx);
                li[r] = qsum16(e0 + e1 + e2 + e3);
                const int prow = quad * 4 + r;
                Ps[wave][prow][ 0 + fr] = __float2bfloat16(e0);
                Ps[wave][prow][16 + fr] = __float2bfloat16(e1);
                Ps[wave][prow][32 + fr] = __float2bfloat16(e2);
                Ps[wave][prow][48 + fr] = __float2bfloat16(e3);
            }
        }

        // ---- PV: O += P @ V  (P via per-wave LDS round-trip) ----
        short8 pa0 = *(const short8*)(&Ps[wave][fr][quad * 8]);
        short8 pa1 = *(const short8*)(&Ps[wave][fr][32 + quad * 8]);
        if (kb == g) {
            #pragma unroll
            for (int dn = 0; dn < 4; dn++) {
                short8 v0 = *(const short8*)(&Vts[dn * 16 + fr][quad * 8]);
                short8 v1 = *(const short8*)(&Vts[dn * 16 + fr][32 + quad * 8]);
                Ointr[dn] = __builtin_amdgcn_mfma_f32_16x16x32_bf16(pa0, v0, Ointr[dn], 0, 0, 0);
                Ointr[dn] = __builtin_amdgcn_mfma_f32_16x16x32_bf16(pa1, v1, Ointr[dn], 0, 0, 0);
            }
        } else {
            #pragma unroll
            for (int dn = 0; dn < 4; dn++) {
                short8 v0 = *(const short8*)(&Vts[dn * 16 + fr][quad * 8]);
                short8 v1 = *(const short8*)(&Vts[dn * 16 + fr][32 + quad * 8]);
                Oint[dn] = __builtin_amdgcn_mfma_f32_16x16x32_bf16(pa0, v0, Oint[dn], 0, 0, 0);
                Oint[dn] = __builtin_amdgcn_mfma_f32_16x16x32_bf16(pa1, v1, Oint[dn], 0, 0, 0);
            }
        }
    }

    // ---- epilogue: gated blend, write oh bf16 ----
    #pragma unroll
    for (int r = 0; r < 4; r++) {
        const float winter = gx[r] / lrun[r];
        const float wintra = gy[r] / li[r];
        const int q = wave * 16 + quad * 4 + r;
        const int n = g * 64 + q;
        #pragma unroll
        for (int dn = 0; dn < 4; dn++) {
            float val = winter * Oint[dn][r] + wintra * Ointr[dn][r];
            oh[(size_t)n * DMODEL + h * HDIM + dn * 16 + fr] = __float2bfloat16(val);
        }
    }
}

// ---------------------------------------------------------------------------
// F: Wo GEMM: C = oh x (Woh + Wol)^T, 64x64 tile, BK=64, f32 store.
// ---------------------------------------------------------------------------
__global__ __launch_bounds__(256) void gemm_wo(
    const __hip_bfloat16* __restrict__ Ah,
    const __hip_bfloat16* __restrict__ Bh, const __hip_bfloat16* __restrict__ Bl,
    float* __restrict__ C)
{
    __shared__ alignas(16) __hip_bfloat16 Ash[64][72];
    __shared__ alignas(16) __hip_bfloat16 Bsh[64][72];
    __shared__ alignas(16) __hip_bfloat16 Bsl[64][72];

    const int n0 = blockIdx.x * 64;
    const int m0 = blockIdx.y * 64;

    const int tid  = threadIdx.x;
    const int wave = tid >> 6;
    const int lane = tid & 63;
    const int lr = tid >> 2;
    const int lc = (tid & 3) * 16;
    const int wm = (wave >> 1) * 32;
    const int wn = (wave & 1) * 32;
    const int fr = lane & 15;
    const int quad = lane >> 4;

    f32x4 acc[2][2] = {};

    for (int k0 = 0; k0 < DMODEL; k0 += 64) {
        const size_t aoff = (size_t)(m0 + lr) * DMODEL + k0 + lc;
        const size_t boff = (size_t)(n0 + lr) * DMODEL + k0 + lc;
        *(uint4*)(&Ash[lr][lc])     = *(const uint4*)(Ah + aoff);
        *(uint4*)(&Ash[lr][lc + 8]) = *(const uint4*)(Ah + aoff + 8);
        *(uint4*)(&Bsh[lr][lc])     = *(const uint4*)(Bh + boff);
        *(uint4*)(&Bsh[lr][lc + 8]) = *(const uint4*)(Bh + boff + 8);
        *(uint4*)(&Bsl[lr][lc])     = *(const uint4*)(Bl + boff);
        *(uint4*)(&Bsl[lr][lc + 8]) = *(const uint4*)(Bl + boff + 8);
        __syncthreads();

        #pragma unroll
        for (int hk = 0; hk < 2; hk++) {
            const int kc0 = hk * 32 + quad * 8;
            short8 a0 = *(const short8*)(&Ash[wm + fr][kc0]);
            short8 a1 = *(const short8*)(&Ash[wm + 16 + fr][kc0]);
            short8 b0h = *(const short8*)(&Bsh[wn + fr][kc0]);
            short8 b1h = *(const short8*)(&Bsh[wn + 16 + fr][kc0]);
            short8 b0l = *(const short8*)(&Bsl[wn + fr][kc0]);
            short8 b1l = *(const short8*)(&Bsl[wn + 16 + fr][kc0]);
            acc[0][0] = __builtin_amdgcn_mfma_f32_16x16x32_bf16(a0, b0l, acc[0][0], 0, 0, 0);
            acc[0][1] = __builtin_amdgcn_mfma_f32_16x16x32_bf16(a0, b1l, acc[0][1], 0, 0, 0);
            acc[1][0] = __builtin_amdgcn_mfma_f32_16x16x32_bf16(a1, b0l, acc[1][0], 0, 0, 0);
            acc[1][1] = __builtin_amdgcn_mfma_f32_16x16x32_bf16(a1, b1l, acc[1][1], 0, 0, 0);
            acc[0][0] = __builtin_amdgcn_mfma_f32_16x16x32_bf16(a0, b0h, acc[0][0], 0, 0, 0);
            acc[0][1] = __builtin_amdgcn_mfma_f32_16x16x32_bf16(a0, b1h, acc[0][1], 0, 0, 0);
            acc[1][0] = __builtin_amdgcn_mfma_f32_16x16x32_bf16(a1, b0h, acc[1][0], 0, 0, 0);
            acc[1][1] = __builtin_amdgcn_mfma_f32_16x16x32_bf16(a1, b1h, acc[1][1], 0, 0, 0);
        }
        __syncthreads();
    }

    #pragma unroll
    for (int tm = 0; tm < 2; tm++)
    #pragma unroll
    for (int tn = 0; tn < 2; tn++)
    #pragma unroll
    for (int r = 0; r < 4; r++) {
        int row = m0 + wm + tm * 16 + quad * 4 + r;
        int col = n0 + wn + tn * 16 + fr;
        C[(size_t)row * DMODEL + col] = acc[tm][tn][r];
    }
}

// ---------------------------------------------------------------------------
extern "C" void kernel_launch(void* const* d_in, const int* in_sizes, int n_in,
                              void* d_out, int out_size, void* d_ws, size_t ws_size,
                              hipStream_t stream)
{
    const float* x  = (const float*)d_in[0];
    const float* Wq = (const float*)d_in[1];
    const float* Wk = (const float*)d_in[2];
    const float* Wv = (const float*)d_in[3];
    const float* Wg = (const float*)d_in[4];
    const float* Wo = (const float*)d_in[5];

    const size_t M1 = (size_t)NTOK * DMODEL;   // 1M elems

    // workspace layout (~24.5 MB)
    float* S       = (float*)d_ws;                    // 1 MB (scores [1024][256])
    float* xm      = S + (size_t)NTOK * 256;          // 64 KB
    float* kc      = xm + NBLK * DMODEL;              // 64 KB
    float2* gate   = (float2*)(kc + NBLK * DMODEL);   // 128 KB
    __hip_bfloat16* xh  = (__hip_bfloat16*)(gate + NTOK * NHEAD);   // 2 MB
    __hip_bfloat16* xl  = xh + M1;     // 2 MB
    __hip_bfloat16* Wqh = xl + M1;     // 2 MB
    __hip_bfloat16* Wkh = Wqh + M1;    // 2 MB
    __hip_bfloat16* Wvh = Wkh + M1;    // 2 MB
    __hip_bfloat16* Woh = Wvh + M1;    // 2 MB
    __hip_bfloat16* Wol = Woh + M1;    // 2 MB
    __hip_bfloat16* oh  = Wol + M1;    // 2 MB
    __hip_bfloat16* Uh  = oh + M1;     // 512 KB ([256][1024])
    __hip_bfloat16* Ul  = Uh + 256 * DMODEL;  // 512 KB
    __hip_bfloat16* Qb  = Ul + 256 * DMODEL;  // 2 MB  bf16 [n][D]
    __hip_bfloat16* Kb  = Qb + M1;            // 2 MB  bf16 [n][D]
    __hip_bfloat16* Vt  = Kb + M1;            // 2 MB  bf16 [f][n] (transposed)

    prep_kernel<<<6208, 256, 0, stream>>>(
        x, Wq, Wk, Wv, Wo, Wg, xh, xl, Wqh, Wkh, Wvh, Woh, Wol, xm, gate);

    kc_gemm_kernel<<<1024, 256, 0, stream>>>(xm, Wk, kc);
    u_kernel<<<256, 256, 0, stream>>>(kc, Wq, Uh, Ul);

    qkv_score_kernel<<<832, 256, 0, stream>>>(
        xh, xl, Wqh, Wkh, Wvh, Uh, Ul, Qb, Kb, Vt, S);

    attn_mfma_kernel<<<NBLK * NHEAD, 256, 0, stream>>>(Qb, Kb, Vt, S, gate, oh);

    dim3 gwo(16, 16);
    gemm_wo<<<gwo, 256, 0, stream>>>(oh, Woh, Wol, (float*)d_out);
}

// Round 2
// 178.755 us; speedup vs baseline: 1.0845x; 1.0627x over previous
//
#include <hip/hip_runtime.h>
#include <hip/hip_bf16.h>
#include <math.h>

// Problem: B=1, N=1024, D=1024, H=16, C=64, TOPK=2, HD=64, G=16
//
// Round-2 attention restructure: previous MFMA attn was latency-bound
// (256 blocks = 1/CU, 7% occupancy, serial union loop with 2 barriers/iter).
// New attn: grid = (g,h,qtile) = 1024 blocks x 4 waves. All 4 waves of a
// block handle the SAME 16 queries; each wave processes every 4th entry of
// the block list (union of top-2 selections + the causal intra tile), with
// K/V MFMA fragments loaded DIRECTLY from global (L2-resident) -- zero
// barriers in the main loop. Partials (m, l, O) merged across the 4 splits
// via LDS with the exact split-softmax combine. Intra tile owned by one
// split, kept separate (own softmax), blended with gates in the epilogue.

typedef __attribute__((ext_vector_type(8))) short short8;   // 8 bf16 = 4 VGPRs
typedef __attribute__((ext_vector_type(4))) float f32x4;

#define NTOK 1024
#define DMODEL 1024
#define NHEAD 16
#define HDIM 64
#define CHUNK 64
#define NBLK 16

__device__ __forceinline__ float qmax16(float v)
{
    #pragma unroll
    for (int off = 1; off < 16; off <<= 1) v = fmaxf(v, __shfl_xor(v, off));
    return v;
}

__device__ __forceinline__ float qsum16(float v)
{
    #pragma unroll
    for (int off = 1; off < 16; off <<= 1) v += __shfl_xor(v, off);
    return v;
}

// ---------------------------------------------------------------------------
// A: prep. blockIdx roles: [0,5120) casts (which = bid>>10: 0 x split,
// 1 Wq hi, 2 Wk hi, 3 Wv hi, 4 Wo split), [5120,5184) xm, [5184,6208) gate.
// ---------------------------------------------------------------------------
__global__ __launch_bounds__(256) void prep_kernel(
    const float* __restrict__ x,  const float* __restrict__ Wq,
    const float* __restrict__ Wk, const float* __restrict__ Wv,
    const float* __restrict__ Wo, const float* __restrict__ Wg,
    __hip_bfloat16* __restrict__ xh,  __hip_bfloat16* __restrict__ xl,
    __hip_bfloat16* __restrict__ Wqh,
    __hip_bfloat16* __restrict__ Wkh, __hip_bfloat16* __restrict__ Wvh,
    __hip_bfloat16* __restrict__ Woh, __hip_bfloat16* __restrict__ Wol,
    float* __restrict__ xm, float2* __restrict__ gate)
{
    __shared__ float gs[32];
    const int bid = blockIdx.x;
    if (bid < 5120) {
        const int which = bid >> 10;
        const int b = bid & 1023;
        const int i = (b * 256 + threadIdx.x) * 4;
        const float* in; __hip_bfloat16 *hi, *lo = nullptr;
        if (which == 0)      { in = x;  hi = xh;  lo = xl; }
        else if (which == 1) { in = Wq; hi = Wqh; }
        else if (which == 2) { in = Wk; hi = Wkh; }
        else if (which == 3) { in = Wv; hi = Wvh; }
        else                 { in = Wo; hi = Woh; lo = Wol; }
        float4 v = *(const float4*)(in + i);
        float vv[4] = {v.x, v.y, v.z, v.w};
        __hip_bfloat16 h[4], l[4];
        #pragma unroll
        for (int j = 0; j < 4; j++) {
            h[j] = __float2bfloat16(vv[j]);
            l[j] = __float2bfloat16(vv[j] - __bfloat162float(h[j]));
        }
        *(uint2*)(hi + i) = *(uint2*)h;
        if (lo) *(uint2*)(lo + i) = *(uint2*)l;
    } else if (bid < 5184) {
        const int b = bid - 5120;
        const int g = b >> 2;
        const int f = (b & 3) * 256 + threadIdx.x;
        float s = 0.f;
        #pragma unroll 8
        for (int c = 0; c < CHUNK; c++) s += x[(size_t)(g * CHUNK + c) * DMODEL + f];
        xm[g * DMODEL + f] = s * (1.0f / CHUNK);
    } else {
        const int n = bid - 5184;
        const int wave = threadIdx.x >> 6, lane = threadIdx.x & 63;
        #pragma unroll
        for (int jj = 0; jj < 8; jj++) {
            int j = wave * 8 + jj;
            float s = 0.f;
            #pragma unroll
            for (int t = 0; t < 16; t++) {
                int d = lane + (t << 6);
                s += x[n * DMODEL + d] * Wg[j * DMODEL + d];
            }
            #pragma unroll
            for (int off = 32; off; off >>= 1) s += __shfl_xor(s, off);
            if (lane == 0) gs[j] = s;
        }
        __syncthreads();
        if (threadIdx.x < NHEAD) {
            int h = threadIdx.x;
            float a = gs[2 * h], b = gs[2 * h + 1];
            float m = fmaxf(a, b);
            float ea = expf(a - m), eb = expf(b - m);
            float inv = 1.f / (ea + eb);
            gate[n * NHEAD + h] = make_float2(ea * inv, eb * inv);
        }
    }
}

// ---------------------------------------------------------------------------
// B: kc = xm @ Wk^T (exact f32). One block per f; (g = tid>>4, sub = tid&15).
// ---------------------------------------------------------------------------
__global__ __launch_bounds__(256) void kc_gemm_kernel(
    const float* __restrict__ xm, const float* __restrict__ Wk,
    float* __restrict__ kc)
{
    const int f = blockIdx.x;
    const int g = threadIdx.x >> 4;
    const int sub = threadIdx.x & 15;
    const float* wrow = Wk + (size_t)f * DMODEL;
    float s = 0.f;
    #pragma unroll 16
    for (int i = 0; i < 64; i++) {
        int e = i * 16 + sub;
        s += xm[g * DMODEL + e] * wrow[e];
    }
    #pragma unroll
    for (int off = 8; off; off >>= 1) s += __shfl_xor(s, off);
    if (sub == 0) kc[g * DMODEL + f] = s;
}

// ---------------------------------------------------------------------------
// C: U[(h<<4)|g][f] = sum_d kc[g][h*64+d] * Wq[h*64+d][f]  (exact f32),
// then split to bf16 hi/lo rows Uh/Ul [256][1024].
// ---------------------------------------------------------------------------
__global__ __launch_bounds__(256) void u_kernel(
    const float* __restrict__ kc, const float* __restrict__ Wq,
    __hip_bfloat16* __restrict__ Uh, __hip_bfloat16* __restrict__ Ul)
{
    __shared__ float kcs[64];
    const int h = blockIdx.x >> 4, g = blockIdx.x & 15;
    if (threadIdx.x < 64) kcs[threadIdx.x] = kc[g * DMODEL + h * HDIM + threadIdx.x];
    __syncthreads();
    const int col = (h << 4) | g;
    for (int f = threadIdx.x; f < DMODEL; f += 256) {
        float s = 0.f;
        #pragma unroll 16
        for (int d = 0; d < 64; d++)
            s += kcs[d] * Wq[(size_t)(h * HDIM + d) * DMODEL + f];
        __hip_bfloat16 hv = __float2bfloat16(s);
        Uh[(size_t)col * DMODEL + f] = hv;
        Ul[(size_t)col * DMODEL + f] = __float2bfloat16(s - __bfloat162float(hv));
    }
}

// ---------------------------------------------------------------------------
// D: qkv GEMMs (blocks [0,768), BK=64, plain bf16) + score GEMM (blocks
// [768,832): S[1024][256] = (xh+xl) @ (Uh+Ul)^T, 3-term split, ~1e-5 rel).
// Epilogues: Q,K -> bf16 [n][D]; V -> bf16 transposed Vt[f][n] via LDS.
// ---------------------------------------------------------------------------
__global__ __launch_bounds__(256) void qkv_score_kernel(
    const __hip_bfloat16* __restrict__ xh, const __hip_bfloat16* __restrict__ xl,
    const __hip_bfloat16* __restrict__ Wqh, const __hip_bfloat16* __restrict__ Wkh,
    const __hip_bfloat16* __restrict__ Wvh,
    const __hip_bfloat16* __restrict__ Uh, const __hip_bfloat16* __restrict__ Ul,
    __hip_bfloat16* __restrict__ Qb, __hip_bfloat16* __restrict__ Kb,
    __hip_bfloat16* __restrict__ Vt, float* __restrict__ S)
{
    __shared__ uint4 smem4[36864 / 16];     // 36 KB shared scratch, 16B-aligned
    char* smem = (char*)smem4;
    const int b = blockIdx.x;

    const int tid  = threadIdx.x;
    const int wave = tid >> 6;
    const int lane = tid & 63;
    const int lr = tid >> 2;
    const int lc = (tid & 3) * 16;
    const int wm = (wave >> 1) * 32;
    const int wn = (wave & 1) * 32;
    const int fr = lane & 15;
    const int quad = lane >> 4;

    if (b < 768) {
        // ---- QKV GEMM (plain bf16) ----
        __hip_bfloat16 (*Ash)[72] = (__hip_bfloat16(*)[72])smem;
        __hip_bfloat16 (*Bsh)[72] = (__hip_bfloat16(*)[72])(smem + 9216);

        const int widx = b >> 8;
        const int t = b & 255;
        const __hip_bfloat16* __restrict__ Bh =
            (widx == 0) ? Wqh : (widx == 1) ? Wkh : Wvh;
        const int n0 = (t & 15) * 64;
        const int m0 = (t >> 4) * 64;

        f32x4 acc[2][2] = {};

        for (int k0 = 0; k0 < DMODEL; k0 += 64) {
            const size_t aoff = (size_t)(m0 + lr) * DMODEL + k0 + lc;
            const size_t boff = (size_t)(n0 + lr) * DMODEL + k0 + lc;
            *(uint4*)(&Ash[lr][lc])     = *(const uint4*)(xh + aoff);
            *(uint4*)(&Ash[lr][lc + 8]) = *(const uint4*)(xh + aoff + 8);
            *(uint4*)(&Bsh[lr][lc])     = *(const uint4*)(Bh + boff);
            *(uint4*)(&Bsh[lr][lc + 8]) = *(const uint4*)(Bh + boff + 8);
            __syncthreads();

            #pragma unroll
            for (int hk = 0; hk < 2; hk++) {
                const int kc0 = hk * 32 + quad * 8;
                short8 a0 = *(const short8*)(&Ash[wm + fr][kc0]);
                short8 a1 = *(const short8*)(&Ash[wm + 16 + fr][kc0]);
                short8 b0 = *(const short8*)(&Bsh[wn + fr][kc0]);
                short8 b1 = *(const short8*)(&Bsh[wn + 16 + fr][kc0]);
                acc[0][0] = __builtin_amdgcn_mfma_f32_16x16x32_bf16(a0, b0, acc[0][0], 0, 0, 0);
                acc[0][1] = __builtin_amdgcn_mfma_f32_16x16x32_bf16(a0, b1, acc[0][1], 0, 0, 0);
                acc[1][0] = __builtin_amdgcn_mfma_f32_16x16x32_bf16(a1, b0, acc[1][0], 0, 0, 0);
                acc[1][1] = __builtin_amdgcn_mfma_f32_16x16x32_bf16(a1, b1, acc[1][1], 0, 0, 0);
            }
            __syncthreads();
        }

        if (widx == 0) {
            #pragma unroll
            for (int tm = 0; tm < 2; tm++)
            #pragma unroll
            for (int tn = 0; tn < 2; tn++)
            #pragma unroll
            for (int r = 0; r < 4; r++) {
                int row = m0 + wm + tm * 16 + quad * 4 + r;
                int col = n0 + wn + tn * 16 + fr;
                Qb[(size_t)row * DMODEL + col] = __float2bfloat16(acc[tm][tn][r]);
            }
        } else if (widx == 1) {
            #pragma unroll
            for (int tm = 0; tm < 2; tm++)
            #pragma unroll
            for (int tn = 0; tn < 2; tn++)
            #pragma unroll
            for (int r = 0; r < 4; r++) {
                int row = m0 + wm + tm * 16 + quad * 4 + r;
                int col = n0 + wn + tn * 16 + fr;
                Kb[(size_t)row * DMODEL + col] = __float2bfloat16(acc[tm][tn][r]);
            }
        } else {
            // V: transpose 64x64 tile through LDS, store Vt[f][n] coalesced.
            __hip_bfloat16 (*T)[72] = (__hip_bfloat16(*)[72])smem;
            #pragma unroll
            for (int tm = 0; tm < 2; tm++)
            #pragma unroll
            for (int tn = 0; tn < 2; tn++)
            #pragma unroll
            for (int r = 0; r < 4; r++) {
                int nloc = wm + tm * 16 + quad * 4 + r;
                int floc = wn + tn * 16 + fr;
                T[floc][nloc] = __float2bfloat16(acc[tm][tn][r]);
            }
            __syncthreads();
            const size_t o = (size_t)(n0 + lr) * NTOK + m0 + lc;
            *(uint4*)(Vt + o)     = *(uint4*)(&T[lr][lc]);
            *(uint4*)(Vt + o + 8) = *(uint4*)(&T[lr][lc + 8]);
        }
    } else {
        // ---- score GEMM: S = (xh+xl) @ (Uh+Ul)^T, 3-term split ----
        __hip_bfloat16 (*Ash)[72] = (__hip_bfloat16(*)[72])smem;
        __hip_bfloat16 (*Asl)[72] = (__hip_bfloat16(*)[72])(smem + 9216);
        __hip_bfloat16 (*Bsh)[72] = (__hip_bfloat16(*)[72])(smem + 18432);
        __hip_bfloat16 (*Bsl)[72] = (__hip_bfloat16(*)[72])(smem + 27648);

        const int bb = b - 768;                 // [0,64)
        const int m0 = (bb >> 2) * 64;          // 16 token tiles
        const int n0 = (bb & 3) * 64;           // 4 col tiles (256 cols)

        f32x4 acc[2][2] = {};

        for (int k0 = 0; k0 < DMODEL; k0 += 64) {
            const size_t aoff = (size_t)(m0 + lr) * DMODEL + k0 + lc;
            const size_t boff = (size_t)(n0 + lr) * DMODEL + k0 + lc;
            *(uint4*)(&Ash[lr][lc])     = *(const uint4*)(xh + aoff);
            *(uint4*)(&Ash[lr][lc + 8]) = *(const uint4*)(xh + aoff + 8);
            *(uint4*)(&Asl[lr][lc])     = *(const uint4*)(xl + aoff);
            *(uint4*)(&Asl[lr][lc + 8]) = *(const uint4*)(xl + aoff + 8);
            *(uint4*)(&Bsh[lr][lc])     = *(const uint4*)(Uh + boff);
            *(uint4*)(&Bsh[lr][lc + 8]) = *(const uint4*)(Uh + boff + 8);
            *(uint4*)(&Bsl[lr][lc])     = *(const uint4*)(Ul + boff);
            *(uint4*)(&Bsl[lr][lc + 8]) = *(const uint4*)(Ul + boff + 8);
            __syncthreads();

            #pragma unroll
            for (int hk = 0; hk < 2; hk++) {
                const int kc0 = hk * 32 + quad * 8;
                short8 a0h = *(const short8*)(&Ash[wm + fr][kc0]);
                short8 a1h = *(const short8*)(&Ash[wm + 16 + fr][kc0]);
                short8 a0l = *(const short8*)(&Asl[wm + fr][kc0]);
                short8 a1l = *(const short8*)(&Asl[wm + 16 + fr][kc0]);
                short8 b0h = *(const short8*)(&Bsh[wn + fr][kc0]);
                short8 b1h = *(const short8*)(&Bsh[wn + 16 + fr][kc0]);
                short8 b0l = *(const short8*)(&Bsl[wn + fr][kc0]);
                short8 b1l = *(const short8*)(&Bsl[wn + 16 + fr][kc0]);
                acc[0][0] = __builtin_amdgcn_mfma_f32_16x16x32_bf16(a0l, b0h, acc[0][0], 0, 0, 0);
                acc[0][1] = __builtin_amdgcn_mfma_f32_16x16x32_bf16(a0l, b1h, acc[0][1], 0, 0, 0);
                acc[1][0] = __builtin_amdgcn_mfma_f32_16x16x32_bf16(a1l, b0h, acc[1][0], 0, 0, 0);
                acc[1][1] = __builtin_amdgcn_mfma_f32_16x16x32_bf16(a1l, b1h, acc[1][1], 0, 0, 0);
                acc[0][0] = __builtin_amdgcn_mfma_f32_16x16x32_bf16(a0h, b0l, acc[0][0], 0, 0, 0);
                acc[0][1] = __builtin_amdgcn_mfma_f32_16x16x32_bf16(a0h, b1l, acc[0][1], 0, 0, 0);
                acc[1][0] = __builtin_amdgcn_mfma_f32_16x16x32_bf16(a1h, b0l, acc[1][0], 0, 0, 0);
                acc[1][1] = __builtin_amdgcn_mfma_f32_16x16x32_bf16(a1h, b1l, acc[1][1], 0, 0, 0);
                acc[0][0] = __builtin_amdgcn_mfma_f32_16x16x32_bf16(a0h, b0h, acc[0][0], 0, 0, 0);
                acc[0][1] = __builtin_amdgcn_mfma_f32_16x16x32_bf16(a0h, b1h, acc[0][1], 0, 0, 0);
                acc[1][0] = __builtin_amdgcn_mfma_f32_16x16x32_bf16(a1h, b0h, acc[1][0], 0, 0, 0);
                acc[1][1] = __builtin_amdgcn_mfma_f32_16x16x32_bf16(a1h, b1h, acc[1][1], 0, 0, 0);
            }
            __syncthreads();
        }

        #pragma unroll
        for (int tm = 0; tm < 2; tm++)
        #pragma unroll
        for (int tn = 0; tn < 2; tn++)
        #pragma unroll
        for (int r = 0; r < 4; r++) {
            int row = m0 + wm + tm * 16 + quad * 4 + r;
            int col = n0 + wn + tn * 16 + fr;
            S[(size_t)row * 256 + col] = acc[tm][tn][r];
        }
    }
}

// ---------------------------------------------------------------------------
// E: split-K MFMA attention. Grid = (g,h,qtile) = 1024 blocks x 4 waves.
// All 4 waves handle the same 16 queries; wave s processes entries
// {j : j % 4 == s} of the block list (sorted union of top-2 + intra last).
// K/V fragments loaded directly from global (L2-resident) -- no barriers in
// the main loop. Split partials merged in LDS (exact softmax combine).
// ---------------------------------------------------------------------------
__global__ __launch_bounds__(256, 4) void attn_mfma_kernel(
    const __hip_bfloat16* __restrict__ Qb, const __hip_bfloat16* __restrict__ Kb,
    const __hip_bfloat16* __restrict__ Vt, const float* __restrict__ S,
    const float2* __restrict__ gate, __hip_bfloat16* __restrict__ oh)
{
    __shared__ float OS[4][16][64];     // per-split inter partial O
    __shared__ float OIs[16][64];       // intra O
    __shared__ float mS[4][16], lS[4][16], liS[16];
    __shared__ int i1s[16], i2s[16];
    __shared__ float2 sgate[16];
    __shared__ unsigned unionMask;
    __shared__ __hip_bfloat16 Ps[4][16][72];   // per-wave P round-trip

    const int bid = blockIdx.x;
    const int qt = bid & 3;
    const int h  = (bid >> 2) & 15;
    const int g  = bid >> 6;
    const int tid = threadIdx.x;
    const int s = tid >> 6;             // wave = key-split id
    const int lane = tid & 63;
    const int fr = lane & 15, quad = lane >> 4;

    // ---- prologue: per-query top-2 (exact tie semantics), gate, union ----
    if (tid < 16) {
        const int n = g * 64 + qt * 16 + tid;
        const float* Sn = S + (size_t)n * 256 + h * 16;
        float sc[NBLK];
        #pragma unroll
        for (int gg = 0; gg < NBLK; gg++)
            sc[gg] = (n >= (gg << 6)) ? -INFINITY : Sn[gg];
        int i1 = -1, i2 = -1;
        float b1 = -INFINITY;
        #pragma unroll
        for (int gg = 0; gg < NBLK; gg++) if (i1 < 0 || sc[gg] > b1) { b1 = sc[gg]; i1 = gg; }
        float b2 = -INFINITY;
        #pragma unroll
        for (int gg = 0; gg < NBLK; gg++) { if (gg == i1) continue; if (i2 < 0 || sc[gg] > b2) { b2 = sc[gg]; i2 = gg; } }
        i1s[tid] = i1; i2s[tid] = i2;
        sgate[tid] = gate[(size_t)n * NHEAD + h];
        unsigned m = (1u << i1) | (1u << i2);
        #pragma unroll
        for (int off = 1; off < 16; off <<= 1) m |= (unsigned)__shfl_xor((int)m, off);
        if (tid == 0) unionMask = m;
    }
    __syncthreads();

    const unsigned um = unionMask;

    // ---- Q A-fragments direct from global ----
    const size_t qrow = (size_t)(g * 64 + qt * 16 + fr) * DMODEL + h * HDIM + quad * 8;
    const short8 qa0 = *(const short8*)(Qb + qrow);
    const short8 qa1 = *(const short8*)(Qb + qrow + 32);

    // per-lane copies of top-2 / gate for this quad's 4 query rows
    int qi1[4], qi2[4];
    #pragma unroll
    for (int r = 0; r < 4; r++) {
        int q = quad * 4 + r;
        qi1[r] = i1s[q]; qi2[r] = i2s[q];
    }

    f32x4 Oint[4] = {};        // inter accumulator (16q x 64d)
    float mrun[4] = {-INFINITY, -INFINITY, -INFINITY, -INFINITY};
    float lrun[4] = {0.f, 0.f, 0.f, 0.f};

    const __hip_bfloat16* __restrict__ Kh = Kb + h * HDIM + quad * 8;
    const __hip_bfloat16* __restrict__ Vh = Vt + (size_t)(h * HDIM) * NTOK + quad * 8;

    int j = 0;
    for (int kb = 0; kb < NBLK; kb++) {
        if (!((um >> kb) & 1u)) continue;
        if ((j++ & 3) != s) continue;

        // ---- QK^T: 16q x 64k, K frags direct from global ----
        f32x4 sacc[4] = {};
        #pragma unroll
        for (int t = 0; t < 4; t++) {
            const size_t krow = (size_t)(kb * 64 + t * 16 + fr) * DMODEL;
            short8 kb0 = *(const short8*)(Kh + krow);
            short8 kb1 = *(const short8*)(Kh + krow + 32);
            sacc[t] = __builtin_amdgcn_mfma_f32_16x16x32_bf16(qa0, kb0, sacc[t], 0, 0, 0);
            sacc[t] = __builtin_amdgcn_mfma_f32_16x16x32_bf16(qa1, kb1, sacc[t], 0, 0, 0);
        }

        // ---- inter online softmax, per-query selected-block gating ----
        #pragma unroll
        for (int r = 0; r < 4; r++) {
            const bool sel = (kb == qi1[r]) | (kb == qi2[r]);   // quad-uniform
            float v0 = sacc[0][r] * 0.125f, v1 = sacc[1][r] * 0.125f;
            float v2 = sacc[2][r] * 0.125f, v3 = sacc[3][r] * 0.125f;
            float mx = qmax16(fmaxf(fmaxf(v0, v1), fmaxf(v2, v3)));
            float mnew = sel ? fmaxf(mrun[r], mx) : mrun[r];
            float f = sel ? __expf(mrun[r] - mnew) : 1.0f;
            float e0 = sel ? __expf(v0 - mnew) : 0.f;
            float e1 = sel ? __expf(v1 - mnew) : 0.f;
            float e2 = sel ? __expf(v2 - mnew) : 0.f;
            float e3 = sel ? __expf(v3 - mnew) : 0.f;
            float es = qsum16(e0 + e1 + e2 + e3);
            lrun[r] = lrun[r] * f + es;
            mrun[r] = mnew;
            #pragma unroll
            for (int dn = 0; dn < 4; dn++) Oint[dn][r] *= f;
            const int prow = quad * 4 + r;
            Ps[s][prow][ 0 + fr] = __float2bfloat16(e0);
            Ps[s][prow][16 + fr] = __float2bfloat16(e1);
            Ps[s][prow][32 + fr] = __float2bfloat16(e2);
            Ps[s][prow][48 + fr] = __float2bfloat16(e3);
        }

        // ---- PV: O += P @ V, V frags direct from global ----
        short8 pa0 = *(const short8*)(&Ps[s][fr][quad * 8]);
        short8 pa1 = *(const short8*)(&Ps[s][fr][32 + quad * 8]);
        #pragma unroll
        for (int dn = 0; dn < 4; dn++) {
            const size_t vrow = (size_t)(dn * 16 + fr) * NTOK + kb * 64;
            short8 v0 = *(const short8*)(Vh + vrow);
            short8 v1 = *(const short8*)(Vh + vrow + 32);
            Oint[dn] = __builtin_amdgcn_mfma_f32_16x16x32_bf16(pa0, v0, Oint[dn], 0, 0, 0);
            Oint[dn] = __builtin_amdgcn_mfma_f32_16x16x32_bf16(pa1, v1, Oint[dn], 0, 0, 0);
        }
    }

    // ---- intra tile (kb == g), owned by split (popcount(um) % 4) ----
    if ((j & 3) == s) {
        f32x4 sacc[4] = {};
        #pragma unroll
        for (int t = 0; t < 4; t++) {
            const size_t krow = (size_t)(g * 64 + t * 16 + fr) * DMODEL;
            short8 kb0 = *(const short8*)(Kh + krow);
            short8 kb1 = *(const short8*)(Kh + krow + 32);
            sacc[t] = __builtin_amdgcn_mfma_f32_16x16x32_bf16(qa0, kb0, sacc[t], 0, 0, 0);
            sacc[t] = __builtin_amdgcn_mfma_f32_16x16x32_bf16(qa1, kb1, sacc[t], 0, 0, 0);
        }
        f32x4 Ointr[4] = {};
        #pragma unroll
        for (int r = 0; r < 4; r++) {
            const int qloc = qt * 16 + quad * 4 + r;   // query row in chunk
            float vv[4];
            #pragma unroll
            for (int t = 0; t < 4; t++) {
                const int col = t * 16 + fr;
                float v = sacc[t][r] * 0.125f;
                vv[t] = (col <= qloc) ? v : -INFINITY;
            }
            float mx = qmax16(fmaxf(fmaxf(vv[0], vv[1]), fmaxf(vv[2], vv[3])));
            float e0 = __expf(vv[0] - mx), e1 = __expf(vv[1] - mx);
            float e2 = __expf(vv[2] - mx), e3 = __expf(vv[3] - mx);
            float lsum = qsum16(e0 + e1 + e2 + e3);
            const int prow = quad * 4 + r;
            if (fr == 0) liS[prow] = lsum;
            Ps[s][prow][ 0 + fr] = __float2bfloat16(e0);
            Ps[s][prow][16 + fr] = __float2bfloat16(e1);
            Ps[s][prow][32 + fr] = __float2bfloat16(e2);
            Ps[s][prow][48 + fr] = __float2bfloat16(e3);
        }
        short8 pa0 = *(const short8*)(&Ps[s][fr][quad * 8]);
        short8 pa1 = *(const short8*)(&Ps[s][fr][32 + quad * 8]);
        #pragma unroll
        for (int dn = 0; dn < 4; dn++) {
            const size_t vrow = (size_t)(dn * 16 + fr) * NTOK + g * 64;
            short8 v0 = *(const short8*)(Vh + vrow);
            short8 v1 = *(const short8*)(Vh + vrow + 32);
            Ointr[dn] = __builtin_amdgcn_mfma_f32_16x16x32_bf16(pa0, v0, Ointr[dn], 0, 0, 0);
            Ointr[dn] = __builtin_amdgcn_mfma_f32_16x16x32_bf16(pa1, v1, Ointr[dn], 0, 0, 0);
        }
        #pragma unroll
        for (int r = 0; r < 4; r++)
        #pragma unroll
        for (int dn = 0; dn < 4; dn++)
            OIs[quad * 4 + r][dn * 16 + fr] = Ointr[dn][r];
    }

    // ---- publish split partials ----
    #pragma unroll
    for (int r = 0; r < 4; r++) {
        if (fr == 0) { mS[s][quad * 4 + r] = mrun[r]; lS[s][quad * 4 + r] = lrun[r]; }
        #pragma unroll
        for (int dn = 0; dn < 4; dn++)
            OS[s][quad * 4 + r][dn * 16 + fr] = Oint[dn][r];
    }
    __syncthreads();

    // ---- merge splits + gated blend, write oh bf16 ----
    {
        const int q = tid >> 4;
        const int db = (tid & 15) * 4;
        float M = fmaxf(fmaxf(mS[0][q], mS[1][q]), fmaxf(mS[2][q], mS[3][q]));
        float L = 0.f;
        float o0 = 0.f, o1 = 0.f, o2 = 0.f, o3 = 0.f;
        #pragma unroll
        for (int ss = 0; ss < 4; ss++) {
            float p = __expf(mS[ss][q] - M);
            L += lS[ss][q] * p;
            o0 += OS[ss][q][db + 0] * p;
            o1 += OS[ss][q][db + 1] * p;
            o2 += OS[ss][q][db + 2] * p;
            o3 += OS[ss][q][db + 3] * p;
        }
        const float2 gt = sgate[q];
        const float wi = gt.x / L;
        const float wl = gt.y / liS[q];
        unsigned short out4[4];
        out4[0] = __builtin_bit_cast(unsigned short, __float2bfloat16(wi * o0 + wl * OIs[q][db + 0]));
        out4[1] = __builtin_bit_cast(unsigned short, __float2bfloat16(wi * o1 + wl * OIs[q][db + 1]));
        out4[2] = __builtin_bit_cast(unsigned short, __float2bfloat16(wi * o2 + wl * OIs[q][db + 2]));
        out4[3] = __builtin_bit_cast(unsigned short, __float2bfloat16(wi * o3 + wl * OIs[q][db + 3]));
        const int n = g * 64 + qt * 16 + q;
        *(uint2*)(oh + (size_t)n * DMODEL + h * HDIM + db) = *(uint2*)out4;
    }
}

// ---------------------------------------------------------------------------
// F: Wo GEMM: C = oh x (Woh + Wol)^T, 64x64 tile, BK=64, f32 store.
// ---------------------------------------------------------------------------
__global__ __launch_bounds__(256) void gemm_wo(
    const __hip_bfloat16* __restrict__ Ah,
    const __hip_bfloat16* __restrict__ Bh, const __hip_bfloat16* __restrict__ Bl,
    float* __restrict__ C)
{
    __shared__ alignas(16) __hip_bfloat16 Ash[64][72];
    __shared__ alignas(16) __hip_bfloat16 Bsh[64][72];
    __shared__ alignas(16) __hip_bfloat16 Bsl[64][72];

    const int n0 = blockIdx.x * 64;
    const int m0 = blockIdx.y * 64;

    const int tid  = threadIdx.x;
    const int wave = tid >> 6;
    const int lane = tid & 63;
    const int lr = tid >> 2;
    const int lc = (tid & 3) * 16;
    const int wm = (wave >> 1) * 32;
    const int wn = (wave & 1) * 32;
    const int fr = lane & 15;
    const int quad = lane >> 4;

    f32x4 acc[2][2] = {};

    for (int k0 = 0; k0 < DMODEL; k0 += 64) {
        const size_t aoff = (size_t)(m0 + lr) * DMODEL + k0 + lc;
        const size_t boff = (size_t)(n0 + lr) * DMODEL + k0 + lc;
        *(uint4*)(&Ash[lr][lc])     = *(const uint4*)(Ah + aoff);
        *(uint4*)(&Ash[lr][lc + 8]) = *(const uint4*)(Ah + aoff + 8);
        *(uint4*)(&Bsh[lr][lc])     = *(const uint4*)(Bh + boff);
        *(uint4*)(&Bsh[lr][lc + 8]) = *(const uint4*)(Bh + boff + 8);
        *(uint4*)(&Bsl[lr][lc])     = *(const uint4*)(Bl + boff);
        *(uint4*)(&Bsl[lr][lc + 8]) = *(const uint4*)(Bl + boff + 8);
        __syncthreads();

        #pragma unroll
        for (int hk = 0; hk < 2; hk++) {
            const int kc0 = hk * 32 + quad * 8;
            short8 a0 = *(const short8*)(&Ash[wm + fr][kc0]);
            short8 a1 = *(const short8*)(&Ash[wm + 16 + fr][kc0]);
            short8 b0h = *(const short8*)(&Bsh[wn + fr][kc0]);
            short8 b1h = *(const short8*)(&Bsh[wn + 16 + fr][kc0]);
            short8 b0l = *(const short8*)(&Bsl[wn + fr][kc0]);
            short8 b1l = *(const short8*)(&Bsl[wn + 16 + fr][kc0]);
            acc[0][0] = __builtin_amdgcn_mfma_f32_16x16x32_bf16(a0, b0l, acc[0][0], 0, 0, 0);
            acc[0][1] = __builtin_amdgcn_mfma_f32_16x16x32_bf16(a0, b1l, acc[0][1], 0, 0, 0);
            acc[1][0] = __builtin_amdgcn_mfma_f32_16x16x32_bf16(a1, b0l, acc[1][0], 0, 0, 0);
            acc[1][1] = __builtin_amdgcn_mfma_f32_16x16x32_bf16(a1, b1l, acc[1][1], 0, 0, 0);
            acc[0][0] = __builtin_amdgcn_mfma_f32_16x16x32_bf16(a0, b0h, acc[0][0], 0, 0, 0);
            acc[0][1] = __builtin_amdgcn_mfma_f32_16x16x32_bf16(a0, b1h, acc[0][1], 0, 0, 0);
            acc[1][0] = __builtin_amdgcn_mfma_f32_16x16x32_bf16(a1, b0h, acc[1][0], 0, 0, 0);
            acc[1][1] = __builtin_amdgcn_mfma_f32_16x16x32_bf16(a1, b1h, acc[1][1], 0, 0, 0);
        }
        __syncthreads();
    }

    #pragma unroll
    for (int tm = 0; tm < 2; tm++)
    #pragma unroll
    for (int tn = 0; tn < 2; tn++)
    #pragma unroll
    for (int r = 0; r < 4; r++) {
        int row = m0 + wm + tm * 16 + quad * 4 + r;
        int col = n0 + wn + tn * 16 + fr;
        C[(size_t)row * DMODEL + col] = acc[tm][tn][r];
    }
}

// ---------------------------------------------------------------------------
extern "C" void kernel_launch(void* const* d_in, const int* in_sizes, int n_in,
                              void* d_out, int out_size, void* d_ws, size_t ws_size,
                              hipStream_t stream)
{
    const float* x  = (const float*)d_in[0];
    const float* Wq = (const float*)d_in[1];
    const float* Wk = (const float*)d_in[2];
    const float* Wv = (const float*)d_in[3];
    const float* Wg = (const float*)d_in[4];
    const float* Wo = (const float*)d_in[5];

    const size_t M1 = (size_t)NTOK * DMODEL;   // 1M elems

    // workspace layout (~24.5 MB)
    float* S       = (float*)d_ws;                    // 1 MB (scores [1024][256])
    float* xm      = S + (size_t)NTOK * 256;          // 64 KB
    float* kc      = xm + NBLK * DMODEL;              // 64 KB
    float2* gate   = (float2*)(kc + NBLK * DMODEL);   // 128 KB
    __hip_bfloat16* xh  = (__hip_bfloat16*)(gate + NTOK * NHEAD);   // 2 MB
    __hip_bfloat16* xl  = xh + M1;     // 2 MB
    __hip_bfloat16* Wqh = xl + M1;     // 2 MB
    __hip_bfloat16* Wkh = Wqh + M1;    // 2 MB
    __hip_bfloat16* Wvh = Wkh + M1;    // 2 MB
    __hip_bfloat16* Woh = Wvh + M1;    // 2 MB
    __hip_bfloat16* Wol = Woh + M1;    // 2 MB
    __hip_bfloat16* oh  = Wol + M1;    // 2 MB
    __hip_bfloat16* Uh  = oh + M1;     // 512 KB ([256][1024])
    __hip_bfloat16* Ul  = Uh + 256 * DMODEL;  // 512 KB
    __hip_bfloat16* Qb  = Ul + 256 * DMODEL;  // 2 MB  bf16 [n][D]
    __hip_bfloat16* Kb  = Qb + M1;            // 2 MB  bf16 [n][D]
    __hip_bfloat16* Vt  = Kb + M1;            // 2 MB  bf16 [f][n] (transposed)

    prep_kernel<<<6208, 256, 0, stream>>>(
        x, Wq, Wk, Wv, Wo, Wg, xh, xl, Wqh, Wkh, Wvh, Woh, Wol, xm, gate);

    kc_gemm_kernel<<<1024, 256, 0, stream>>>(xm, Wk, kc);
    u_kernel<<<256, 256, 0, stream>>>(kc, Wq, Uh, Ul);

    qkv_score_kernel<<<832, 256, 0, stream>>>(
        xh, xl, Wqh, Wkh, Wvh, Uh, Ul, Qb, Kb, Vt, S);

    attn_mfma_kernel<<<NBLK * NHEAD * 4, 256, 0, stream>>>(Qb, Kb, Vt, S, gate, oh);

    dim3 gwo(16, 16);
    gemm_wo<<<gwo, 256, 0, stream>>>(oh, Woh, Wol, (float*)d_out);
}

// Round 3
// 161.810 us; speedup vs baseline: 1.1981x; 1.1047x over previous
//
#include <hip/hip_runtime.h>
#include <hip/hip_bf16.h>
#include <math.h>

// Problem: B=1, N=1024, D=1024, H=16, C=64, TOPK=2, HD=64, G=16
//
// Round-3: GEMM staging rewritten to async global->LDS
// (__builtin_amdgcn_global_load_lds, width=16). LDS tiles are UNPADDED
// [64][64] bf16 (gload_lds needs linear dest); bank conflicts handled by the
// both-sides XOR swizzle: global SOURCE pre-swizzled per lane
// (chunk' = (lane&7) ^ ((lane>>3)&7)) and ds_read applies slot = chunk^(row&7).
// gemm_wo widened to 8 waves (512 thr) for 2 waves/SIMD. Attention unchanged
// from round 2 (split-4 waves, direct-global K/V frags, LDS merge).

typedef __attribute__((ext_vector_type(8))) short short8;   // 8 bf16 = 4 VGPRs
typedef __attribute__((ext_vector_type(4))) float f32x4;

#define NTOK 1024
#define DMODEL 1024
#define NHEAD 16
#define HDIM 64
#define CHUNK 64
#define NBLK 16

__device__ __forceinline__ float qmax16(float v)
{
    #pragma unroll
    for (int off = 1; off < 16; off <<= 1) v = fmaxf(v, __shfl_xor(v, off));
    return v;
}

__device__ __forceinline__ float qsum16(float v)
{
    #pragma unroll
    for (int off = 1; off < 16; off <<= 1) v += __shfl_xor(v, off);
    return v;
}

// ---- async-staged 64x64 bf16 tile helpers (linear LDS + XOR swizzle) ----
// LDS[row][slot] (slot = 16B chunk, 8 per 128B row) holds global chunk
// slot ^ (row & 7). Reader of logical chunk c reads slot c ^ (row & 7).

#define GLOAD_LDS16(gp, lp)                                              \
    __builtin_amdgcn_global_load_lds(                                    \
        (const __attribute__((address_space(1))) void*)(gp),             \
        (__attribute__((address_space(3))) void*)(lp), 16, 0, 0)

// 4-wave variant: wave w stages 2 KB (calls j=0,1), rows (2w+j)*8 + lane>>3.
__device__ __forceinline__ void stage64(const __hip_bfloat16* __restrict__ g0,
                                        __hip_bfloat16* t, int wave, int lane)
{
    const int sub = lane >> 3;              // row within 8-row group
    const int cch = (lane & 7) ^ sub;       // pre-swizzled source chunk
    #pragma unroll
    for (int j = 0; j < 2; j++) {
        const int rr = (2 * wave + j) * 8 + sub;
        GLOAD_LDS16(g0 + (size_t)rr * DMODEL + cch * 8, t + (2 * wave + j) * 512);
    }
}

// 8-wave variant: wave w stages 1 KB (call w), rows w*8 + lane>>3.
__device__ __forceinline__ void stage64w8(const __hip_bfloat16* __restrict__ g0,
                                          __hip_bfloat16* t, int wave, int lane)
{
    const int sub = lane >> 3;
    const int cch = (lane & 7) ^ sub;
    GLOAD_LDS16(g0 + (size_t)(wave * 8 + sub) * DMODEL + cch * 8, t + wave * 512);
}

// swizzled fragment read: logical (row, chunk) -> 16B
__device__ __forceinline__ short8 ldsfrag(const __hip_bfloat16* t, int row, int chunk)
{
    return *(const short8*)((const char*)t + row * 128 + (((chunk) ^ (row & 7)) << 4));
}

// ---------------------------------------------------------------------------
// A: prep. blockIdx roles: [0,5120) casts (which = bid>>10: 0 x split,
// 1 Wq hi, 2 Wk hi, 3 Wv hi, 4 Wo split), [5120,5184) xm, [5184,6208) gate.
// ---------------------------------------------------------------------------
__global__ __launch_bounds__(256) void prep_kernel(
    const float* __restrict__ x,  const float* __restrict__ Wq,
    const float* __restrict__ Wk, const float* __restrict__ Wv,
    const float* __restrict__ Wo, const float* __restrict__ Wg,
    __hip_bfloat16* __restrict__ xh,  __hip_bfloat16* __restrict__ xl,
    __hip_bfloat16* __restrict__ Wqh,
    __hip_bfloat16* __restrict__ Wkh, __hip_bfloat16* __restrict__ Wvh,
    __hip_bfloat16* __restrict__ Woh, __hip_bfloat16* __restrict__ Wol,
    float* __restrict__ xm, float2* __restrict__ gate)
{
    __shared__ float gs[32];
    const int bid = blockIdx.x;
    if (bid < 5120) {
        const int which = bid >> 10;
        const int b = bid & 1023;
        const int i = (b * 256 + threadIdx.x) * 4;
        const float* in; __hip_bfloat16 *hi, *lo = nullptr;
        if (which == 0)      { in = x;  hi = xh;  lo = xl; }
        else if (which == 1) { in = Wq; hi = Wqh; }
        else if (which == 2) { in = Wk; hi = Wkh; }
        else if (which == 3) { in = Wv; hi = Wvh; }
        else                 { in = Wo; hi = Woh; lo = Wol; }
        float4 v = *(const float4*)(in + i);
        float vv[4] = {v.x, v.y, v.z, v.w};
        __hip_bfloat16 h[4], l[4];
        #pragma unroll
        for (int j = 0; j < 4; j++) {
            h[j] = __float2bfloat16(vv[j]);
            l[j] = __float2bfloat16(vv[j] - __bfloat162float(h[j]));
        }
        *(uint2*)(hi + i) = *(uint2*)h;
        if (lo) *(uint2*)(lo + i) = *(uint2*)l;
    } else if (bid < 5184) {
        const int b = bid - 5120;
        const int g = b >> 2;
        const int f = (b & 3) * 256 + threadIdx.x;
        float s = 0.f;
        #pragma unroll 8
        for (int c = 0; c < CHUNK; c++) s += x[(size_t)(g * CHUNK + c) * DMODEL + f];
        xm[g * DMODEL + f] = s * (1.0f / CHUNK);
    } else {
        const int n = bid - 5184;
        const int wave = threadIdx.x >> 6, lane = threadIdx.x & 63;
        #pragma unroll
        for (int jj = 0; jj < 8; jj++) {
            int j = wave * 8 + jj;
            float s = 0.f;
            #pragma unroll
            for (int t = 0; t < 16; t++) {
                int d = lane + (t << 6);
                s += x[n * DMODEL + d] * Wg[j * DMODEL + d];
            }
            #pragma unroll
            for (int off = 32; off; off >>= 1) s += __shfl_xor(s, off);
            if (lane == 0) gs[j] = s;
        }
        __syncthreads();
        if (threadIdx.x < NHEAD) {
            int h = threadIdx.x;
            float a = gs[2 * h], b = gs[2 * h + 1];
            float m = fmaxf(a, b);
            float ea = expf(a - m), eb = expf(b - m);
            float inv = 1.f / (ea + eb);
            gate[n * NHEAD + h] = make_float2(ea * inv, eb * inv);
        }
    }
}

// ---------------------------------------------------------------------------
// B: kc = xm @ Wk^T (exact f32). One block per f; (g = tid>>4, sub = tid&15).
// ---------------------------------------------------------------------------
__global__ __launch_bounds__(256) void kc_gemm_kernel(
    const float* __restrict__ xm, const float* __restrict__ Wk,
    float* __restrict__ kc)
{
    const int f = blockIdx.x;
    const int g = threadIdx.x >> 4;
    const int sub = threadIdx.x & 15;
    const float* wrow = Wk + (size_t)f * DMODEL;
    float s = 0.f;
    #pragma unroll 16
    for (int i = 0; i < 64; i++) {
        int e = i * 16 + sub;
        s += xm[g * DMODEL + e] * wrow[e];
    }
    #pragma unroll
    for (int off = 8; off; off >>= 1) s += __shfl_xor(s, off);
    if (sub == 0) kc[g * DMODEL + f] = s;
}

// ---------------------------------------------------------------------------
// C: U[(h<<4)|g][f] = sum_d kc[g][h*64+d] * Wq[h*64+d][f]  (exact f32),
// then split to bf16 hi/lo rows Uh/Ul [256][1024].
// ---------------------------------------------------------------------------
__global__ __launch_bounds__(256) void u_kernel(
    const float* __restrict__ kc, const float* __restrict__ Wq,
    __hip_bfloat16* __restrict__ Uh, __hip_bfloat16* __restrict__ Ul)
{
    __shared__ float kcs[64];
    const int h = blockIdx.x >> 4, g = blockIdx.x & 15;
    if (threadIdx.x < 64) kcs[threadIdx.x] = kc[g * DMODEL + h * HDIM + threadIdx.x];
    __syncthreads();
    const int col = (h << 4) | g;
    for (int f = threadIdx.x; f < DMODEL; f += 256) {
        float s = 0.f;
        #pragma unroll 16
        for (int d = 0; d < 64; d++)
            s += kcs[d] * Wq[(size_t)(h * HDIM + d) * DMODEL + f];
        __hip_bfloat16 hv = __float2bfloat16(s);
        Uh[(size_t)col * DMODEL + f] = hv;
        Ul[(size_t)col * DMODEL + f] = __float2bfloat16(s - __bfloat162float(hv));
    }
}

// ---------------------------------------------------------------------------
// D: qkv GEMMs (blocks [0,768), BK=64, plain bf16) + score GEMM (blocks
// [768,832): S[1024][256] = (xh+xl) @ (Uh+Ul)^T, 3-term split).
// Staging via global_load_lds (16B) into linear [64][64] tiles + XOR swizzle.
// Epilogues: Q,K -> bf16 [n][D]; V -> bf16 transposed Vt[f][n] via LDS.
// ---------------------------------------------------------------------------
__global__ __launch_bounds__(256) void qkv_score_kernel(
    const __hip_bfloat16* __restrict__ xh, const __hip_bfloat16* __restrict__ xl,
    const __hip_bfloat16* __restrict__ Wqh, const __hip_bfloat16* __restrict__ Wkh,
    const __hip_bfloat16* __restrict__ Wvh,
    const __hip_bfloat16* __restrict__ Uh, const __hip_bfloat16* __restrict__ Ul,
    __hip_bfloat16* __restrict__ Qb, __hip_bfloat16* __restrict__ Kb,
    __hip_bfloat16* __restrict__ Vt, float* __restrict__ S)
{
    __shared__ alignas(16) char smem[32768];    // 4 x 8KB unpadded tiles
    __hip_bfloat16* AshP = (__hip_bfloat16*)smem;
    __hip_bfloat16* AslP = (__hip_bfloat16*)(smem + 8192);
    __hip_bfloat16* BshP = (__hip_bfloat16*)(smem + 16384);
    __hip_bfloat16* BslP = (__hip_bfloat16*)(smem + 24576);

    const int b = blockIdx.x;
    const int tid  = threadIdx.x;
    const int wave = tid >> 6;
    const int lane = tid & 63;
    const int lr = tid >> 2;
    const int lc = (tid & 3) * 16;
    const int wm = (wave >> 1) * 32;
    const int wn = (wave & 1) * 32;
    const int fr = lane & 15;
    const int quad = lane >> 4;

    if (b < 768) {
        // ---- QKV GEMM (plain bf16), A + B staged async ----
        const int widx = b >> 8;
        const int t = b & 255;
        const __hip_bfloat16* __restrict__ Bh =
            (widx == 0) ? Wqh : (widx == 1) ? Wkh : Wvh;
        const int n0 = (t & 15) * 64;
        const int m0 = (t >> 4) * 64;

        f32x4 acc[2][2] = {};

        for (int k0 = 0; k0 < DMODEL; k0 += 64) {
            stage64(xh + (size_t)m0 * DMODEL + k0, AshP, wave, lane);
            stage64(Bh + (size_t)n0 * DMODEL + k0, BshP, wave, lane);
            __syncthreads();

            #pragma unroll
            for (int hk = 0; hk < 2; hk++) {
                const int ch = hk * 4 + quad;
                short8 a0 = ldsfrag(AshP, wm + fr, ch);
                short8 a1 = ldsfrag(AshP, wm + 16 + fr, ch);
                short8 b0 = ldsfrag(BshP, wn + fr, ch);
                short8 b1 = ldsfrag(BshP, wn + 16 + fr, ch);
                acc[0][0] = __builtin_amdgcn_mfma_f32_16x16x32_bf16(a0, b0, acc[0][0], 0, 0, 0);
                acc[0][1] = __builtin_amdgcn_mfma_f32_16x16x32_bf16(a0, b1, acc[0][1], 0, 0, 0);
                acc[1][0] = __builtin_amdgcn_mfma_f32_16x16x32_bf16(a1, b0, acc[1][0], 0, 0, 0);
                acc[1][1] = __builtin_amdgcn_mfma_f32_16x16x32_bf16(a1, b1, acc[1][1], 0, 0, 0);
            }
            __syncthreads();
        }

        if (widx == 0) {
            #pragma unroll
            for (int tm = 0; tm < 2; tm++)
            #pragma unroll
            for (int tn = 0; tn < 2; tn++)
            #pragma unroll
            for (int r = 0; r < 4; r++) {
                int row = m0 + wm + tm * 16 + quad * 4 + r;
                int col = n0 + wn + tn * 16 + fr;
                Qb[(size_t)row * DMODEL + col] = __float2bfloat16(acc[tm][tn][r]);
            }
        } else if (widx == 1) {
            #pragma unroll
            for (int tm = 0; tm < 2; tm++)
            #pragma unroll
            for (int tn = 0; tn < 2; tn++)
            #pragma unroll
            for (int r = 0; r < 4; r++) {
                int row = m0 + wm + tm * 16 + quad * 4 + r;
                int col = n0 + wn + tn * 16 + fr;
                Kb[(size_t)row * DMODEL + col] = __float2bfloat16(acc[tm][tn][r]);
            }
        } else {
            // V: transpose 64x64 tile through LDS, store Vt[f][n] coalesced.
            __hip_bfloat16 (*T)[72] = (__hip_bfloat16(*)[72])smem;
            #pragma unroll
            for (int tm = 0; tm < 2; tm++)
            #pragma unroll
            for (int tn = 0; tn < 2; tn++)
            #pragma unroll
            for (int r = 0; r < 4; r++) {
                int nloc = wm + tm * 16 + quad * 4 + r;
                int floc = wn + tn * 16 + fr;
                T[floc][nloc] = __float2bfloat16(acc[tm][tn][r]);
            }
            __syncthreads();
            const size_t o = (size_t)(n0 + lr) * NTOK + m0 + lc;
            *(uint4*)(Vt + o)     = *(uint4*)(&T[lr][lc]);
            *(uint4*)(Vt + o + 8) = *(uint4*)(&T[lr][lc + 8]);
        }
    } else {
        // ---- score GEMM: S = (xh+xl) @ (Uh+Ul)^T, 3-term split ----
        const int bb = b - 768;                 // [0,64)
        const int m0 = (bb >> 2) * 64;          // 16 token tiles
        const int n0 = (bb & 3) * 64;           // 4 col tiles (256 cols)

        f32x4 acc[2][2] = {};

        for (int k0 = 0; k0 < DMODEL; k0 += 64) {
            stage64(xh + (size_t)m0 * DMODEL + k0, AshP, wave, lane);
            stage64(xl + (size_t)m0 * DMODEL + k0, AslP, wave, lane);
            stage64(Uh + (size_t)n0 * DMODEL + k0, BshP, wave, lane);
            stage64(Ul + (size_t)n0 * DMODEL + k0, BslP, wave, lane);
            __syncthreads();

            #pragma unroll
            for (int hk = 0; hk < 2; hk++) {
                const int ch = hk * 4 + quad;
                short8 a0h = ldsfrag(AshP, wm + fr, ch);
                short8 a1h = ldsfrag(AshP, wm + 16 + fr, ch);
                short8 a0l = ldsfrag(AslP, wm + fr, ch);
                short8 a1l = ldsfrag(AslP, wm + 16 + fr, ch);
                short8 b0h = ldsfrag(BshP, wn + fr, ch);
                short8 b1h = ldsfrag(BshP, wn + 16 + fr, ch);
                short8 b0l = ldsfrag(BslP, wn + fr, ch);
                short8 b1l = ldsfrag(BslP, wn + 16 + fr, ch);
                acc[0][0] = __builtin_amdgcn_mfma_f32_16x16x32_bf16(a0l, b0h, acc[0][0], 0, 0, 0);
                acc[0][1] = __builtin_amdgcn_mfma_f32_16x16x32_bf16(a0l, b1h, acc[0][1], 0, 0, 0);
                acc[1][0] = __builtin_amdgcn_mfma_f32_16x16x32_bf16(a1l, b0h, acc[1][0], 0, 0, 0);
                acc[1][1] = __builtin_amdgcn_mfma_f32_16x16x32_bf16(a1l, b1h, acc[1][1], 0, 0, 0);
                acc[0][0] = __builtin_amdgcn_mfma_f32_16x16x32_bf16(a0h, b0l, acc[0][0], 0, 0, 0);
                acc[0][1] = __builtin_amdgcn_mfma_f32_16x16x32_bf16(a0h, b1l, acc[0][1], 0, 0, 0);
                acc[1][0] = __builtin_amdgcn_mfma_f32_16x16x32_bf16(a1h, b0l, acc[1][0], 0, 0, 0);
                acc[1][1] = __builtin_amdgcn_mfma_f32_16x16x32_bf16(a1h, b1l, acc[1][1], 0, 0, 0);
                acc[0][0] = __builtin_amdgcn_mfma_f32_16x16x32_bf16(a0h, b0h, acc[0][0], 0, 0, 0);
                acc[0][1] = __builtin_amdgcn_mfma_f32_16x16x32_bf16(a0h, b1h, acc[0][1], 0, 0, 0);
                acc[1][0] = __builtin_amdgcn_mfma_f32_16x16x32_bf16(a1h, b0h, acc[1][0], 0, 0, 0);
                acc[1][1] = __builtin_amdgcn_mfma_f32_16x16x32_bf16(a1h, b1h, acc[1][1], 0, 0, 0);
            }
            __syncthreads();
        }

        #pragma unroll
        for (int tm = 0; tm < 2; tm++)
        #pragma unroll
        for (int tn = 0; tn < 2; tn++)
        #pragma unroll
        for (int r = 0; r < 4; r++) {
            int row = m0 + wm + tm * 16 + quad * 4 + r;
            int col = n0 + wn + tn * 16 + fr;
            S[(size_t)row * 256 + col] = acc[tm][tn][r];
        }
    }
}

// ---------------------------------------------------------------------------
// E: split-K MFMA attention (unchanged from round 2). Grid = (g,h,qtile) =
// 1024 blocks x 4 waves; wave s processes every 4th entry of the union block
// list; K/V frags direct from global; LDS merge with exact softmax combine.
// ---------------------------------------------------------------------------
__global__ __launch_bounds__(256, 4) void attn_mfma_kernel(
    const __hip_bfloat16* __restrict__ Qb, const __hip_bfloat16* __restrict__ Kb,
    const __hip_bfloat16* __restrict__ Vt, const float* __restrict__ S,
    const float2* __restrict__ gate, __hip_bfloat16* __restrict__ oh)
{
    __shared__ float OS[4][16][64];     // per-split inter partial O
    __shared__ float OIs[16][64];       // intra O
    __shared__ float mS[4][16], lS[4][16], liS[16];
    __shared__ int i1s[16], i2s[16];
    __shared__ float2 sgate[16];
    __shared__ unsigned unionMask;
    __shared__ __hip_bfloat16 Ps[4][16][72];   // per-wave P round-trip

    const int bid = blockIdx.x;
    const int qt = bid & 3;
    const int h  = (bid >> 2) & 15;
    const int g  = bid >> 6;
    const int tid = threadIdx.x;
    const int s = tid >> 6;             // wave = key-split id
    const int lane = tid & 63;
    const int fr = lane & 15, quad = lane >> 4;

    // ---- prologue: per-query top-2 (exact tie semantics), gate, union ----
    if (tid < 16) {
        const int n = g * 64 + qt * 16 + tid;
        const float* Sn = S + (size_t)n * 256 + h * 16;
        float sc[NBLK];
        #pragma unroll
        for (int gg = 0; gg < NBLK; gg++)
            sc[gg] = (n >= (gg << 6)) ? -INFINITY : Sn[gg];
        int i1 = -1, i2 = -1;
        float b1 = -INFINITY;
        #pragma unroll
        for (int gg = 0; gg < NBLK; gg++) if (i1 < 0 || sc[gg] > b1) { b1 = sc[gg]; i1 = gg; }
        float b2 = -INFINITY;
        #pragma unroll
        for (int gg = 0; gg < NBLK; gg++) { if (gg == i1) continue; if (i2 < 0 || sc[gg] > b2) { b2 = sc[gg]; i2 = gg; } }
        i1s[tid] = i1; i2s[tid] = i2;
        sgate[tid] = gate[(size_t)n * NHEAD + h];
        unsigned m = (1u << i1) | (1u << i2);
        #pragma unroll
        for (int off = 1; off < 16; off <<= 1) m |= (unsigned)__shfl_xor((int)m, off);
        if (tid == 0) unionMask = m;
    }
    __syncthreads();

    const unsigned um = unionMask;

    // ---- Q A-fragments direct from global ----
    const size_t qrow = (size_t)(g * 64 + qt * 16 + fr) * DMODEL + h * HDIM + quad * 8;
    const short8 qa0 = *(const short8*)(Qb + qrow);
    const short8 qa1 = *(const short8*)(Qb + qrow + 32);

    // per-lane copies of top-2 / gate for this quad's 4 query rows
    int qi1[4], qi2[4];
    #pragma unroll
    for (int r = 0; r < 4; r++) {
        int q = quad * 4 + r;
        qi1[r] = i1s[q]; qi2[r] = i2s[q];
    }

    f32x4 Oint[4] = {};        // inter accumulator (16q x 64d)
    float mrun[4] = {-INFINITY, -INFINITY, -INFINITY, -INFINITY};
    float lrun[4] = {0.f, 0.f, 0.f, 0.f};

    const __hip_bfloat16* __restrict__ Kh = Kb + h * HDIM + quad * 8;
    const __hip_bfloat16* __restrict__ Vh = Vt + (size_t)(h * HDIM) * NTOK + quad * 8;

    int j = 0;
    for (int kb = 0; kb < NBLK; kb++) {
        if (!((um >> kb) & 1u)) continue;
        if ((j++ & 3) != s) continue;

        // ---- QK^T: 16q x 64k, K frags direct from global ----
        f32x4 sacc[4] = {};
        #pragma unroll
        for (int t = 0; t < 4; t++) {
            const size_t krow = (size_t)(kb * 64 + t * 16 + fr) * DMODEL;
            short8 kb0 = *(const short8*)(Kh + krow);
            short8 kb1 = *(const short8*)(Kh + krow + 32);
            sacc[t] = __builtin_amdgcn_mfma_f32_16x16x32_bf16(qa0, kb0, sacc[t], 0, 0, 0);
            sacc[t] = __builtin_amdgcn_mfma_f32_16x16x32_bf16(qa1, kb1, sacc[t], 0, 0, 0);
        }

        // ---- inter online softmax, per-query selected-block gating ----
        #pragma unroll
        for (int r = 0; r < 4; r++) {
            const bool sel = (kb == qi1[r]) | (kb == qi2[r]);   // quad-uniform
            float v0 = sacc[0][r] * 0.125f, v1 = sacc[1][r] * 0.125f;
            float v2 = sacc[2][r] * 0.125f, v3 = sacc[3][r] * 0.125f;
            float mx = qmax16(fmaxf(fmaxf(v0, v1), fmaxf(v2, v3)));
            float mnew = sel ? fmaxf(mrun[r], mx) : mrun[r];
            float f = sel ? __expf(mrun[r] - mnew) : 1.0f;
            float e0 = sel ? __expf(v0 - mnew) : 0.f;
            float e1 = sel ? __expf(v1 - mnew) : 0.f;
            float e2 = sel ? __expf(v2 - mnew) : 0.f;
            float e3 = sel ? __expf(v3 - mnew) : 0.f;
            float es = qsum16(e0 + e1 + e2 + e3);
            lrun[r] = lrun[r] * f + es;
            mrun[r] = mnew;
            #pragma unroll
            for (int dn = 0; dn < 4; dn++) Oint[dn][r] *= f;
            const int prow = quad * 4 + r;
            Ps[s][prow][ 0 + fr] = __float2bfloat16(e0);
            Ps[s][prow][16 + fr] = __float2bfloat16(e1);
            Ps[s][prow][32 + fr] = __float2bfloat16(e2);
            Ps[s][prow][48 + fr] = __float2bfloat16(e3);
        }

        // ---- PV: O += P @ V, V frags direct from global ----
        short8 pa0 = *(const short8*)(&Ps[s][fr][quad * 8]);
        short8 pa1 = *(const short8*)(&Ps[s][fr][32 + quad * 8]);
        #pragma unroll
        for (int dn = 0; dn < 4; dn++) {
            const size_t vrow = (size_t)(dn * 16 + fr) * NTOK + kb * 64;
            short8 v0 = *(const short8*)(Vh + vrow);
            short8 v1 = *(const short8*)(Vh + vrow + 32);
            Oint[dn] = __builtin_amdgcn_mfma_f32_16x16x32_bf16(pa0, v0, Oint[dn], 0, 0, 0);
            Oint[dn] = __builtin_amdgcn_mfma_f32_16x16x32_bf16(pa1, v1, Oint[dn], 0, 0, 0);
        }
    }

    // ---- intra tile (kb == g), owned by split (popcount(um) % 4) ----
    if ((j & 3) == s) {
        f32x4 sacc[4] = {};
        #pragma unroll
        for (int t = 0; t < 4; t++) {
            const size_t krow = (size_t)(g * 64 + t * 16 + fr) * DMODEL;
            short8 kb0 = *(const short8*)(Kh + krow);
            short8 kb1 = *(const short8*)(Kh + krow + 32);
            sacc[t] = __builtin_amdgcn_mfma_f32_16x16x32_bf16(qa0, kb0, sacc[t], 0, 0, 0);
            sacc[t] = __builtin_amdgcn_mfma_f32_16x16x32_bf16(qa1, kb1, sacc[t], 0, 0, 0);
        }
        f32x4 Ointr[4] = {};
        #pragma unroll
        for (int r = 0; r < 4; r++) {
            const int qloc = qt * 16 + quad * 4 + r;   // query row in chunk
            float vv[4];
            #pragma unroll
            for (int t = 0; t < 4; t++) {
                const int col = t * 16 + fr;
                float v = sacc[t][r] * 0.125f;
                vv[t] = (col <= qloc) ? v : -INFINITY;
            }
            float mx = qmax16(fmaxf(fmaxf(vv[0], vv[1]), fmaxf(vv[2], vv[3])));
            float e0 = __expf(vv[0] - mx), e1 = __expf(vv[1] - mx);
            float e2 = __expf(vv[2] - mx), e3 = __expf(vv[3] - mx);
            float lsum = qsum16(e0 + e1 + e2 + e3);
            const int prow = quad * 4 + r;
            if (fr == 0) liS[prow] = lsum;
            Ps[s][prow][ 0 + fr] = __float2bfloat16(e0);
            Ps[s][prow][16 + fr] = __float2bfloat16(e1);
            Ps[s][prow][32 + fr] = __float2bfloat16(e2);
            Ps[s][prow][48 + fr] = __float2bfloat16(e3);
        }
        short8 pa0 = *(const short8*)(&Ps[s][fr][quad * 8]);
        short8 pa1 = *(const short8*)(&Ps[s][fr][32 + quad * 8]);
        f32x4 Ointr2[4] = {};
        #pragma unroll
        for (int dn = 0; dn < 4; dn++) {
            const size_t vrow = (size_t)(dn * 16 + fr) * NTOK + g * 64;
            short8 v0 = *(const short8*)(Vh + vrow);
            short8 v1 = *(const short8*)(Vh + vrow + 32);
            Ointr2[dn] = __builtin_amdgcn_mfma_f32_16x16x32_bf16(pa0, v0, Ointr[dn], 0, 0, 0);
            Ointr2[dn] = __builtin_amdgcn_mfma_f32_16x16x32_bf16(pa1, v1, Ointr2[dn], 0, 0, 0);
        }
        #pragma unroll
        for (int r = 0; r < 4; r++)
        #pragma unroll
        for (int dn = 0; dn < 4; dn++)
            OIs[quad * 4 + r][dn * 16 + fr] = Ointr2[dn][r];
    }

    // ---- publish split partials ----
    #pragma unroll
    for (int r = 0; r < 4; r++) {
        if (fr == 0) { mS[s][quad * 4 + r] = mrun[r]; lS[s][quad * 4 + r] = lrun[r]; }
        #pragma unroll
        for (int dn = 0; dn < 4; dn++)
            OS[s][quad * 4 + r][dn * 16 + fr] = Oint[dn][r];
    }
    __syncthreads();

    // ---- merge splits + gated blend, write oh bf16 ----
    {
        const int q = tid >> 4;
        const int db = (tid & 15) * 4;
        float M = fmaxf(fmaxf(mS[0][q], mS[1][q]), fmaxf(mS[2][q], mS[3][q]));
        float L = 0.f;
        float o0 = 0.f, o1 = 0.f, o2 = 0.f, o3 = 0.f;
        #pragma unroll
        for (int ss = 0; ss < 4; ss++) {
            float p = __expf(mS[ss][q] - M);
            L += lS[ss][q] * p;
            o0 += OS[ss][q][db + 0] * p;
            o1 += OS[ss][q][db + 1] * p;
            o2 += OS[ss][q][db + 2] * p;
            o3 += OS[ss][q][db + 3] * p;
        }
        const float2 gt = sgate[q];
        const float wi = gt.x / L;
        const float wl = gt.y / liS[q];
        unsigned short out4[4];
        out4[0] = __builtin_bit_cast(unsigned short, __float2bfloat16(wi * o0 + wl * OIs[q][db + 0]));
        out4[1] = __builtin_bit_cast(unsigned short, __float2bfloat16(wi * o1 + wl * OIs[q][db + 1]));
        out4[2] = __builtin_bit_cast(unsigned short, __float2bfloat16(wi * o2 + wl * OIs[q][db + 2]));
        out4[3] = __builtin_bit_cast(unsigned short, __float2bfloat16(wi * o3 + wl * OIs[q][db + 3]));
        const int n = g * 64 + qt * 16 + q;
        *(uint2*)(oh + (size_t)n * DMODEL + h * HDIM + db) = *(uint2*)out4;
    }
}

// ---------------------------------------------------------------------------
// F: Wo GEMM: C = oh x (Woh + Wol)^T, 64x64 tile, BK=64, f32 store.
// 8 waves (512 thr) for 2 waves/SIMD; async staging, 3 tiles (A, Bh, Bl).
// ---------------------------------------------------------------------------
__global__ __launch_bounds__(512) void gemm_wo(
    const __hip_bfloat16* __restrict__ Ah,
    const __hip_bfloat16* __restrict__ Bh, const __hip_bfloat16* __restrict__ Bl,
    float* __restrict__ C)
{
    __shared__ alignas(16) char smem[24576];
    __hip_bfloat16* AshP = (__hip_bfloat16*)smem;
    __hip_bfloat16* BshP = (__hip_bfloat16*)(smem + 8192);
    __hip_bfloat16* BslP = (__hip_bfloat16*)(smem + 16384);

    const int n0 = blockIdx.x * 64;
    const int m0 = blockIdx.y * 64;

    const int tid  = threadIdx.x;
    const int wave = tid >> 6;          // 0..7
    const int lane = tid & 63;
    const int wm = (wave >> 1) * 16;    // {0,16,32,48}
    const int wn = (wave & 1) * 32;     // {0,32}
    const int fr = lane & 15;
    const int quad = lane >> 4;

    f32x4 acc[2] = {};

    for (int k0 = 0; k0 < DMODEL; k0 += 64) {
        stage64w8(Ah + (size_t)m0 * DMODEL + k0, AshP, wave, lane);
        stage64w8(Bh + (size_t)n0 * DMODEL + k0, BshP, wave, lane);
        stage64w8(Bl + (size_t)n0 * DMODEL + k0, BslP, wave, lane);
        __syncthreads();

        #pragma unroll
        for (int hk = 0; hk < 2; hk++) {
            const int ch = hk * 4 + quad;
            short8 a0  = ldsfrag(AshP, wm + fr, ch);
            short8 b0h = ldsfrag(BshP, wn + fr, ch);
            short8 b1h = ldsfrag(BshP, wn + 16 + fr, ch);
            short8 b0l = ldsfrag(BslP, wn + fr, ch);
            short8 b1l = ldsfrag(BslP, wn + 16 + fr, ch);
            acc[0] = __builtin_amdgcn_mfma_f32_16x16x32_bf16(a0, b0l, acc[0], 0, 0, 0);
            acc[1] = __builtin_amdgcn_mfma_f32_16x16x32_bf16(a0, b1l, acc[1], 0, 0, 0);
            acc[0] = __builtin_amdgcn_mfma_f32_16x16x32_bf16(a0, b0h, acc[0], 0, 0, 0);
            acc[1] = __builtin_amdgcn_mfma_f32_16x16x32_bf16(a0, b1h, acc[1], 0, 0, 0);
        }
        __syncthreads();
    }

    #pragma unroll
    for (int tn = 0; tn < 2; tn++)
    #pragma unroll
    for (int r = 0; r < 4; r++) {
        int row = m0 + wm + quad * 4 + r;
        int col = n0 + wn + tn * 16 + fr;
        C[(size_t)row * DMODEL + col] = acc[tn][r];
    }
}

// ---------------------------------------------------------------------------
extern "C" void kernel_launch(void* const* d_in, const int* in_sizes, int n_in,
                              void* d_out, int out_size, void* d_ws, size_t ws_size,
                              hipStream_t stream)
{
    const float* x  = (const float*)d_in[0];
    const float* Wq = (const float*)d_in[1];
    const float* Wk = (const float*)d_in[2];
    const float* Wv = (const float*)d_in[3];
    const float* Wg = (const float*)d_in[4];
    const float* Wo = (const float*)d_in[5];

    const size_t M1 = (size_t)NTOK * DMODEL;   // 1M elems

    // workspace layout (~24.5 MB)
    float* S       = (float*)d_ws;                    // 1 MB (scores [1024][256])
    float* xm      = S + (size_t)NTOK * 256;          // 64 KB
    float* kc      = xm + NBLK * DMODEL;              // 64 KB
    float2* gate   = (float2*)(kc + NBLK * DMODEL);   // 128 KB
    __hip_bfloat16* xh  = (__hip_bfloat16*)(gate + NTOK * NHEAD);   // 2 MB
    __hip_bfloat16* xl  = xh + M1;     // 2 MB
    __hip_bfloat16* Wqh = xl + M1;     // 2 MB
    __hip_bfloat16* Wkh = Wqh + M1;    // 2 MB
    __hip_bfloat16* Wvh = Wkh + M1;    // 2 MB
    __hip_bfloat16* Woh = Wvh + M1;    // 2 MB
    __hip_bfloat16* Wol = Woh + M1;    // 2 MB
    __hip_bfloat16* oh  = Wol + M1;    // 2 MB
    __hip_bfloat16* Uh  = oh + M1;     // 512 KB ([256][1024])
    __hip_bfloat16* Ul  = Uh + 256 * DMODEL;  // 512 KB
    __hip_bfloat16* Qb  = Ul + 256 * DMODEL;  // 2 MB  bf16 [n][D]
    __hip_bfloat16* Kb  = Qb + M1;            // 2 MB  bf16 [n][D]
    __hip_bfloat16* Vt  = Kb + M1;            // 2 MB  bf16 [f][n] (transposed)

    prep_kernel<<<6208, 256, 0, stream>>>(
        x, Wq, Wk, Wv, Wo, Wg, xh, xl, Wqh, Wkh, Wvh, Woh, Wol, xm, gate);

    kc_gemm_kernel<<<1024, 256, 0, stream>>>(xm, Wk, kc);
    u_kernel<<<256, 256, 0, stream>>>(kc, Wq, Uh, Ul);

    qkv_score_kernel<<<832, 256, 0, stream>>>(
        xh, xl, Wqh, Wkh, Wvh, Uh, Ul, Qb, Kb, Vt, S);

    attn_mfma_kernel<<<NBLK * NHEAD * 4, 256, 0, stream>>>(Qb, Kb, Vt, S, gate, oh);

    dim3 gwo(16, 16);
    gemm_wo<<<gwo, 512, 0, stream>>>(oh, Woh, Wol, (float*)d_out);
}

// Round 4
// 158.931 us; speedup vs baseline: 1.2198x; 1.0181x over previous
//
#include <hip/hip_runtime.h>
#include <hip/hip_bf16.h>
#include <math.h>

// Problem: B=1, N=1024, D=1024, H=16, C=64, TOPK=2, HD=64, G=16
//
// Round-4: QKV GEMM rebuilt as 128x128 tiles (m97-class): fused N over
// {Wq,Wk,Wv} -> 192 blocks, acc[4][4]/wave (32 MFMA / 16 ds_read per K-step),
// double-buffered LDS with 2-phase schedule (stage next tile BEFORE compute,
// one barrier per K-step). K-accumulation order identical to round-3 ->
// bit-identical outputs. V epilogue transposes 128^2 via LDS in two 64-col
// passes. Score GEMM (64 blocks) and all other kernels unchanged.

typedef __attribute__((ext_vector_type(8))) short short8;   // 8 bf16 = 4 VGPRs
typedef __attribute__((ext_vector_type(4))) float f32x4;

#define NTOK 1024
#define DMODEL 1024
#define NHEAD 16
#define HDIM 64
#define CHUNK 64
#define NBLK 16

__device__ __forceinline__ float qmax16(float v)
{
    #pragma unroll
    for (int off = 1; off < 16; off <<= 1) v = fmaxf(v, __shfl_xor(v, off));
    return v;
}

__device__ __forceinline__ float qsum16(float v)
{
    #pragma unroll
    for (int off = 1; off < 16; off <<= 1) v += __shfl_xor(v, off);
    return v;
}

// ---- async-staged bf16 tile helpers (linear LDS + XOR swizzle) ----
// LDS[row][slot] (slot = 16B chunk, 8 per 128B row) holds global chunk
// slot ^ (row & 7). Reader of logical chunk c reads slot c ^ (row & 7).

#define GLOAD_LDS16(gp, lp)                                              \
    __builtin_amdgcn_global_load_lds(                                    \
        (const __attribute__((address_space(1))) void*)(gp),             \
        (__attribute__((address_space(3))) void*)(lp), 16, 0, 0)

// 64-row tile, 4 waves: wave w stages rows [w*16, w*16+16).
__device__ __forceinline__ void stage64(const __hip_bfloat16* __restrict__ g0,
                                        __hip_bfloat16* t, int wave, int lane)
{
    const int sub = lane >> 3;              // row within 8-row group
    const int cch = (lane & 7) ^ sub;       // pre-swizzled source chunk
    #pragma unroll
    for (int j = 0; j < 2; j++) {
        const int rr = (2 * wave + j) * 8 + sub;
        GLOAD_LDS16(g0 + (size_t)rr * DMODEL + cch * 8, t + (2 * wave + j) * 512);
    }
}

// 128-row tile, 4 waves: wave w stages rows [w*32, w*32+32) (4 calls).
__device__ __forceinline__ void stage128(const __hip_bfloat16* __restrict__ g0,
                                         __hip_bfloat16* t, int wave, int lane)
{
    const int sub = lane >> 3;
    const int cch = (lane & 7) ^ sub;
    #pragma unroll
    for (int j = 0; j < 4; j++) {
        const int grp = wave * 4 + j;
        GLOAD_LDS16(g0 + (size_t)(grp * 8 + sub) * DMODEL + cch * 8, t + grp * 512);
    }
}

// 64-row tile, 8 waves: wave w stages rows [w*8, w*8+8).
__device__ __forceinline__ void stage64w8(const __hip_bfloat16* __restrict__ g0,
                                          __hip_bfloat16* t, int wave, int lane)
{
    const int sub = lane >> 3;
    const int cch = (lane & 7) ^ sub;
    GLOAD_LDS16(g0 + (size_t)(wave * 8 + sub) * DMODEL + cch * 8, t + wave * 512);
}

// swizzled fragment read: logical (row, chunk) -> 16B
__device__ __forceinline__ short8 ldsfrag(const __hip_bfloat16* t, int row, int chunk)
{
    return *(const short8*)((const char*)t + row * 128 + (((chunk) ^ (row & 7)) << 4));
}

// ---------------------------------------------------------------------------
// A: prep. blockIdx roles: [0,5120) casts (which = bid>>10: 0 x split,
// 1 Wq hi, 2 Wk hi, 3 Wv hi, 4 Wo split), [5120,5184) xm, [5184,6208) gate.
// ---------------------------------------------------------------------------
__global__ __launch_bounds__(256) void prep_kernel(
    const float* __restrict__ x,  const float* __restrict__ Wq,
    const float* __restrict__ Wk, const float* __restrict__ Wv,
    const float* __restrict__ Wo, const float* __restrict__ Wg,
    __hip_bfloat16* __restrict__ xh,  __hip_bfloat16* __restrict__ xl,
    __hip_bfloat16* __restrict__ Wqh,
    __hip_bfloat16* __restrict__ Wkh, __hip_bfloat16* __restrict__ Wvh,
    __hip_bfloat16* __restrict__ Woh, __hip_bfloat16* __restrict__ Wol,
    float* __restrict__ xm, float2* __restrict__ gate)
{
    __shared__ float gs[32];
    const int bid = blockIdx.x;
    if (bid < 5120) {
        const int which = bid >> 10;
        const int b = bid & 1023;
        const int i = (b * 256 + threadIdx.x) * 4;
        const float* in; __hip_bfloat16 *hi, *lo = nullptr;
        if (which == 0)      { in = x;  hi = xh;  lo = xl; }
        else if (which == 1) { in = Wq; hi = Wqh; }
        else if (which == 2) { in = Wk; hi = Wkh; }
        else if (which == 3) { in = Wv; hi = Wvh; }
        else                 { in = Wo; hi = Woh; lo = Wol; }
        float4 v = *(const float4*)(in + i);
        float vv[4] = {v.x, v.y, v.z, v.w};
        __hip_bfloat16 h[4], l[4];
        #pragma unroll
        for (int j = 0; j < 4; j++) {
            h[j] = __float2bfloat16(vv[j]);
            l[j] = __float2bfloat16(vv[j] - __bfloat162float(h[j]));
        }
        *(uint2*)(hi + i) = *(uint2*)h;
        if (lo) *(uint2*)(lo + i) = *(uint2*)l;
    } else if (bid < 5184) {
        const int b = bid - 5120;
        const int g = b >> 2;
        const int f = (b & 3) * 256 + threadIdx.x;
        float s = 0.f;
        #pragma unroll 8
        for (int c = 0; c < CHUNK; c++) s += x[(size_t)(g * CHUNK + c) * DMODEL + f];
        xm[g * DMODEL + f] = s * (1.0f / CHUNK);
    } else {
        const int n = bid - 5184;
        const int wave = threadIdx.x >> 6, lane = threadIdx.x & 63;
        #pragma unroll
        for (int jj = 0; jj < 8; jj++) {
            int j = wave * 8 + jj;
            float s = 0.f;
            #pragma unroll
            for (int t = 0; t < 16; t++) {
                int d = lane + (t << 6);
                s += x[n * DMODEL + d] * Wg[j * DMODEL + d];
            }
            #pragma unroll
            for (int off = 32; off; off >>= 1) s += __shfl_xor(s, off);
            if (lane == 0) gs[j] = s;
        }
        __syncthreads();
        if (threadIdx.x < NHEAD) {
            int h = threadIdx.x;
            float a = gs[2 * h], b = gs[2 * h + 1];
            float m = fmaxf(a, b);
            float ea = expf(a - m), eb = expf(b - m);
            float inv = 1.f / (ea + eb);
            gate[n * NHEAD + h] = make_float2(ea * inv, eb * inv);
        }
    }
}

// ---------------------------------------------------------------------------
// B: kc = xm @ Wk^T (exact f32). One block per f; (g = tid>>4, sub = tid&15).
// ---------------------------------------------------------------------------
__global__ __launch_bounds__(256) void kc_gemm_kernel(
    const float* __restrict__ xm, const float* __restrict__ Wk,
    float* __restrict__ kc)
{
    const int f = blockIdx.x;
    const int g = threadIdx.x >> 4;
    const int sub = threadIdx.x & 15;
    const float* wrow = Wk + (size_t)f * DMODEL;
    float s = 0.f;
    #pragma unroll 16
    for (int i = 0; i < 64; i++) {
        int e = i * 16 + sub;
        s += xm[g * DMODEL + e] * wrow[e];
    }
    #pragma unroll
    for (int off = 8; off; off >>= 1) s += __shfl_xor(s, off);
    if (sub == 0) kc[g * DMODEL + f] = s;
}

// ---------------------------------------------------------------------------
// C: U[(h<<4)|g][f] = sum_d kc[g][h*64+d] * Wq[h*64+d][f]  (exact f32),
// then split to bf16 hi/lo rows Uh/Ul [256][1024].
// ---------------------------------------------------------------------------
__global__ __launch_bounds__(256) void u_kernel(
    const float* __restrict__ kc, const float* __restrict__ Wq,
    __hip_bfloat16* __restrict__ Uh, __hip_bfloat16* __restrict__ Ul)
{
    __shared__ float kcs[64];
    const int h = blockIdx.x >> 4, g = blockIdx.x & 15;
    if (threadIdx.x < 64) kcs[threadIdx.x] = kc[g * DMODEL + h * HDIM + threadIdx.x];
    __syncthreads();
    const int col = (h << 4) | g;
    for (int f = threadIdx.x; f < DMODEL; f += 256) {
        float s = 0.f;
        #pragma unroll 16
        for (int d = 0; d < 64; d++)
            s += kcs[d] * Wq[(size_t)(h * HDIM + d) * DMODEL + f];
        __hip_bfloat16 hv = __float2bfloat16(s);
        Uh[(size_t)col * DMODEL + f] = hv;
        Ul[(size_t)col * DMODEL + f] = __float2bfloat16(s - __bfloat162float(hv));
    }
}

// ---------------------------------------------------------------------------
// D: blocks [0,192): fused QKV GEMM, 128x128 tiles, double-buffered 2-phase.
//    blocks [192,256): score GEMM S = (xh+xl)@(Uh+Ul)^T (64x64, 3-term).
// Epilogues: Q,K -> bf16 [n][D]; V -> bf16 transposed Vt[f][n] via LDS.
// ---------------------------------------------------------------------------
__global__ __launch_bounds__(256) void qkv_score_kernel(
    const __hip_bfloat16* __restrict__ xh, const __hip_bfloat16* __restrict__ xl,
    const __hip_bfloat16* __restrict__ Wqh, const __hip_bfloat16* __restrict__ Wkh,
    const __hip_bfloat16* __restrict__ Wvh,
    const __hip_bfloat16* __restrict__ Uh, const __hip_bfloat16* __restrict__ Ul,
    __hip_bfloat16* __restrict__ Qb, __hip_bfloat16* __restrict__ Kb,
    __hip_bfloat16* __restrict__ Vt, float* __restrict__ S)
{
    __shared__ alignas(16) char smem[65536];

    const int b = blockIdx.x;
    const int tid  = threadIdx.x;
    const int wave = tid >> 6;
    const int lane = tid & 63;
    const int fr = lane & 15;
    const int quad = lane >> 4;

    if (b < 192) {
        // ---- fused QKV GEMM, 128x128 tile, dbuf 2-phase ----
        __hip_bfloat16* A0 = (__hip_bfloat16*)smem;             // 16 KB
        __hip_bfloat16* B0 = (__hip_bfloat16*)(smem + 16384);   // 16 KB
        __hip_bfloat16* A1 = (__hip_bfloat16*)(smem + 32768);
        __hip_bfloat16* B1 = (__hip_bfloat16*)(smem + 49152);

        const int widx = b >> 6;              // 0=Q 1=K 2=V
        const int t = b & 63;
        const int m0 = (t >> 3) * 128;
        const int n0 = (t & 7) * 128;
        const __hip_bfloat16* __restrict__ Bw =
            (widx == 0) ? Wqh : (widx == 1) ? Wkh : Wvh;

        const int wm = (wave >> 1) * 64;
        const int wn = (wave & 1) * 64;

        f32x4 acc[4][4] = {};

        stage128(xh + (size_t)m0 * DMODEL, A0, wave, lane);
        stage128(Bw + (size_t)n0 * DMODEL, B0, wave, lane);
        __syncthreads();

        for (int kt = 0; kt < 16; kt++) {
            const int cur = kt & 1;
            __hip_bfloat16* Ac = cur ? A1 : A0;
            __hip_bfloat16* Bc = cur ? B1 : B0;
            if (kt < 15) {
                __hip_bfloat16* An = cur ? A0 : A1;
                __hip_bfloat16* Bn = cur ? B0 : B1;
                stage128(xh + (size_t)m0 * DMODEL + (kt + 1) * 64, An, wave, lane);
                stage128(Bw + (size_t)n0 * DMODEL + (kt + 1) * 64, Bn, wave, lane);
            }
            #pragma unroll
            for (int hk = 0; hk < 2; hk++) {
                const int ch = hk * 4 + quad;
                short8 am[4], bn[4];
                #pragma unroll
                for (int i = 0; i < 4; i++) am[i] = ldsfrag(Ac, wm + i * 16 + fr, ch);
                #pragma unroll
                for (int j = 0; j < 4; j++) bn[j] = ldsfrag(Bc, wn + j * 16 + fr, ch);
                #pragma unroll
                for (int i = 0; i < 4; i++)
                #pragma unroll
                for (int j = 0; j < 4; j++)
                    acc[i][j] = __builtin_amdgcn_mfma_f32_16x16x32_bf16(am[i], bn[j], acc[i][j], 0, 0, 0);
            }
            __syncthreads();
        }

        if (widx == 0 || widx == 1) {
            __hip_bfloat16* __restrict__ Out = (widx == 0) ? Qb : Kb;
            #pragma unroll
            for (int i = 0; i < 4; i++)
            #pragma unroll
            for (int j = 0; j < 4; j++)
            #pragma unroll
            for (int r = 0; r < 4; r++) {
                int row = m0 + wm + i * 16 + quad * 4 + r;
                int col = n0 + wn + j * 16 + fr;
                Out[(size_t)row * DMODEL + col] = __float2bfloat16(acc[i][j][r]);
            }
        } else {
            // V: transpose 128x128 via LDS in two 64-col passes -> Vt[f][n]
            __hip_bfloat16 (*T)[136] = (__hip_bfloat16(*)[136])smem;
            for (int p = 0; p < 2; p++) {
                __syncthreads();
                if ((wn >> 6) == p) {
                    #pragma unroll
                    for (int i = 0; i < 4; i++)
                    #pragma unroll
                    for (int j = 0; j < 4; j++)
                    #pragma unroll
                    for (int r = 0; r < 4; r++) {
                        int nloc = wm + i * 16 + quad * 4 + r;        // 0..127
                        int floc = (wn - p * 64) + j * 16 + fr;       // 0..63
                        T[floc][nloc] = __float2bfloat16(acc[i][j][r]);
                    }
                }
                __syncthreads();
                const int row = tid >> 2;             // 0..63
                const int cb  = (tid & 3) * 32;       // col base (elems)
                const size_t o = (size_t)(n0 + p * 64 + row) * NTOK + m0 + cb;
                #pragma unroll
                for (int u = 0; u < 4; u++)
                    *(uint4*)(Vt + o + u * 8) = *(uint4*)(&T[row][cb + u * 8]);
            }
        }
    } else {
        // ---- score GEMM: S = (xh+xl) @ (Uh+Ul)^T, 3-term split ----
        __hip_bfloat16* AshP = (__hip_bfloat16*)smem;
        __hip_bfloat16* AslP = (__hip_bfloat16*)(smem + 8192);
        __hip_bfloat16* BshP = (__hip_bfloat16*)(smem + 16384);
        __hip_bfloat16* BslP = (__hip_bfloat16*)(smem + 24576);

        const int wm = (wave >> 1) * 32;
        const int wn = (wave & 1) * 32;

        const int bb = b - 192;                 // [0,64)
        const int m0 = (bb >> 2) * 64;          // 16 token tiles
        const int n0 = (bb & 3) * 64;           // 4 col tiles (256 cols)

        f32x4 acc[2][2] = {};

        for (int k0 = 0; k0 < DMODEL; k0 += 64) {
            stage64(xh + (size_t)m0 * DMODEL + k0, AshP, wave, lane);
            stage64(xl + (size_t)m0 * DMODEL + k0, AslP, wave, lane);
            stage64(Uh + (size_t)n0 * DMODEL + k0, BshP, wave, lane);
            stage64(Ul + (size_t)n0 * DMODEL + k0, BslP, wave, lane);
            __syncthreads();

            #pragma unroll
            for (int hk = 0; hk < 2; hk++) {
                const int ch = hk * 4 + quad;
                short8 a0h = ldsfrag(AshP, wm + fr, ch);
                short8 a1h = ldsfrag(AshP, wm + 16 + fr, ch);
                short8 a0l = ldsfrag(AslP, wm + fr, ch);
                short8 a1l = ldsfrag(AslP, wm + 16 + fr, ch);
                short8 b0h = ldsfrag(BshP, wn + fr, ch);
                short8 b1h = ldsfrag(BshP, wn + 16 + fr, ch);
                short8 b0l = ldsfrag(BslP, wn + fr, ch);
                short8 b1l = ldsfrag(BslP, wn + 16 + fr, ch);
                acc[0][0] = __builtin_amdgcn_mfma_f32_16x16x32_bf16(a0l, b0h, acc[0][0], 0, 0, 0);
                acc[0][1] = __builtin_amdgcn_mfma_f32_16x16x32_bf16(a0l, b1h, acc[0][1], 0, 0, 0);
                acc[1][0] = __builtin_amdgcn_mfma_f32_16x16x32_bf16(a1l, b0h, acc[1][0], 0, 0, 0);
                acc[1][1] = __builtin_amdgcn_mfma_f32_16x16x32_bf16(a1l, b1h, acc[1][1], 0, 0, 0);
                acc[0][0] = __builtin_amdgcn_mfma_f32_16x16x32_bf16(a0h, b0l, acc[0][0], 0, 0, 0);
                acc[0][1] = __builtin_amdgcn_mfma_f32_16x16x32_bf16(a0h, b1l, acc[0][1], 0, 0, 0);
                acc[1][0] = __builtin_amdgcn_mfma_f32_16x16x32_bf16(a1h, b0l, acc[1][0], 0, 0, 0);
                acc[1][1] = __builtin_amdgcn_mfma_f32_16x16x32_bf16(a1h, b1l, acc[1][1], 0, 0, 0);
                acc[0][0] = __builtin_amdgcn_mfma_f32_16x16x32_bf16(a0h, b0h, acc[0][0], 0, 0, 0);
                acc[0][1] = __builtin_amdgcn_mfma_f32_16x16x32_bf16(a0h, b1h, acc[0][1], 0, 0, 0);
                acc[1][0] = __builtin_amdgcn_mfma_f32_16x16x32_bf16(a1h, b0h, acc[1][0], 0, 0, 0);
                acc[1][1] = __builtin_amdgcn_mfma_f32_16x16x32_bf16(a1h, b1h, acc[1][1], 0, 0, 0);
            }
            __syncthreads();
        }

        #pragma unroll
        for (int tm = 0; tm < 2; tm++)
        #pragma unroll
        for (int tn = 0; tn < 2; tn++)
        #pragma unroll
        for (int r = 0; r < 4; r++) {
            int row = m0 + wm + tm * 16 + quad * 4 + r;
            int col = n0 + wn + tn * 16 + fr;
            S[(size_t)row * 256 + col] = acc[tm][tn][r];
        }
    }
}

// ---------------------------------------------------------------------------
// E: split-K MFMA attention (unchanged). Grid = (g,h,qtile) = 1024 blocks x
// 4 waves; wave s processes every 4th entry of the union block list; K/V
// frags direct from global; LDS merge with exact softmax combine.
// ---------------------------------------------------------------------------
__global__ __launch_bounds__(256, 4) void attn_mfma_kernel(
    const __hip_bfloat16* __restrict__ Qb, const __hip_bfloat16* __restrict__ Kb,
    const __hip_bfloat16* __restrict__ Vt, const float* __restrict__ S,
    const float2* __restrict__ gate, __hip_bfloat16* __restrict__ oh)
{
    __shared__ float OS[4][16][64];     // per-split inter partial O
    __shared__ float OIs[16][64];       // intra O
    __shared__ float mS[4][16], lS[4][16], liS[16];
    __shared__ int i1s[16], i2s[16];
    __shared__ float2 sgate[16];
    __shared__ unsigned unionMask;
    __shared__ __hip_bfloat16 Ps[4][16][72];   // per-wave P round-trip

    const int bid = blockIdx.x;
    const int qt = bid & 3;
    const int h  = (bid >> 2) & 15;
    const int g  = bid >> 6;
    const int tid = threadIdx.x;
    const int s = tid >> 6;             // wave = key-split id
    const int lane = tid & 63;
    const int fr = lane & 15, quad = lane >> 4;

    // ---- prologue: per-query top-2 (exact tie semantics), gate, union ----
    if (tid < 16) {
        const int n = g * 64 + qt * 16 + tid;
        const float* Sn = S + (size_t)n * 256 + h * 16;
        float sc[NBLK];
        #pragma unroll
        for (int gg = 0; gg < NBLK; gg++)
            sc[gg] = (n >= (gg << 6)) ? -INFINITY : Sn[gg];
        int i1 = -1, i2 = -1;
        float b1 = -INFINITY;
        #pragma unroll
        for (int gg = 0; gg < NBLK; gg++) if (i1 < 0 || sc[gg] > b1) { b1 = sc[gg]; i1 = gg; }
        float b2 = -INFINITY;
        #pragma unroll
        for (int gg = 0; gg < NBLK; gg++) { if (gg == i1) continue; if (i2 < 0 || sc[gg] > b2) { b2 = sc[gg]; i2 = gg; } }
        i1s[tid] = i1; i2s[tid] = i2;
        sgate[tid] = gate[(size_t)n * NHEAD + h];
        unsigned m = (1u << i1) | (1u << i2);
        #pragma unroll
        for (int off = 1; off < 16; off <<= 1) m |= (unsigned)__shfl_xor((int)m, off);
        if (tid == 0) unionMask = m;
    }
    __syncthreads();

    const unsigned um = unionMask;

    // ---- Q A-fragments direct from global ----
    const size_t qrow = (size_t)(g * 64 + qt * 16 + fr) * DMODEL + h * HDIM + quad * 8;
    const short8 qa0 = *(const short8*)(Qb + qrow);
    const short8 qa1 = *(const short8*)(Qb + qrow + 32);

    // per-lane copies of top-2 / gate for this quad's 4 query rows
    int qi1[4], qi2[4];
    #pragma unroll
    for (int r = 0; r < 4; r++) {
        int q = quad * 4 + r;
        qi1[r] = i1s[q]; qi2[r] = i2s[q];
    }

    f32x4 Oint[4] = {};        // inter accumulator (16q x 64d)
    float mrun[4] = {-INFINITY, -INFINITY, -INFINITY, -INFINITY};
    float lrun[4] = {0.f, 0.f, 0.f, 0.f};

    const __hip_bfloat16* __restrict__ Kh = Kb + h * HDIM + quad * 8;
    const __hip_bfloat16* __restrict__ Vh = Vt + (size_t)(h * HDIM) * NTOK + quad * 8;

    int j = 0;
    for (int kb = 0; kb < NBLK; kb++) {
        if (!((um >> kb) & 1u)) continue;
        if ((j++ & 3) != s) continue;

        // ---- QK^T: 16q x 64k, K frags direct from global ----
        f32x4 sacc[4] = {};
        #pragma unroll
        for (int t = 0; t < 4; t++) {
            const size_t krow = (size_t)(kb * 64 + t * 16 + fr) * DMODEL;
            short8 kb0 = *(const short8*)(Kh + krow);
            short8 kb1 = *(const short8*)(Kh + krow + 32);
            sacc[t] = __builtin_amdgcn_mfma_f32_16x16x32_bf16(qa0, kb0, sacc[t], 0, 0, 0);
            sacc[t] = __builtin_amdgcn_mfma_f32_16x16x32_bf16(qa1, kb1, sacc[t], 0, 0, 0);
        }

        // ---- inter online softmax, per-query selected-block gating ----
        #pragma unroll
        for (int r = 0; r < 4; r++) {
            const bool sel = (kb == qi1[r]) | (kb == qi2[r]);   // quad-uniform
            float v0 = sacc[0][r] * 0.125f, v1 = sacc[1][r] * 0.125f;
            float v2 = sacc[2][r] * 0.125f, v3 = sacc[3][r] * 0.125f;
            float mx = qmax16(fmaxf(fmaxf(v0, v1), fmaxf(v2, v3)));
            float mnew = sel ? fmaxf(mrun[r], mx) : mrun[r];
            float f = sel ? __expf(mrun[r] - mnew) : 1.0f;
            float e0 = sel ? __expf(v0 - mnew) : 0.f;
            float e1 = sel ? __expf(v1 - mnew) : 0.f;
            float e2 = sel ? __expf(v2 - mnew) : 0.f;
            float e3 = sel ? __expf(v3 - mnew) : 0.f;
            float es = qsum16(e0 + e1 + e2 + e3);
            lrun[r] = lrun[r] * f + es;
            mrun[r] = mnew;
            #pragma unroll
            for (int dn = 0; dn < 4; dn++) Oint[dn][r] *= f;
            const int prow = quad * 4 + r;
            Ps[s][prow][ 0 + fr] = __float2bfloat16(e0);
            Ps[s][prow][16 + fr] = __float2bfloat16(e1);
            Ps[s][prow][32 + fr] = __float2bfloat16(e2);
            Ps[s][prow][48 + fr] = __float2bfloat16(e3);
        }

        // ---- PV: O += P @ V, V frags direct from global ----
        short8 pa0 = *(const short8*)(&Ps[s][fr][quad * 8]);
        short8 pa1 = *(const short8*)(&Ps[s][fr][32 + quad * 8]);
        #pragma unroll
        for (int dn = 0; dn < 4; dn++) {
            const size_t vrow = (size_t)(dn * 16 + fr) * NTOK + kb * 64;
            short8 v0 = *(const short8*)(Vh + vrow);
            short8 v1 = *(const short8*)(Vh + vrow + 32);
            Oint[dn] = __builtin_amdgcn_mfma_f32_16x16x32_bf16(pa0, v0, Oint[dn], 0, 0, 0);
            Oint[dn] = __builtin_amdgcn_mfma_f32_16x16x32_bf16(pa1, v1, Oint[dn], 0, 0, 0);
        }
    }

    // ---- intra tile (kb == g), owned by split (popcount(um) % 4) ----
    if ((j & 3) == s) {
        f32x4 sacc[4] = {};
        #pragma unroll
        for (int t = 0; t < 4; t++) {
            const size_t krow = (size_t)(g * 64 + t * 16 + fr) * DMODEL;
            short8 kb0 = *(const short8*)(Kh + krow);
            short8 kb1 = *(const short8*)(Kh + krow + 32);
            sacc[t] = __builtin_amdgcn_mfma_f32_16x16x32_bf16(qa0, kb0, sacc[t], 0, 0, 0);
            sacc[t] = __builtin_amdgcn_mfma_f32_16x16x32_bf16(qa1, kb1, sacc[t], 0, 0, 0);
        }
        f32x4 Ointr[4] = {};
        #pragma unroll
        for (int r = 0; r < 4; r++) {
            const int qloc = qt * 16 + quad * 4 + r;   // query row in chunk
            float vv[4];
            #pragma unroll
            for (int t = 0; t < 4; t++) {
                const int col = t * 16 + fr;
                float v = sacc[t][r] * 0.125f;
                vv[t] = (col <= qloc) ? v : -INFINITY;
            }
            float mx = qmax16(fmaxf(fmaxf(vv[0], vv[1]), fmaxf(vv[2], vv[3])));
            float e0 = __expf(vv[0] - mx), e1 = __expf(vv[1] - mx);
            float e2 = __expf(vv[2] - mx), e3 = __expf(vv[3] - mx);
            float lsum = qsum16(e0 + e1 + e2 + e3);
            const int prow = quad * 4 + r;
            if (fr == 0) liS[prow] = lsum;
            Ps[s][prow][ 0 + fr] = __float2bfloat16(e0);
            Ps[s][prow][16 + fr] = __float2bfloat16(e1);
            Ps[s][prow][32 + fr] = __float2bfloat16(e2);
            Ps[s][prow][48 + fr] = __float2bfloat16(e3);
        }
        short8 pa0 = *(const short8*)(&Ps[s][fr][quad * 8]);
        short8 pa1 = *(const short8*)(&Ps[s][fr][32 + quad * 8]);
        f32x4 Ointr2[4] = {};
        #pragma unroll
        for (int dn = 0; dn < 4; dn++) {
            const size_t vrow = (size_t)(dn * 16 + fr) * NTOK + g * 64;
            short8 v0 = *(const short8*)(Vh + vrow);
            short8 v1 = *(const short8*)(Vh + vrow + 32);
            Ointr2[dn] = __builtin_amdgcn_mfma_f32_16x16x32_bf16(pa0, v0, Ointr[dn], 0, 0, 0);
            Ointr2[dn] = __builtin_amdgcn_mfma_f32_16x16x32_bf16(pa1, v1, Ointr2[dn], 0, 0, 0);
        }
        #pragma unroll
        for (int r = 0; r < 4; r++)
        #pragma unroll
        for (int dn = 0; dn < 4; dn++)
            OIs[quad * 4 + r][dn * 16 + fr] = Ointr2[dn][r];
    }

    // ---- publish split partials ----
    #pragma unroll
    for (int r = 0; r < 4; r++) {
        if (fr == 0) { mS[s][quad * 4 + r] = mrun[r]; lS[s][quad * 4 + r] = lrun[r]; }
        #pragma unroll
        for (int dn = 0; dn < 4; dn++)
            OS[s][quad * 4 + r][dn * 16 + fr] = Oint[dn][r];
    }
    __syncthreads();

    // ---- merge splits + gated blend, write oh bf16 ----
    {
        const int q = tid >> 4;
        const int db = (tid & 15) * 4;
        float M = fmaxf(fmaxf(mS[0][q], mS[1][q]), fmaxf(mS[2][q], mS[3][q]));
        float L = 0.f;
        float o0 = 0.f, o1 = 0.f, o2 = 0.f, o3 = 0.f;
        #pragma unroll
        for (int ss = 0; ss < 4; ss++) {
            float p = __expf(mS[ss][q] - M);
            L += lS[ss][q] * p;
            o0 += OS[ss][q][db + 0] * p;
            o1 += OS[ss][q][db + 1] * p;
            o2 += OS[ss][q][db + 2] * p;
            o3 += OS[ss][q][db + 3] * p;
        }
        const float2 gt = sgate[q];
        const float wi = gt.x / L;
        const float wl = gt.y / liS[q];
        unsigned short out4[4];
        out4[0] = __builtin_bit_cast(unsigned short, __float2bfloat16(wi * o0 + wl * OIs[q][db + 0]));
        out4[1] = __builtin_bit_cast(unsigned short, __float2bfloat16(wi * o1 + wl * OIs[q][db + 1]));
        out4[2] = __builtin_bit_cast(unsigned short, __float2bfloat16(wi * o2 + wl * OIs[q][db + 2]));
        out4[3] = __builtin_bit_cast(unsigned short, __float2bfloat16(wi * o3 + wl * OIs[q][db + 3]));
        const int n = g * 64 + qt * 16 + q;
        *(uint2*)(oh + (size_t)n * DMODEL + h * HDIM + db) = *(uint2*)out4;
    }
}

// ---------------------------------------------------------------------------
// F: Wo GEMM: C = oh x (Woh + Wol)^T, 64x64 tile, BK=64, f32 store.
// 8 waves (512 thr) for 2 waves/SIMD; async staging, 3 tiles (A, Bh, Bl).
// ---------------------------------------------------------------------------
__global__ __launch_bounds__(512) void gemm_wo(
    const __hip_bfloat16* __restrict__ Ah,
    const __hip_bfloat16* __restrict__ Bh, const __hip_bfloat16* __restrict__ Bl,
    float* __restrict__ C)
{
    __shared__ alignas(16) char smem[24576];
    __hip_bfloat16* AshP = (__hip_bfloat16*)smem;
    __hip_bfloat16* BshP = (__hip_bfloat16*)(smem + 8192);
    __hip_bfloat16* BslP = (__hip_bfloat16*)(smem + 16384);

    const int n0 = blockIdx.x * 64;
    const int m0 = blockIdx.y * 64;

    const int tid  = threadIdx.x;
    const int wave = tid >> 6;          // 0..7
    const int lane = tid & 63;
    const int wm = (wave >> 1) * 16;    // {0,16,32,48}
    const int wn = (wave & 1) * 32;     // {0,32}
    const int fr = lane & 15;
    const int quad = lane >> 4;

    f32x4 acc[2] = {};

    for (int k0 = 0; k0 < DMODEL; k0 += 64) {
        stage64w8(Ah + (size_t)m0 * DMODEL + k0, AshP, wave, lane);
        stage64w8(Bh + (size_t)n0 * DMODEL + k0, BshP, wave, lane);
        stage64w8(Bl + (size_t)n0 * DMODEL + k0, BslP, wave, lane);
        __syncthreads();

        #pragma unroll
        for (int hk = 0; hk < 2; hk++) {
            const int ch = hk * 4 + quad;
            short8 a0  = ldsfrag(AshP, wm + fr, ch);
            short8 b0h = ldsfrag(BshP, wn + fr, ch);
            short8 b1h = ldsfrag(BshP, wn + 16 + fr, ch);
            short8 b0l = ldsfrag(BslP, wn + fr, ch);
            short8 b1l = ldsfrag(BslP, wn + 16 + fr, ch);
            acc[0] = __builtin_amdgcn_mfma_f32_16x16x32_bf16(a0, b0l, acc[0], 0, 0, 0);
            acc[1] = __builtin_amdgcn_mfma_f32_16x16x32_bf16(a0, b1l, acc[1], 0, 0, 0);
            acc[0] = __builtin_amdgcn_mfma_f32_16x16x32_bf16(a0, b0h, acc[0], 0, 0, 0);
            acc[1] = __builtin_amdgcn_mfma_f32_16x16x32_bf16(a0, b1h, acc[1], 0, 0, 0);
        }
        __syncthreads();
    }

    #pragma unroll
    for (int tn = 0; tn < 2; tn++)
    #pragma unroll
    for (int r = 0; r < 4; r++) {
        int row = m0 + wm + quad * 4 + r;
        int col = n0 + wn + tn * 16 + fr;
        C[(size_t)row * DMODEL + col] = acc[tn][r];
    }
}

// ---------------------------------------------------------------------------
extern "C" void kernel_launch(void* const* d_in, const int* in_sizes, int n_in,
                              void* d_out, int out_size, void* d_ws, size_t ws_size,
                              hipStream_t stream)
{
    const float* x  = (const float*)d_in[0];
    const float* Wq = (const float*)d_in[1];
    const float* Wk = (const float*)d_in[2];
    const float* Wv = (const float*)d_in[3];
    const float* Wg = (const float*)d_in[4];
    const float* Wo = (const float*)d_in[5];

    const size_t M1 = (size_t)NTOK * DMODEL;   // 1M elems

    // workspace layout (~24.5 MB)
    float* S       = (float*)d_ws;                    // 1 MB (scores [1024][256])
    float* xm      = S + (size_t)NTOK * 256;          // 64 KB
    float* kc      = xm + NBLK * DMODEL;              // 64 KB
    float2* gate   = (float2*)(kc + NBLK * DMODEL);   // 128 KB
    __hip_bfloat16* xh  = (__hip_bfloat16*)(gate + NTOK * NHEAD);   // 2 MB
    __hip_bfloat16* xl  = xh + M1;     // 2 MB
    __hip_bfloat16* Wqh = xl + M1;     // 2 MB
    __hip_bfloat16* Wkh = Wqh + M1;    // 2 MB
    __hip_bfloat16* Wvh = Wkh + M1;    // 2 MB
    __hip_bfloat16* Woh = Wvh + M1;    // 2 MB
    __hip_bfloat16* Wol = Woh + M1;    // 2 MB
    __hip_bfloat16* oh  = Wol + M1;    // 2 MB
    __hip_bfloat16* Uh  = oh + M1;     // 512 KB ([256][1024])
    __hip_bfloat16* Ul  = Uh + 256 * DMODEL;  // 512 KB
    __hip_bfloat16* Qb  = Ul + 256 * DMODEL;  // 2 MB  bf16 [n][D]
    __hip_bfloat16* Kb  = Qb + M1;            // 2 MB  bf16 [n][D]
    __hip_bfloat16* Vt  = Kb + M1;            // 2 MB  bf16 [f][n] (transposed)

    prep_kernel<<<6208, 256, 0, stream>>>(
        x, Wq, Wk, Wv, Wo, Wg, xh, xl, Wqh, Wkh, Wvh, Woh, Wol, xm, gate);

    kc_gemm_kernel<<<1024, 256, 0, stream>>>(xm, Wk, kc);
    u_kernel<<<256, 256, 0, stream>>>(kc, Wq, Uh, Ul);

    qkv_score_kernel<<<256, 256, 0, stream>>>(
        xh, xl, Wqh, Wkh, Wvh, Uh, Ul, Qb, Kb, Vt, S);

    attn_mfma_kernel<<<NBLK * NHEAD * 4, 256, 0, stream>>>(Qb, Kb, Vt, S, gate, oh);

    dim3 gwo(16, 16);
    gemm_wo<<<gwo, 512, 0, stream>>>(oh, Woh, Wol, (float*)d_out);
}

// Round 7
// 155.191 us; speedup vs baseline: 1.2492x; 1.0241x over previous
//
#include <hip/hip_runtime.h>
#include <hip/hip_bf16.h>
#include <math.h>

// Problem: B=1, N=1024, D=1024, H=16, C=64, TOPK=2, HD=64, G=16
//
// Round-7 (= round-6 + tail fix): counted-vmcnt software pipelines in the
// two staged GEMMs. stage(t+1); vmcnt(8|3); s_barrier; compute(t); s_barrier.
// TAIL FIX: the final iteration (no prefetch) must drain vmcnt(0) before its
// barrier — round-6 read the last K-tile's LDS before the async loads landed
// (absmax 0.297). MFMA order unchanged -> bit-identical outputs otherwise.

typedef __attribute__((ext_vector_type(8))) short short8;   // 8 bf16 = 4 VGPRs
typedef __attribute__((ext_vector_type(4))) float f32x4;

#define NTOK 1024
#define DMODEL 1024
#define NHEAD 16
#define HDIM 64
#define CHUNK 64
#define NBLK 16

__device__ __forceinline__ float qmax16(float v)
{
    #pragma unroll
    for (int off = 1; off < 16; off <<= 1) v = fmaxf(v, __shfl_xor(v, off));
    return v;
}

__device__ __forceinline__ float qsum16(float v)
{
    #pragma unroll
    for (int off = 1; off < 16; off <<= 1) v += __shfl_xor(v, off);
    return v;
}

// ---- async-staged bf16 tile helpers (linear LDS + XOR swizzle) ----
// LDS[row][slot] (slot = 16B chunk, 8 per 128B row) holds global chunk
// slot ^ (row & 7). Reader of logical chunk c reads slot c ^ (row & 7).

#define GLOAD_LDS16(gp, lp)                                              \
    __builtin_amdgcn_global_load_lds(                                    \
        (const __attribute__((address_space(1))) void*)(gp),             \
        (__attribute__((address_space(3))) void*)(lp), 16, 0, 0)

// 64-row tile, 4 waves: wave w stages rows [w*16, w*16+16). 2 loads/wave.
__device__ __forceinline__ void stage64(const __hip_bfloat16* __restrict__ g0,
                                        __hip_bfloat16* t, int wave, int lane)
{
    const int sub = lane >> 3;              // row within 8-row group
    const int cch = (lane & 7) ^ sub;       // pre-swizzled source chunk
    #pragma unroll
    for (int j = 0; j < 2; j++) {
        const int rr = (2 * wave + j) * 8 + sub;
        GLOAD_LDS16(g0 + (size_t)rr * DMODEL + cch * 8, t + (2 * wave + j) * 512);
    }
}

// 128-row tile, 4 waves: wave w stages rows [w*32, w*32+32). 4 loads/wave.
__device__ __forceinline__ void stage128(const __hip_bfloat16* __restrict__ g0,
                                         __hip_bfloat16* t, int wave, int lane)
{
    const int sub = lane >> 3;
    const int cch = (lane & 7) ^ sub;
    #pragma unroll
    for (int j = 0; j < 4; j++) {
        const int grp = wave * 4 + j;
        GLOAD_LDS16(g0 + (size_t)(grp * 8 + sub) * DMODEL + cch * 8, t + grp * 512);
    }
}

// 64-row tile, 8 waves: wave w stages rows [w*8, w*8+8). 1 load/wave.
__device__ __forceinline__ void stage64w8(const __hip_bfloat16* __restrict__ g0,
                                          __hip_bfloat16* t, int wave, int lane)
{
    const int sub = lane >> 3;
    const int cch = (lane & 7) ^ sub;
    GLOAD_LDS16(g0 + (size_t)(wave * 8 + sub) * DMODEL + cch * 8, t + wave * 512);
}

// swizzled fragment read: logical (row, chunk) -> 16B
__device__ __forceinline__ short8 ldsfrag(const __hip_bfloat16* t, int row, int chunk)
{
    return *(const short8*)((const char*)t + row * 128 + (((chunk) ^ (row & 7)) << 4));
}

// ---------------------------------------------------------------------------
// A: prep. blockIdx roles: [0,5120) casts (which = bid>>10: 0 x split,
// 1 Wq hi, 2 Wk hi, 3 Wv hi, 4 Wo split), [5120,5184) xm, [5184,6208) gate.
// ---------------------------------------------------------------------------
__global__ __launch_bounds__(256) void prep_kernel(
    const float* __restrict__ x,  const float* __restrict__ Wq,
    const float* __restrict__ Wk, const float* __restrict__ Wv,
    const float* __restrict__ Wo, const float* __restrict__ Wg,
    __hip_bfloat16* __restrict__ xh,  __hip_bfloat16* __restrict__ xl,
    __hip_bfloat16* __restrict__ Wqh,
    __hip_bfloat16* __restrict__ Wkh, __hip_bfloat16* __restrict__ Wvh,
    __hip_bfloat16* __restrict__ Woh, __hip_bfloat16* __restrict__ Wol,
    float* __restrict__ xm, float2* __restrict__ gate)
{
    __shared__ float gs[32];
    const int bid = blockIdx.x;
    if (bid < 5120) {
        const int which = bid >> 10;
        const int b = bid & 1023;
        const int i = (b * 256 + threadIdx.x) * 4;
        const float* in; __hip_bfloat16 *hi, *lo = nullptr;
        if (which == 0)      { in = x;  hi = xh;  lo = xl; }
        else if (which == 1) { in = Wq; hi = Wqh; }
        else if (which == 2) { in = Wk; hi = Wkh; }
        else if (which == 3) { in = Wv; hi = Wvh; }
        else                 { in = Wo; hi = Woh; lo = Wol; }
        float4 v = *(const float4*)(in + i);
        float vv[4] = {v.x, v.y, v.z, v.w};
        __hip_bfloat16 h[4], l[4];
        #pragma unroll
        for (int j = 0; j < 4; j++) {
            h[j] = __float2bfloat16(vv[j]);
            l[j] = __float2bfloat16(vv[j] - __bfloat162float(h[j]));
        }
        *(uint2*)(hi + i) = *(uint2*)h;
        if (lo) *(uint2*)(lo + i) = *(uint2*)l;
    } else if (bid < 5184) {
        const int b = bid - 5120;
        const int g = b >> 2;
        const int f = (b & 3) * 256 + threadIdx.x;
        float s = 0.f;
        #pragma unroll 8
        for (int c = 0; c < CHUNK; c++) s += x[(size_t)(g * CHUNK + c) * DMODEL + f];
        xm[g * DMODEL + f] = s * (1.0f / CHUNK);
    } else {
        const int n = bid - 5184;
        const int wave = threadIdx.x >> 6, lane = threadIdx.x & 63;
        #pragma unroll
        for (int jj = 0; jj < 8; jj++) {
            int j = wave * 8 + jj;
            float s = 0.f;
            #pragma unroll
            for (int t = 0; t < 16; t++) {
                int d = lane + (t << 6);
                s += x[n * DMODEL + d] * Wg[j * DMODEL + d];
            }
            #pragma unroll
            for (int off = 32; off; off >>= 1) s += __shfl_xor(s, off);
            if (lane == 0) gs[j] = s;
        }
        __syncthreads();
        if (threadIdx.x < NHEAD) {
            int h = threadIdx.x;
            float a = gs[2 * h], b = gs[2 * h + 1];
            float m = fmaxf(a, b);
            float ea = expf(a - m), eb = expf(b - m);
            float inv = 1.f / (ea + eb);
            gate[n * NHEAD + h] = make_float2(ea * inv, eb * inv);
        }
    }
}

// ---------------------------------------------------------------------------
// B: kc = xm @ Wk^T (exact f32). One block per f; (g = tid>>4, sub = tid&15).
// ---------------------------------------------------------------------------
__global__ __launch_bounds__(256) void kc_gemm_kernel(
    const float* __restrict__ xm, const float* __restrict__ Wk,
    float* __restrict__ kc)
{
    const int f = blockIdx.x;
    const int g = threadIdx.x >> 4;
    const int sub = threadIdx.x & 15;
    const float* wrow = Wk + (size_t)f * DMODEL;
    float s = 0.f;
    #pragma unroll 16
    for (int i = 0; i < 64; i++) {
        int e = i * 16 + sub;
        s += xm[g * DMODEL + e] * wrow[e];
    }
    #pragma unroll
    for (int off = 8; off; off >>= 1) s += __shfl_xor(s, off);
    if (sub == 0) kc[g * DMODEL + f] = s;
}

// ---------------------------------------------------------------------------
// C: U[(h<<4)|g][f] = sum_d kc[g][h*64+d] * Wq[h*64+d][f]  (exact f32),
// then split to bf16 hi/lo rows Uh/Ul [256][1024].
// ---------------------------------------------------------------------------
__global__ __launch_bounds__(256) void u_kernel(
    const float* __restrict__ kc, const float* __restrict__ Wq,
    __hip_bfloat16* __restrict__ Uh, __hip_bfloat16* __restrict__ Ul)
{
    __shared__ float kcs[64];
    const int h = blockIdx.x >> 4, g = blockIdx.x & 15;
    if (threadIdx.x < 64) kcs[threadIdx.x] = kc[g * DMODEL + h * HDIM + threadIdx.x];
    __syncthreads();
    const int col = (h << 4) | g;
    for (int f = threadIdx.x; f < DMODEL; f += 256) {
        float s = 0.f;
        #pragma unroll 16
        for (int d = 0; d < 64; d++)
            s += kcs[d] * Wq[(size_t)(h * HDIM + d) * DMODEL + f];
        __hip_bfloat16 hv = __float2bfloat16(s);
        Uh[(size_t)col * DMODEL + f] = hv;
        Ul[(size_t)col * DMODEL + f] = __float2bfloat16(s - __bfloat162float(hv));
    }
}

// ---------------------------------------------------------------------------
// D: blocks [0,192): fused QKV GEMM, 128x128 tiles, counted-vmcnt pipeline.
//    blocks [192,256): score GEMM S = (xh+xl)@(Uh+Ul)^T (64x64, 3-term).
// Epilogues: Q,K -> bf16 [n][D]; V -> bf16 transposed Vt[f][n] via LDS.
// ---------------------------------------------------------------------------
__global__ __launch_bounds__(256) void qkv_score_kernel(
    const __hip_bfloat16* __restrict__ xh, const __hip_bfloat16* __restrict__ xl,
    const __hip_bfloat16* __restrict__ Wqh, const __hip_bfloat16* __restrict__ Wkh,
    const __hip_bfloat16* __restrict__ Wvh,
    const __hip_bfloat16* __restrict__ Uh, const __hip_bfloat16* __restrict__ Ul,
    __hip_bfloat16* __restrict__ Qb, __hip_bfloat16* __restrict__ Kb,
    __hip_bfloat16* __restrict__ Vt, float* __restrict__ S)
{
    __shared__ alignas(16) char smem[65536];

    const int b = blockIdx.x;
    const int tid  = threadIdx.x;
    const int wave = tid >> 6;
    const int lane = tid & 63;
    const int fr = lane & 15;
    const int quad = lane >> 4;

    if (b < 192) {
        // ---- fused QKV GEMM, 128x128 tile, counted-vmcnt dbuf pipeline ----
        __hip_bfloat16* A0 = (__hip_bfloat16*)smem;             // 16 KB
        __hip_bfloat16* B0 = (__hip_bfloat16*)(smem + 16384);   // 16 KB
        __hip_bfloat16* A1 = (__hip_bfloat16*)(smem + 32768);
        __hip_bfloat16* B1 = (__hip_bfloat16*)(smem + 49152);

        const int widx = b >> 6;              // 0=Q 1=K 2=V
        const int t = b & 63;
        const int m0 = (t >> 3) * 128;
        const int n0 = (t & 7) * 128;
        const __hip_bfloat16* __restrict__ Bw =
            (widx == 0) ? Wqh : (widx == 1) ? Wkh : Wvh;

        const int wm = (wave >> 1) * 64;
        const int wn = (wave & 1) * 64;

        f32x4 acc[4][4] = {};

        // prologue: stage tile 0, full drain
        stage128(xh + (size_t)m0 * DMODEL, A0, wave, lane);
        stage128(Bw + (size_t)n0 * DMODEL, B0, wave, lane);
        asm volatile("s_waitcnt vmcnt(0)" ::: "memory");
        __builtin_amdgcn_sched_barrier(0);
        __builtin_amdgcn_s_barrier();

        for (int kt = 0; kt < 16; kt++) {
            const int cur = kt & 1;
            __hip_bfloat16* Ac = cur ? A1 : A0;
            __hip_bfloat16* Bc = cur ? B1 : B0;
            if (kt < 15) {
                __hip_bfloat16* An = cur ? A0 : A1;
                __hip_bfloat16* Bn = cur ? B0 : B1;
                // issue next tile's 8 loads/wave; they fly during compute(kt)
                stage128(xh + (size_t)m0 * DMODEL + (kt + 1) * 64, An, wave, lane);
                stage128(Bw + (size_t)n0 * DMODEL + (kt + 1) * 64, Bn, wave, lane);
                asm volatile("s_waitcnt vmcnt(8)" ::: "memory");  // tile kt landed
            } else {
                // tail: tile-15 loads (issued at kt=14) may still be in flight
                asm volatile("s_waitcnt vmcnt(0)" ::: "memory");
            }
            __builtin_amdgcn_sched_barrier(0);
            __builtin_amdgcn_s_barrier();      // all waves' tile-kt rows visible
            __builtin_amdgcn_sched_barrier(0);

            #pragma unroll
            for (int hk = 0; hk < 2; hk++) {
                const int ch = hk * 4 + quad;
                short8 am[4], bn[4];
                #pragma unroll
                for (int i = 0; i < 4; i++) am[i] = ldsfrag(Ac, wm + i * 16 + fr, ch);
                #pragma unroll
                for (int j = 0; j < 4; j++) bn[j] = ldsfrag(Bc, wn + j * 16 + fr, ch);
                #pragma unroll
                for (int i = 0; i < 4; i++)
                #pragma unroll
                for (int j = 0; j < 4; j++)
                    acc[i][j] = __builtin_amdgcn_mfma_f32_16x16x32_bf16(am[i], bn[j], acc[i][j], 0, 0, 0);
            }
            __builtin_amdgcn_sched_barrier(0);
            __builtin_amdgcn_s_barrier();      // reads done before buf reuse
            __builtin_amdgcn_sched_barrier(0);
        }

        if (widx == 0 || widx == 1) {
            __hip_bfloat16* __restrict__ Out = (widx == 0) ? Qb : Kb;
            #pragma unroll
            for (int i = 0; i < 4; i++)
            #pragma unroll
            for (int j = 0; j < 4; j++)
            #pragma unroll
            for (int r = 0; r < 4; r++) {
                int row = m0 + wm + i * 16 + quad * 4 + r;
                int col = n0 + wn + j * 16 + fr;
                Out[(size_t)row * DMODEL + col] = __float2bfloat16(acc[i][j][r]);
            }
        } else {
            // V: transpose 128x128 via LDS in two 64-col passes -> Vt[f][n]
            __hip_bfloat16 (*T)[136] = (__hip_bfloat16(*)[136])smem;
            for (int p = 0; p < 2; p++) {
                __syncthreads();
                if ((wn >> 6) == p) {
                    #pragma unroll
                    for (int i = 0; i < 4; i++)
                    #pragma unroll
                    for (int j = 0; j < 4; j++)
                    #pragma unroll
                    for (int r = 0; r < 4; r++) {
                        int nloc = wm + i * 16 + quad * 4 + r;        // 0..127
                        int floc = (wn - p * 64) + j * 16 + fr;       // 0..63
                        T[floc][nloc] = __float2bfloat16(acc[i][j][r]);
                    }
                }
                __syncthreads();
                const int row = tid >> 2;             // 0..63
                const int cb  = (tid & 3) * 32;       // col base (elems)
                const size_t o = (size_t)(n0 + p * 64 + row) * NTOK + m0 + cb;
                #pragma unroll
                for (int u = 0; u < 4; u++)
                    *(uint4*)(Vt + o + u * 8) = *(uint4*)(&T[row][cb + u * 8]);
            }
        }
    } else {
        // ---- score GEMM: S = (xh+xl) @ (Uh+Ul)^T, 3-term split ----
        __hip_bfloat16* AshP = (__hip_bfloat16*)smem;
        __hip_bfloat16* AslP = (__hip_bfloat16*)(smem + 8192);
        __hip_bfloat16* BshP = (__hip_bfloat16*)(smem + 16384);
        __hip_bfloat16* BslP = (__hip_bfloat16*)(smem + 24576);

        const int wm = (wave >> 1) * 32;
        const int wn = (wave & 1) * 32;

        const int bb = b - 192;                 // [0,64)
        const int m0 = (bb >> 2) * 64;          // 16 token tiles
        const int n0 = (bb & 3) * 64;           // 4 col tiles (256 cols)

        f32x4 acc[2][2] = {};

        for (int k0 = 0; k0 < DMODEL; k0 += 64) {
            stage64(xh + (size_t)m0 * DMODEL + k0, AshP, wave, lane);
            stage64(xl + (size_t)m0 * DMODEL + k0, AslP, wave, lane);
            stage64(Uh + (size_t)n0 * DMODEL + k0, BshP, wave, lane);
            stage64(Ul + (size_t)n0 * DMODEL + k0, BslP, wave, lane);
            __syncthreads();

            #pragma unroll
            for (int hk = 0; hk < 2; hk++) {
                const int ch = hk * 4 + quad;
                short8 a0h = ldsfrag(AshP, wm + fr, ch);
                short8 a1h = ldsfrag(AshP, wm + 16 + fr, ch);
                short8 a0l = ldsfrag(AslP, wm + fr, ch);
                short8 a1l = ldsfrag(AslP, wm + 16 + fr, ch);
                short8 b0h = ldsfrag(BshP, wn + fr, ch);
                short8 b1h = ldsfrag(BshP, wn + 16 + fr, ch);
                short8 b0l = ldsfrag(BslP, wn + fr, ch);
                short8 b1l = ldsfrag(BslP, wn + 16 + fr, ch);
                acc[0][0] = __builtin_amdgcn_mfma_f32_16x16x32_bf16(a0l, b0h, acc[0][0], 0, 0, 0);
                acc[0][1] = __builtin_amdgcn_mfma_f32_16x16x32_bf16(a0l, b1h, acc[0][1], 0, 0, 0);
                acc[1][0] = __builtin_amdgcn_mfma_f32_16x16x32_bf16(a1l, b0h, acc[1][0], 0, 0, 0);
                acc[1][1] = __builtin_amdgcn_mfma_f32_16x16x32_bf16(a1l, b1h, acc[1][1], 0, 0, 0);
                acc[0][0] = __builtin_amdgcn_mfma_f32_16x16x32_bf16(a0h, b0l, acc[0][0], 0, 0, 0);
                acc[0][1] = __builtin_amdgcn_mfma_f32_16x16x32_bf16(a0h, b1l, acc[0][1], 0, 0, 0);
                acc[1][0] = __builtin_amdgcn_mfma_f32_16x16x32_bf16(a1h, b0l, acc[1][0], 0, 0, 0);
                acc[1][1] = __builtin_amdgcn_mfma_f32_16x16x32_bf16(a1h, b1l, acc[1][1], 0, 0, 0);
                acc[0][0] = __builtin_amdgcn_mfma_f32_16x16x32_bf16(a0h, b0h, acc[0][0], 0, 0, 0);
                acc[0][1] = __builtin_amdgcn_mfma_f32_16x16x32_bf16(a0h, b1h, acc[0][1], 0, 0, 0);
                acc[1][0] = __builtin_amdgcn_mfma_f32_16x16x32_bf16(a1h, b0h, acc[1][0], 0, 0, 0);
                acc[1][1] = __builtin_amdgcn_mfma_f32_16x16x32_bf16(a1h, b1h, acc[1][1], 0, 0, 0);
            }
            __syncthreads();
        }

        #pragma unroll
        for (int tm = 0; tm < 2; tm++)
        #pragma unroll
        for (int tn = 0; tn < 2; tn++)
        #pragma unroll
        for (int r = 0; r < 4; r++) {
            int row = m0 + wm + tm * 16 + quad * 4 + r;
            int col = n0 + wn + tn * 16 + fr;
            S[(size_t)row * 256 + col] = acc[tm][tn][r];
        }
    }
}

// ---------------------------------------------------------------------------
// E: split-K MFMA attention (unchanged). Grid = (g,h,qtile) = 1024 blocks x
// 4 waves; wave s processes every 4th entry of the union block list; K/V
// frags direct from global; LDS merge with exact softmax combine.
// ---------------------------------------------------------------------------
__global__ __launch_bounds__(256, 4) void attn_mfma_kernel(
    const __hip_bfloat16* __restrict__ Qb, const __hip_bfloat16* __restrict__ Kb,
    const __hip_bfloat16* __restrict__ Vt, const float* __restrict__ S,
    const float2* __restrict__ gate, __hip_bfloat16* __restrict__ oh)
{
    __shared__ float OS[4][16][64];     // per-split inter partial O
    __shared__ float OIs[16][64];       // intra O
    __shared__ float mS[4][16], lS[4][16], liS[16];
    __shared__ int i1s[16], i2s[16];
    __shared__ float2 sgate[16];
    __shared__ unsigned unionMask;
    __shared__ __hip_bfloat16 Ps[4][16][72];   // per-wave P round-trip

    const int bid = blockIdx.x;
    const int qt = bid & 3;
    const int h  = (bid >> 2) & 15;
    const int g  = bid >> 6;
    const int tid = threadIdx.x;
    const int s = tid >> 6;             // wave = key-split id
    const int lane = tid & 63;
    const int fr = lane & 15, quad = lane >> 4;

    // ---- prologue: per-query top-2 (exact tie semantics), gate, union ----
    if (tid < 16) {
        const int n = g * 64 + qt * 16 + tid;
        const float* Sn = S + (size_t)n * 256 + h * 16;
        float sc[NBLK];
        #pragma unroll
        for (int gg = 0; gg < NBLK; gg++)
            sc[gg] = (n >= (gg << 6)) ? -INFINITY : Sn[gg];
        int i1 = -1, i2 = -1;
        float b1 = -INFINITY;
        #pragma unroll
        for (int gg = 0; gg < NBLK; gg++) if (i1 < 0 || sc[gg] > b1) { b1 = sc[gg]; i1 = gg; }
        float b2 = -INFINITY;
        #pragma unroll
        for (int gg = 0; gg < NBLK; gg++) { if (gg == i1) continue; if (i2 < 0 || sc[gg] > b2) { b2 = sc[gg]; i2 = gg; } }
        i1s[tid] = i1; i2s[tid] = i2;
        sgate[tid] = gate[(size_t)n * NHEAD + h];
        unsigned m = (1u << i1) | (1u << i2);
        #pragma unroll
        for (int off = 1; off < 16; off <<= 1) m |= (unsigned)__shfl_xor((int)m, off);
        if (tid == 0) unionMask = m;
    }
    __syncthreads();

    const unsigned um = unionMask;

    // ---- Q A-fragments direct from global ----
    const size_t qrow = (size_t)(g * 64 + qt * 16 + fr) * DMODEL + h * HDIM + quad * 8;
    const short8 qa0 = *(const short8*)(Qb + qrow);
    const short8 qa1 = *(const short8*)(Qb + qrow + 32);

    // per-lane copies of top-2 / gate for this quad's 4 query rows
    int qi1[4], qi2[4];
    #pragma unroll
    for (int r = 0; r < 4; r++) {
        int q = quad * 4 + r;
        qi1[r] = i1s[q]; qi2[r] = i2s[q];
    }

    f32x4 Oint[4] = {};        // inter accumulator (16q x 64d)
    float mrun[4] = {-INFINITY, -INFINITY, -INFINITY, -INFINITY};
    float lrun[4] = {0.f, 0.f, 0.f, 0.f};

    const __hip_bfloat16* __restrict__ Kh = Kb + h * HDIM + quad * 8;
    const __hip_bfloat16* __restrict__ Vh = Vt + (size_t)(h * HDIM) * NTOK + quad * 8;

    int j = 0;
    for (int kb = 0; kb < NBLK; kb++) {
        if (!((um >> kb) & 1u)) continue;
        if ((j++ & 3) != s) continue;

        // ---- QK^T: 16q x 64k, K frags direct from global ----
        f32x4 sacc[4] = {};
        #pragma unroll
        for (int t = 0; t < 4; t++) {
            const size_t krow = (size_t)(kb * 64 + t * 16 + fr) * DMODEL;
            short8 kb0 = *(const short8*)(Kh + krow);
            short8 kb1 = *(const short8*)(Kh + krow + 32);
            sacc[t] = __builtin_amdgcn_mfma_f32_16x16x32_bf16(qa0, kb0, sacc[t], 0, 0, 0);
            sacc[t] = __builtin_amdgcn_mfma_f32_16x16x32_bf16(qa1, kb1, sacc[t], 0, 0, 0);
        }

        // ---- inter online softmax, per-query selected-block gating ----
        #pragma unroll
        for (int r = 0; r < 4; r++) {
            const bool sel = (kb == qi1[r]) | (kb == qi2[r]);   // quad-uniform
            float v0 = sacc[0][r] * 0.125f, v1 = sacc[1][r] * 0.125f;
            float v2 = sacc[2][r] * 0.125f, v3 = sacc[3][r] * 0.125f;
            float mx = qmax16(fmaxf(fmaxf(v0, v1), fmaxf(v2, v3)));
            float mnew = sel ? fmaxf(mrun[r], mx) : mrun[r];
            float f = sel ? __expf(mrun[r] - mnew) : 1.0f;
            float e0 = sel ? __expf(v0 - mnew) : 0.f;
            float e1 = sel ? __expf(v1 - mnew) : 0.f;
            float e2 = sel ? __expf(v2 - mnew) : 0.f;
            float e3 = sel ? __expf(v3 - mnew) : 0.f;
            float es = qsum16(e0 + e1 + e2 + e3);
            lrun[r] = lrun[r] * f + es;
            mrun[r] = mnew;
            #pragma unroll
            for (int dn = 0; dn < 4; dn++) Oint[dn][r] *= f;
            const int prow = quad * 4 + r;
            Ps[s][prow][ 0 + fr] = __float2bfloat16(e0);
            Ps[s][prow][16 + fr] = __float2bfloat16(e1);
            Ps[s][prow][32 + fr] = __float2bfloat16(e2);
            Ps[s][prow][48 + fr] = __float2bfloat16(e3);
        }

        // ---- PV: O += P @ V, V frags direct from global ----
        short8 pa0 = *(const short8*)(&Ps[s][fr][quad * 8]);
        short8 pa1 = *(const short8*)(&Ps[s][fr][32 + quad * 8]);
        #pragma unroll
        for (int dn = 0; dn < 4; dn++) {
            const size_t vrow = (size_t)(dn * 16 + fr) * NTOK + kb * 64;
            short8 v0 = *(const short8*)(Vh + vrow);
            short8 v1 = *(const short8*)(Vh + vrow + 32);
            Oint[dn] = __builtin_amdgcn_mfma_f32_16x16x32_bf16(pa0, v0, Oint[dn], 0, 0, 0);
            Oint[dn] = __builtin_amdgcn_mfma_f32_16x16x32_bf16(pa1, v1, Oint[dn], 0, 0, 0);
        }
    }

    // ---- intra tile (kb == g), owned by split (popcount(um) % 4) ----
    if ((j & 3) == s) {
        f32x4 sacc[4] = {};
        #pragma unroll
        for (int t = 0; t < 4; t++) {
            const size_t krow = (size_t)(g * 64 + t * 16 + fr) * DMODEL;
            short8 kb0 = *(const short8*)(Kh + krow);
            short8 kb1 = *(const short8*)(Kh + krow + 32);
            sacc[t] = __builtin_amdgcn_mfma_f32_16x16x32_bf16(qa0, kb0, sacc[t], 0, 0, 0);
            sacc[t] = __builtin_amdgcn_mfma_f32_16x16x32_bf16(qa1, kb1, sacc[t], 0, 0, 0);
        }
        f32x4 Ointr[4] = {};
        #pragma unroll
        for (int r = 0; r < 4; r++) {
            const int qloc = qt * 16 + quad * 4 + r;   // query row in chunk
            float vv[4];
            #pragma unroll
            for (int t = 0; t < 4; t++) {
                const int col = t * 16 + fr;
                float v = sacc[t][r] * 0.125f;
                vv[t] = (col <= qloc) ? v : -INFINITY;
            }
            float mx = qmax16(fmaxf(fmaxf(vv[0], vv[1]), fmaxf(vv[2], vv[3])));
            float e0 = __expf(vv[0] - mx), e1 = __expf(vv[1] - mx);
            float e2 = __expf(vv[2] - mx), e3 = __expf(vv[3] - mx);
            float lsum = qsum16(e0 + e1 + e2 + e3);
            const int prow = quad * 4 + r;
            if (fr == 0) liS[prow] = lsum;
            Ps[s][prow][ 0 + fr] = __float2bfloat16(e0);
            Ps[s][prow][16 + fr] = __float2bfloat16(e1);
            Ps[s][prow][32 + fr] = __float2bfloat16(e2);
            Ps[s][prow][48 + fr] = __float2bfloat16(e3);
        }
        short8 pa0 = *(const short8*)(&Ps[s][fr][quad * 8]);
        short8 pa1 = *(const short8*)(&Ps[s][fr][32 + quad * 8]);
        f32x4 Ointr2[4] = {};
        #pragma unroll
        for (int dn = 0; dn < 4; dn++) {
            const size_t vrow = (size_t)(dn * 16 + fr) * NTOK + g * 64;
            short8 v0 = *(const short8*)(Vh + vrow);
            short8 v1 = *(const short8*)(Vh + vrow + 32);
            Ointr2[dn] = __builtin_amdgcn_mfma_f32_16x16x32_bf16(pa0, v0, Ointr[dn], 0, 0, 0);
            Ointr2[dn] = __builtin_amdgcn_mfma_f32_16x16x32_bf16(pa1, v1, Ointr2[dn], 0, 0, 0);
        }
        #pragma unroll
        for (int r = 0; r < 4; r++)
        #pragma unroll
        for (int dn = 0; dn < 4; dn++)
            OIs[quad * 4 + r][dn * 16 + fr] = Ointr2[dn][r];
    }

    // ---- publish split partials ----
    #pragma unroll
    for (int r = 0; r < 4; r++) {
        if (fr == 0) { mS[s][quad * 4 + r] = mrun[r]; lS[s][quad * 4 + r] = lrun[r]; }
        #pragma unroll
        for (int dn = 0; dn < 4; dn++)
            OS[s][quad * 4 + r][dn * 16 + fr] = Oint[dn][r];
    }
    __syncthreads();

    // ---- merge splits + gated blend, write oh bf16 ----
    {
        const int q = tid >> 4;
        const int db = (tid & 15) * 4;
        float M = fmaxf(fmaxf(mS[0][q], mS[1][q]), fmaxf(mS[2][q], mS[3][q]));
        float L = 0.f;
        float o0 = 0.f, o1 = 0.f, o2 = 0.f, o3 = 0.f;
        #pragma unroll
        for (int ss = 0; ss < 4; ss++) {
            float p = __expf(mS[ss][q] - M);
            L += lS[ss][q] * p;
            o0 += OS[ss][q][db + 0] * p;
            o1 += OS[ss][q][db + 1] * p;
            o2 += OS[ss][q][db + 2] * p;
            o3 += OS[ss][q][db + 3] * p;
        }
        const float2 gt = sgate[q];
        const float wi = gt.x / L;
        const float wl = gt.y / liS[q];
        unsigned short out4[4];
        out4[0] = __builtin_bit_cast(unsigned short, __float2bfloat16(wi * o0 + wl * OIs[q][db + 0]));
        out4[1] = __builtin_bit_cast(unsigned short, __float2bfloat16(wi * o1 + wl * OIs[q][db + 1]));
        out4[2] = __builtin_bit_cast(unsigned short, __float2bfloat16(wi * o2 + wl * OIs[q][db + 2]));
        out4[3] = __builtin_bit_cast(unsigned short, __float2bfloat16(wi * o3 + wl * OIs[q][db + 3]));
        const int n = g * 64 + qt * 16 + q;
        *(uint2*)(oh + (size_t)n * DMODEL + h * HDIM + db) = *(uint2*)out4;
    }
}

// ---------------------------------------------------------------------------
// F: Wo GEMM: C = oh x (Woh + Wol)^T, 64x64 tile, BK=64, f32 store.
// 8 waves (512 thr); double-buffered counted-vmcnt pipeline (3 loads/wave).
// Scalar shared pointers only (pointer arrays into LDS fail to compile).
// ---------------------------------------------------------------------------
__global__ __launch_bounds__(512) void gemm_wo(
    const __hip_bfloat16* __restrict__ Ah,
    const __hip_bfloat16* __restrict__ Bh, const __hip_bfloat16* __restrict__ Bl,
    float* __restrict__ C)
{
    __shared__ alignas(16) char smem[49152];
    __hip_bfloat16* As0 = (__hip_bfloat16*)smem;
    __hip_bfloat16* Bh0 = (__hip_bfloat16*)(smem + 8192);
    __hip_bfloat16* Bl0 = (__hip_bfloat16*)(smem + 16384);
    __hip_bfloat16* As1 = (__hip_bfloat16*)(smem + 24576);
    __hip_bfloat16* Bh1 = (__hip_bfloat16*)(smem + 32768);
    __hip_bfloat16* Bl1 = (__hip_bfloat16*)(smem + 40960);

    const int n0 = blockIdx.x * 64;
    const int m0 = blockIdx.y * 64;

    const int tid  = threadIdx.x;
    const int wave = tid >> 6;          // 0..7
    const int lane = tid & 63;
    const int wm = (wave >> 1) * 16;    // {0,16,32,48}
    const int wn = (wave & 1) * 32;     // {0,32}
    const int fr = lane & 15;
    const int quad = lane >> 4;

    f32x4 acc[2] = {};

    stage64w8(Ah + (size_t)m0 * DMODEL, As0, wave, lane);
    stage64w8(Bh + (size_t)n0 * DMODEL, Bh0, wave, lane);
    stage64w8(Bl + (size_t)n0 * DMODEL, Bl0, wave, lane);
    asm volatile("s_waitcnt vmcnt(0)" ::: "memory");
    __builtin_amdgcn_sched_barrier(0);
    __builtin_amdgcn_s_barrier();

    for (int kt = 0; kt < 16; kt++) {
        const int cur = kt & 1;
        __hip_bfloat16* Ac  = cur ? As1 : As0;
        __hip_bfloat16* Bhc = cur ? Bh1 : Bh0;
        __hip_bfloat16* Blc = cur ? Bl1 : Bl0;
        if (kt < 15) {
            __hip_bfloat16* An  = cur ? As0 : As1;
            __hip_bfloat16* Bhn = cur ? Bh0 : Bh1;
            __hip_bfloat16* Bln = cur ? Bl0 : Bl1;
            stage64w8(Ah + (size_t)m0 * DMODEL + (kt + 1) * 64, An, wave, lane);
            stage64w8(Bh + (size_t)n0 * DMODEL + (kt + 1) * 64, Bhn, wave, lane);
            stage64w8(Bl + (size_t)n0 * DMODEL + (kt + 1) * 64, Bln, wave, lane);
            asm volatile("s_waitcnt vmcnt(3)" ::: "memory");
        } else {
            // tail: tile-15 loads may still be in flight — full drain
            asm volatile("s_waitcnt vmcnt(0)" ::: "memory");
        }
        __builtin_amdgcn_sched_barrier(0);
        __builtin_amdgcn_s_barrier();
        __builtin_amdgcn_sched_barrier(0);

        #pragma unroll
        for (int hk = 0; hk < 2; hk++) {
            const int ch = hk * 4 + quad;
            short8 a0  = ldsfrag(Ac, wm + fr, ch);
            short8 b0h = ldsfrag(Bhc, wn + fr, ch);
            short8 b1h = ldsfrag(Bhc, wn + 16 + fr, ch);
            short8 b0l = ldsfrag(Blc, wn + fr, ch);
            short8 b1l = ldsfrag(Blc, wn + 16 + fr, ch);
            acc[0] = __builtin_amdgcn_mfma_f32_16x16x32_bf16(a0, b0l, acc[0], 0, 0, 0);
            acc[1] = __builtin_amdgcn_mfma_f32_16x16x32_bf16(a0, b1l, acc[1], 0, 0, 0);
            acc[0] = __builtin_amdgcn_mfma_f32_16x16x32_bf16(a0, b0h, acc[0], 0, 0, 0);
            acc[1] = __builtin_amdgcn_mfma_f32_16x16x32_bf16(a0, b1h, acc[1], 0, 0, 0);
        }
        __builtin_amdgcn_sched_barrier(0);
        __builtin_amdgcn_s_barrier();
        __builtin_amdgcn_sched_barrier(0);
    }

    #pragma unroll
    for (int tn = 0; tn < 2; tn++)
    #pragma unroll
    for (int r = 0; r < 4; r++) {
        int row = m0 + wm + quad * 4 + r;
        int col = n0 + wn + tn * 16 + fr;
        C[(size_t)row * DMODEL + col] = acc[tn][r];
    }
}

// ---------------------------------------------------------------------------
extern "C" void kernel_launch(void* const* d_in, const int* in_sizes, int n_in,
                              void* d_out, int out_size, void* d_ws, size_t ws_size,
                              hipStream_t stream)
{
    const float* x  = (const float*)d_in[0];
    const float* Wq = (const float*)d_in[1];
    const float* Wk = (const float*)d_in[2];
    const float* Wv = (const float*)d_in[3];
    const float* Wg = (const float*)d_in[4];
    const float* Wo = (const float*)d_in[5];

    const size_t M1 = (size_t)NTOK * DMODEL;   // 1M elems

    // workspace layout (~24.5 MB)
    float* S       = (float*)d_ws;                    // 1 MB (scores [1024][256])
    float* xm      = S + (size_t)NTOK * 256;          // 64 KB
    float* kc      = xm + NBLK * DMODEL;              // 64 KB
    float2* gate   = (float2*)(kc + NBLK * DMODEL);   // 128 KB
    __hip_bfloat16* xh  = (__hip_bfloat16*)(gate + NTOK * NHEAD);   // 2 MB
    __hip_bfloat16* xl  = xh + M1;     // 2 MB
    __hip_bfloat16* Wqh = xl + M1;     // 2 MB
    __hip_bfloat16* Wkh = Wqh + M1;    // 2 MB
    __hip_bfloat16* Wvh = Wkh + M1;    // 2 MB
    __hip_bfloat16* Woh = Wvh + M1;    // 2 MB
    __hip_bfloat16* Wol = Woh + M1;    // 2 MB
    __hip_bfloat16* oh  = Wol + M1;    // 2 MB
    __hip_bfloat16* Uh  = oh + M1;     // 512 KB ([256][1024])
    __hip_bfloat16* Ul  = Uh + 256 * DMODEL;  // 512 KB
    __hip_bfloat16* Qb  = Ul + 256 * DMODEL;  // 2 MB  bf16 [n][D]
    __hip_bfloat16* Kb  = Qb + M1;            // 2 MB  bf16 [n][D]
    __hip_bfloat16* Vt  = Kb + M1;            // 2 MB  bf16 [f][n] (transposed)

    prep_kernel<<<6208, 256, 0, stream>>>(
        x, Wq, Wk, Wv, Wo, Wg, xh, xl, Wqh, Wkh, Wvh, Woh, Wol, xm, gate);

    kc_gemm_kernel<<<1024, 256, 0, stream>>>(xm, Wk, kc);
    u_kernel<<<256, 256, 0, stream>>>(kc, Wq, Uh, Ul);

    qkv_score_kernel<<<256, 256, 0, stream>>>(
        xh, xl, Wqh, Wkh, Wvh, Uh, Ul, Qb, Kb, Vt, S);

    attn_mfma_kernel<<<NBLK * NHEAD * 4, 256, 0, stream>>>(Qb, Kb, Vt, S, gate, oh);

    dim3 gwo(16, 16);
    gemm_wo<<<gwo, 512, 0, stream>>>(oh, Woh, Wol, (float*)d_out);
}

// Round 8
// 143.501 us; speedup vs baseline: 1.3510x; 1.0815x over previous
//
#include <hip/hip_runtime.h>
#include <hip/hip_bf16.h>
#include <math.h>

// Problem: B=1, N=1024, D=1024, H=16, C=64, TOPK=2, HD=64, G=16
//
// Round-8: remove redundant L2 traffic in the two small kernels.
// (1) gate moved from prep (1024 blocks re-reading Wg 128KB each ≈ 135 MB L2)
//     into qkv_score as a 16-block GEMM: xg = (xh+xl)@(Wgh+Wgl)^T (3-term
//     bf16 split) + 2-way softmax epilogue via shfl_xor pairing. Gate feeds
//     only the blend (not top-2 selection) -> no flip risk.
// (2) u_kernel: 256 blocks x 256KB Wq reads (64 MB, 16x redundant) -> 128
//     blocks (h x f-slice-128) reading each Wq slice once (4 MB), reused
//     across all 16 g in registers. d-accumulation order IDENTICAL ->
//     bit-identical U. GEMM pipelines unchanged from round 7.

typedef __attribute__((ext_vector_type(8))) short short8;   // 8 bf16 = 4 VGPRs
typedef __attribute__((ext_vector_type(4))) float f32x4;

#define NTOK 1024
#define DMODEL 1024
#define NHEAD 16
#define HDIM 64
#define CHUNK 64
#define NBLK 16

__device__ __forceinline__ float qmax16(float v)
{
    #pragma unroll
    for (int off = 1; off < 16; off <<= 1) v = fmaxf(v, __shfl_xor(v, off));
    return v;
}

__device__ __forceinline__ float qsum16(float v)
{
    #pragma unroll
    for (int off = 1; off < 16; off <<= 1) v += __shfl_xor(v, off);
    return v;
}

// ---- async-staged bf16 tile helpers (linear LDS + XOR swizzle) ----
// LDS[row][slot] (slot = 16B chunk, 8 per 128B row) holds global chunk
// slot ^ (row & 7). Reader of logical chunk c reads slot c ^ (row & 7).

#define GLOAD_LDS16(gp, lp)                                              \
    __builtin_amdgcn_global_load_lds(                                    \
        (const __attribute__((address_space(1))) void*)(gp),             \
        (__attribute__((address_space(3))) void*)(lp), 16, 0, 0)

// 64-row tile, 4 waves: wave w stages rows [w*16, w*16+16). 2 loads/wave.
__device__ __forceinline__ void stage64(const __hip_bfloat16* __restrict__ g0,
                                        __hip_bfloat16* t, int wave, int lane)
{
    const int sub = lane >> 3;              // row within 8-row group
    const int cch = (lane & 7) ^ sub;       // pre-swizzled source chunk
    #pragma unroll
    for (int j = 0; j < 2; j++) {
        const int rr = (2 * wave + j) * 8 + sub;
        GLOAD_LDS16(g0 + (size_t)rr * DMODEL + cch * 8, t + (2 * wave + j) * 512);
    }
}

// 128-row tile, 4 waves: wave w stages rows [w*32, w*32+32). 4 loads/wave.
__device__ __forceinline__ void stage128(const __hip_bfloat16* __restrict__ g0,
                                         __hip_bfloat16* t, int wave, int lane)
{
    const int sub = lane >> 3;
    const int cch = (lane & 7) ^ sub;
    #pragma unroll
    for (int j = 0; j < 4; j++) {
        const int grp = wave * 4 + j;
        GLOAD_LDS16(g0 + (size_t)(grp * 8 + sub) * DMODEL + cch * 8, t + grp * 512);
    }
}

// 8-rows-per-wave tile: wave w stages rows [w*8, w*8+8). 1 load/wave.
// (with 4 waves: 32 rows; with 8 waves: 64 rows)
__device__ __forceinline__ void stage64w8(const __hip_bfloat16* __restrict__ g0,
                                          __hip_bfloat16* t, int wave, int lane)
{
    const int sub = lane >> 3;
    const int cch = (lane & 7) ^ sub;
    GLOAD_LDS16(g0 + (size_t)(wave * 8 + sub) * DMODEL + cch * 8, t + wave * 512);
}

// swizzled fragment read: logical (row, chunk) -> 16B
__device__ __forceinline__ short8 ldsfrag(const __hip_bfloat16* t, int row, int chunk)
{
    return *(const short8*)((const char*)t + row * 128 + (((chunk) ^ (row & 7)) << 4));
}

// ---------------------------------------------------------------------------
// A: prep. blockIdx roles: [0,5120) casts (which = bid>>10: 0 x split,
// 1 Wq hi, 2 Wk hi, 3 Wv hi, 4 Wo split), [5120,5184) xm,
// [5184,5216) Wg hi/lo cast (32 blocks). Gate moved to qkv_score.
// ---------------------------------------------------------------------------
__global__ __launch_bounds__(256) void prep_kernel(
    const float* __restrict__ x,  const float* __restrict__ Wq,
    const float* __restrict__ Wk, const float* __restrict__ Wv,
    const float* __restrict__ Wo, const float* __restrict__ Wg,
    __hip_bfloat16* __restrict__ xh,  __hip_bfloat16* __restrict__ xl,
    __hip_bfloat16* __restrict__ Wqh,
    __hip_bfloat16* __restrict__ Wkh, __hip_bfloat16* __restrict__ Wvh,
    __hip_bfloat16* __restrict__ Woh, __hip_bfloat16* __restrict__ Wol,
    __hip_bfloat16* __restrict__ Wgh, __hip_bfloat16* __restrict__ Wgl,
    float* __restrict__ xm)
{
    const int bid = blockIdx.x;
    if (bid < 5120) {
        const int which = bid >> 10;
        const int b = bid & 1023;
        const int i = (b * 256 + threadIdx.x) * 4;
        const float* in; __hip_bfloat16 *hi, *lo = nullptr;
        if (which == 0)      { in = x;  hi = xh;  lo = xl; }
        else if (which == 1) { in = Wq; hi = Wqh; }
        else if (which == 2) { in = Wk; hi = Wkh; }
        else if (which == 3) { in = Wv; hi = Wvh; }
        else                 { in = Wo; hi = Woh; lo = Wol; }
        float4 v = *(const float4*)(in + i);
        float vv[4] = {v.x, v.y, v.z, v.w};
        __hip_bfloat16 h[4], l[4];
        #pragma unroll
        for (int j = 0; j < 4; j++) {
            h[j] = __float2bfloat16(vv[j]);
            l[j] = __float2bfloat16(vv[j] - __bfloat162float(h[j]));
        }
        *(uint2*)(hi + i) = *(uint2*)h;
        if (lo) *(uint2*)(lo + i) = *(uint2*)l;
    } else if (bid < 5184) {
        const int b = bid - 5120;
        const int g = b >> 2;
        const int f = (b & 3) * 256 + threadIdx.x;
        float s = 0.f;
        #pragma unroll 8
        for (int c = 0; c < CHUNK; c++) s += x[(size_t)(g * CHUNK + c) * DMODEL + f];
        xm[g * DMODEL + f] = s * (1.0f / CHUNK);
    } else {
        // Wg hi/lo cast: 32 blocks x 256 thr x 4 elems = 32768 = 32*1024
        const int b = bid - 5184;
        const int i = (b * 256 + threadIdx.x) * 4;
        float4 v = *(const float4*)(Wg + i);
        float vv[4] = {v.x, v.y, v.z, v.w};
        __hip_bfloat16 h[4], l[4];
        #pragma unroll
        for (int j = 0; j < 4; j++) {
            h[j] = __float2bfloat16(vv[j]);
            l[j] = __float2bfloat16(vv[j] - __bfloat162float(h[j]));
        }
        *(uint2*)(Wgh + i) = *(uint2*)h;
        *(uint2*)(Wgl + i) = *(uint2*)l;
    }
}

// ---------------------------------------------------------------------------
// B: kc = xm @ Wk^T (exact f32). One block per f; (g = tid>>4, sub = tid&15).
// ---------------------------------------------------------------------------
__global__ __launch_bounds__(256) void kc_gemm_kernel(
    const float* __restrict__ xm, const float* __restrict__ Wk,
    float* __restrict__ kc)
{
    const int f = blockIdx.x;
    const int g = threadIdx.x >> 4;
    const int sub = threadIdx.x & 15;
    const float* wrow = Wk + (size_t)f * DMODEL;
    float s = 0.f;
    #pragma unroll 16
    for (int i = 0; i < 64; i++) {
        int e = i * 16 + sub;
        s += xm[g * DMODEL + e] * wrow[e];
    }
    #pragma unroll
    for (int off = 8; off; off >>= 1) s += __shfl_xor(s, off);
    if (sub == 0) kc[g * DMODEL + f] = s;
}

// ---------------------------------------------------------------------------
// C: U[(h<<4)|g][f] = sum_d kc[g][h*64+d] * Wq[h*64+d][f]  (exact f32, same
// ascending-d order as before -> bit-identical U). Block = (h, f-slice-128):
// 128 blocks; Wq slice read ONCE per block, reused across all 16 g.
// ---------------------------------------------------------------------------
__global__ __launch_bounds__(256) void u_kernel(
    const float* __restrict__ kc, const float* __restrict__ Wq,
    __hip_bfloat16* __restrict__ Uh, __hip_bfloat16* __restrict__ Ul)
{
    __shared__ float kcs[16][64];
    const int h = blockIdx.x >> 3, fs = blockIdx.x & 7;
    for (int i = threadIdx.x; i < 1024; i += 256) {
        int g = i >> 6, d = i & 63;
        kcs[g][d] = kc[g * DMODEL + h * HDIM + d];
    }
    __syncthreads();
    const int f = fs * 128 + (threadIdx.x & 127);
    const int gh = threadIdx.x >> 7;      // 0..1 -> g range [gh*8, gh*8+8)
    float acc[8] = {};
    for (int d = 0; d < 64; d++) {
        float wv = Wq[(size_t)(h * HDIM + d) * DMODEL + f];
        #pragma unroll
        for (int gg = 0; gg < 8; gg++)
            acc[gg] += kcs[gh * 8 + gg][d] * wv;
    }
    #pragma unroll
    for (int gg = 0; gg < 8; gg++) {
        const int col = (h << 4) | (gh * 8 + gg);
        float s = acc[gg];
        __hip_bfloat16 hv = __float2bfloat16(s);
        Uh[(size_t)col * DMODEL + f] = hv;
        Ul[(size_t)col * DMODEL + f] = __float2bfloat16(s - __bfloat162float(hv));
    }
}

// ---------------------------------------------------------------------------
// D: blocks [0,192): fused QKV GEMM, 128x128 tiles, counted-vmcnt pipeline.
//    blocks [192,256): score GEMM S = (xh+xl)@(Uh+Ul)^T (64x64, 3-term).
//    blocks [256,272): gate GEMM xg = (xh+xl)@(Wgh+Wgl)^T + pair softmax.
// Epilogues: Q,K -> bf16 [n][D]; V -> bf16 transposed Vt[f][n] via LDS.
// ---------------------------------------------------------------------------
__global__ __launch_bounds__(256) void qkv_score_kernel(
    const __hip_bfloat16* __restrict__ xh, const __hip_bfloat16* __restrict__ xl,
    const __hip_bfloat16* __restrict__ Wqh, const __hip_bfloat16* __restrict__ Wkh,
    const __hip_bfloat16* __restrict__ Wvh,
    const __hip_bfloat16* __restrict__ Uh, const __hip_bfloat16* __restrict__ Ul,
    const __hip_bfloat16* __restrict__ Wgh, const __hip_bfloat16* __restrict__ Wgl,
    __hip_bfloat16* __restrict__ Qb, __hip_bfloat16* __restrict__ Kb,
    __hip_bfloat16* __restrict__ Vt, float* __restrict__ S,
    float2* __restrict__ gate)
{
    __shared__ alignas(16) char smem[65536];

    const int b = blockIdx.x;
    const int tid  = threadIdx.x;
    const int wave = tid >> 6;
    const int lane = tid & 63;
    const int fr = lane & 15;
    const int quad = lane >> 4;

    if (b < 192) {
        // ---- fused QKV GEMM, 128x128 tile, counted-vmcnt dbuf pipeline ----
        __hip_bfloat16* A0 = (__hip_bfloat16*)smem;             // 16 KB
        __hip_bfloat16* B0 = (__hip_bfloat16*)(smem + 16384);   // 16 KB
        __hip_bfloat16* A1 = (__hip_bfloat16*)(smem + 32768);
        __hip_bfloat16* B1 = (__hip_bfloat16*)(smem + 49152);

        const int widx = b >> 6;              // 0=Q 1=K 2=V
        const int t = b & 63;
        const int m0 = (t >> 3) * 128;
        const int n0 = (t & 7) * 128;
        const __hip_bfloat16* __restrict__ Bw =
            (widx == 0) ? Wqh : (widx == 1) ? Wkh : Wvh;

        const int wm = (wave >> 1) * 64;
        const int wn = (wave & 1) * 64;

        f32x4 acc[4][4] = {};

        // prologue: stage tile 0, full drain
        stage128(xh + (size_t)m0 * DMODEL, A0, wave, lane);
        stage128(Bw + (size_t)n0 * DMODEL, B0, wave, lane);
        asm volatile("s_waitcnt vmcnt(0)" ::: "memory");
        __builtin_amdgcn_sched_barrier(0);
        __builtin_amdgcn_s_barrier();

        for (int kt = 0; kt < 16; kt++) {
            const int cur = kt & 1;
            __hip_bfloat16* Ac = cur ? A1 : A0;
            __hip_bfloat16* Bc = cur ? B1 : B0;
            if (kt < 15) {
                __hip_bfloat16* An = cur ? A0 : A1;
                __hip_bfloat16* Bn = cur ? B0 : B1;
                // issue next tile's 8 loads/wave; they fly during compute(kt)
                stage128(xh + (size_t)m0 * DMODEL + (kt + 1) * 64, An, wave, lane);
                stage128(Bw + (size_t)n0 * DMODEL + (kt + 1) * 64, Bn, wave, lane);
                asm volatile("s_waitcnt vmcnt(8)" ::: "memory");  // tile kt landed
            } else {
                // tail: tile-15 loads (issued at kt=14) may still be in flight
                asm volatile("s_waitcnt vmcnt(0)" ::: "memory");
            }
            __builtin_amdgcn_sched_barrier(0);
            __builtin_amdgcn_s_barrier();      // all waves' tile-kt rows visible
            __builtin_amdgcn_sched_barrier(0);

            #pragma unroll
            for (int hk = 0; hk < 2; hk++) {
                const int ch = hk * 4 + quad;
                short8 am[4], bn[4];
                #pragma unroll
                for (int i = 0; i < 4; i++) am[i] = ldsfrag(Ac, wm + i * 16 + fr, ch);
                #pragma unroll
                for (int j = 0; j < 4; j++) bn[j] = ldsfrag(Bc, wn + j * 16 + fr, ch);
                #pragma unroll
                for (int i = 0; i < 4; i++)
                #pragma unroll
                for (int j = 0; j < 4; j++)
                    acc[i][j] = __builtin_amdgcn_mfma_f32_16x16x32_bf16(am[i], bn[j], acc[i][j], 0, 0, 0);
            }
            __builtin_amdgcn_sched_barrier(0);
            __builtin_amdgcn_s_barrier();      // reads done before buf reuse
            __builtin_amdgcn_sched_barrier(0);
        }

        if (widx == 0 || widx == 1) {
            __hip_bfloat16* __restrict__ Out = (widx == 0) ? Qb : Kb;
            #pragma unroll
            for (int i = 0; i < 4; i++)
            #pragma unroll
            for (int j = 0; j < 4; j++)
            #pragma unroll
            for (int r = 0; r < 4; r++) {
                int row = m0 + wm + i * 16 + quad * 4 + r;
                int col = n0 + wn + j * 16 + fr;
                Out[(size_t)row * DMODEL + col] = __float2bfloat16(acc[i][j][r]);
            }
        } else {
            // V: transpose 128x128 via LDS in two 64-col passes -> Vt[f][n]
            __hip_bfloat16 (*T)[136] = (__hip_bfloat16(*)[136])smem;
            for (int p = 0; p < 2; p++) {
                __syncthreads();
                if ((wn >> 6) == p) {
                    #pragma unroll
                    for (int i = 0; i < 4; i++)
                    #pragma unroll
                    for (int j = 0; j < 4; j++)
                    #pragma unroll
                    for (int r = 0; r < 4; r++) {
                        int nloc = wm + i * 16 + quad * 4 + r;        // 0..127
                        int floc = (wn - p * 64) + j * 16 + fr;       // 0..63
                        T[floc][nloc] = __float2bfloat16(acc[i][j][r]);
                    }
                }
                __syncthreads();
                const int row = tid >> 2;             // 0..63
                const int cb  = (tid & 3) * 32;       // col base (elems)
                const size_t o = (size_t)(n0 + p * 64 + row) * NTOK + m0 + cb;
                #pragma unroll
                for (int u = 0; u < 4; u++)
                    *(uint4*)(Vt + o + u * 8) = *(uint4*)(&T[row][cb + u * 8]);
            }
        }
    } else if (b < 256) {
        // ---- score GEMM: S = (xh+xl) @ (Uh+Ul)^T, 3-term split ----
        __hip_bfloat16* AshP = (__hip_bfloat16*)smem;
        __hip_bfloat16* AslP = (__hip_bfloat16*)(smem + 8192);
        __hip_bfloat16* BshP = (__hip_bfloat16*)(smem + 16384);
        __hip_bfloat16* BslP = (__hip_bfloat16*)(smem + 24576);

        const int wm = (wave >> 1) * 32;
        const int wn = (wave & 1) * 32;

        const int bb = b - 192;                 // [0,64)
        const int m0 = (bb >> 2) * 64;          // 16 token tiles
        const int n0 = (bb & 3) * 64;           // 4 col tiles (256 cols)

        f32x4 acc[2][2] = {};

        for (int k0 = 0; k0 < DMODEL; k0 += 64) {
            stage64(xh + (size_t)m0 * DMODEL + k0, AshP, wave, lane);
            stage64(xl + (size_t)m0 * DMODEL + k0, AslP, wave, lane);
            stage64(Uh + (size_t)n0 * DMODEL + k0, BshP, wave, lane);
            stage64(Ul + (size_t)n0 * DMODEL + k0, BslP, wave, lane);
            __syncthreads();

            #pragma unroll
            for (int hk = 0; hk < 2; hk++) {
                const int ch = hk * 4 + quad;
                short8 a0h = ldsfrag(AshP, wm + fr, ch);
                short8 a1h = ldsfrag(AshP, wm + 16 + fr, ch);
                short8 a0l = ldsfrag(AslP, wm + fr, ch);
                short8 a1l = ldsfrag(AslP, wm + 16 + fr, ch);
                short8 b0h = ldsfrag(BshP, wn + fr, ch);
                short8 b1h = ldsfrag(BshP, wn + 16 + fr, ch);
                short8 b0l = ldsfrag(BslP, wn + fr, ch);
                short8 b1l = ldsfrag(BslP, wn + 16 + fr, ch);
                acc[0][0] = __builtin_amdgcn_mfma_f32_16x16x32_bf16(a0l, b0h, acc[0][0], 0, 0, 0);
                acc[0][1] = __builtin_amdgcn_mfma_f32_16x16x32_bf16(a0l, b1h, acc[0][1], 0, 0, 0);
                acc[1][0] = __builtin_amdgcn_mfma_f32_16x16x32_bf16(a1l, b0h, acc[1][0], 0, 0, 0);
                acc[1][1] = __builtin_amdgcn_mfma_f32_16x16x32_bf16(a1l, b1h, acc[1][1], 0, 0, 0);
                acc[0][0] = __builtin_amdgcn_mfma_f32_16x16x32_bf16(a0h, b0l, acc[0][0], 0, 0, 0);
                acc[0][1] = __builtin_amdgcn_mfma_f32_16x16x32_bf16(a0h, b1l, acc[0][1], 0, 0, 0);
                acc[1][0] = __builtin_amdgcn_mfma_f32_16x16x32_bf16(a1h, b0l, acc[1][0], 0, 0, 0);
                acc[1][1] = __builtin_amdgcn_mfma_f32_16x16x32_bf16(a1h, b1l, acc[1][1], 0, 0, 0);
                acc[0][0] = __builtin_amdgcn_mfma_f32_16x16x32_bf16(a0h, b0h, acc[0][0], 0, 0, 0);
                acc[0][1] = __builtin_amdgcn_mfma_f32_16x16x32_bf16(a0h, b1h, acc[0][1], 0, 0, 0);
                acc[1][0] = __builtin_amdgcn_mfma_f32_16x16x32_bf16(a1h, b0h, acc[1][0], 0, 0, 0);
                acc[1][1] = __builtin_amdgcn_mfma_f32_16x16x32_bf16(a1h, b1h, acc[1][1], 0, 0, 0);
            }
            __syncthreads();
        }

        #pragma unroll
        for (int tm = 0; tm < 2; tm++)
        #pragma unroll
        for (int tn = 0; tn < 2; tn++)
        #pragma unroll
        for (int r = 0; r < 4; r++) {
            int row = m0 + wm + tm * 16 + quad * 4 + r;
            int col = n0 + wn + tn * 16 + fr;
            S[(size_t)row * 256 + col] = acc[tm][tn][r];
        }
    } else {
        // ---- gate GEMM: xg = (xh+xl) @ (Wgh+Wgl)^T (64x32, 3-term), then
        //      softmax over column pairs (2h, 2h+1) -> gate[n][h] float2.
        __hip_bfloat16* AshP = (__hip_bfloat16*)smem;
        __hip_bfloat16* AslP = (__hip_bfloat16*)(smem + 8192);
        __hip_bfloat16* GhP  = (__hip_bfloat16*)(smem + 16384);   // 32x64 = 4KB
        __hip_bfloat16* GlP  = (__hip_bfloat16*)(smem + 20480);

        const int bb = b - 256;                 // [0,16)
        const int m0 = bb * 64;

        f32x4 acc[2] = {};

        for (int k0 = 0; k0 < DMODEL; k0 += 64) {
            stage64(xh + (size_t)m0 * DMODEL + k0, AshP, wave, lane);
            stage64(xl + (size_t)m0 * DMODEL + k0, AslP, wave, lane);
            stage64w8(Wgh + k0, GhP, wave, lane);   // 4 waves -> rows 0..31
            stage64w8(Wgl + k0, GlP, wave, lane);
            __syncthreads();

            #pragma unroll
            for (int hk = 0; hk < 2; hk++) {
                const int ch = hk * 4 + quad;
                short8 ah  = ldsfrag(AshP, wave * 16 + fr, ch);
                short8 al  = ldsfrag(AslP, wave * 16 + fr, ch);
                short8 b0h = ldsfrag(GhP, fr, ch);
                short8 b1h = ldsfrag(GhP, 16 + fr, ch);
                short8 b0l = ldsfrag(GlP, fr, ch);
                short8 b1l = ldsfrag(GlP, 16 + fr, ch);
                acc[0] = __builtin_amdgcn_mfma_f32_16x16x32_bf16(al, b0h, acc[0], 0, 0, 0);
                acc[1] = __builtin_amdgcn_mfma_f32_16x16x32_bf16(al, b1h, acc[1], 0, 0, 0);
                acc[0] = __builtin_amdgcn_mfma_f32_16x16x32_bf16(ah, b0l, acc[0], 0, 0, 0);
                acc[1] = __builtin_amdgcn_mfma_f32_16x16x32_bf16(ah, b1l, acc[1], 0, 0, 0);
                acc[0] = __builtin_amdgcn_mfma_f32_16x16x32_bf16(ah, b0h, acc[0], 0, 0, 0);
                acc[1] = __builtin_amdgcn_mfma_f32_16x16x32_bf16(ah, b1h, acc[1], 0, 0, 0);
            }
            __syncthreads();
        }

        #pragma unroll
        for (int tn = 0; tn < 2; tn++)
        #pragma unroll
        for (int r = 0; r < 4; r++) {
            float v = acc[tn][r];
            float nb = __shfl_xor(v, 1);       // pair (2h, 2h+1) = (even, odd) fr
            if (!(fr & 1)) {
                float m = fmaxf(v, nb);
                float ea = expf(v - m), eb = expf(nb - m);
                float inv = 1.f / (ea + eb);
                const int hcol = tn * 8 + (fr >> 1);
                const int row = m0 + wave * 16 + quad * 4 + r;
                gate[(size_t)row * NHEAD + hcol] = make_float2(ea * inv, eb * inv);
            }
        }
    }
}

// ---------------------------------------------------------------------------
// E: split-K MFMA attention (unchanged). Grid = (g,h,qtile) = 1024 blocks x
// 4 waves; wave s processes every 4th entry of the union block list; K/V
// frags direct from global; LDS merge with exact softmax combine.
// ---------------------------------------------------------------------------
__global__ __launch_bounds__(256, 4) void attn_mfma_kernel(
    const __hip_bfloat16* __restrict__ Qb, const __hip_bfloat16* __restrict__ Kb,
    const __hip_bfloat16* __restrict__ Vt, const float* __restrict__ S,
    const float2* __restrict__ gate, __hip_bfloat16* __restrict__ oh)
{
    __shared__ float OS[4][16][64];     // per-split inter partial O
    __shared__ float OIs[16][64];       // intra O
    __shared__ float mS[4][16], lS[4][16], liS[16];
    __shared__ int i1s[16], i2s[16];
    __shared__ float2 sgate[16];
    __shared__ unsigned unionMask;
    __shared__ __hip_bfloat16 Ps[4][16][72];   // per-wave P round-trip

    const int bid = blockIdx.x;
    const int qt = bid & 3;
    const int h  = (bid >> 2) & 15;
    const int g  = bid >> 6;
    const int tid = threadIdx.x;
    const int s = tid >> 6;             // wave = key-split id
    const int lane = tid & 63;
    const int fr = lane & 15, quad = lane >> 4;

    // ---- prologue: per-query top-2 (exact tie semantics), gate, union ----
    if (tid < 16) {
        const int n = g * 64 + qt * 16 + tid;
        const float* Sn = S + (size_t)n * 256 + h * 16;
        float sc[NBLK];
        #pragma unroll
        for (int gg = 0; gg < NBLK; gg++)
            sc[gg] = (n >= (gg << 6)) ? -INFINITY : Sn[gg];
        int i1 = -1, i2 = -1;
        float b1 = -INFINITY;
        #pragma unroll
        for (int gg = 0; gg < NBLK; gg++) if (i1 < 0 || sc[gg] > b1) { b1 = sc[gg]; i1 = gg; }
        float b2 = -INFINITY;
        #pragma unroll
        for (int gg = 0; gg < NBLK; gg++) { if (gg == i1) continue; if (i2 < 0 || sc[gg] > b2) { b2 = sc[gg]; i2 = gg; } }
        i1s[tid] = i1; i2s[tid] = i2;
        sgate[tid] = gate[(size_t)n * NHEAD + h];
        unsigned m = (1u << i1) | (1u << i2);
        #pragma unroll
        for (int off = 1; off < 16; off <<= 1) m |= (unsigned)__shfl_xor((int)m, off);
        if (tid == 0) unionMask = m;
    }
    __syncthreads();

    const unsigned um = unionMask;

    // ---- Q A-fragments direct from global ----
    const size_t qrow = (size_t)(g * 64 + qt * 16 + fr) * DMODEL + h * HDIM + quad * 8;
    const short8 qa0 = *(const short8*)(Qb + qrow);
    const short8 qa1 = *(const short8*)(Qb + qrow + 32);

    // per-lane copies of top-2 / gate for this quad's 4 query rows
    int qi1[4], qi2[4];
    #pragma unroll
    for (int r = 0; r < 4; r++) {
        int q = quad * 4 + r;
        qi1[r] = i1s[q]; qi2[r] = i2s[q];
    }

    f32x4 Oint[4] = {};        // inter accumulator (16q x 64d)
    float mrun[4] = {-INFINITY, -INFINITY, -INFINITY, -INFINITY};
    float lrun[4] = {0.f, 0.f, 0.f, 0.f};

    const __hip_bfloat16* __restrict__ Kh = Kb + h * HDIM + quad * 8;
    const __hip_bfloat16* __restrict__ Vh = Vt + (size_t)(h * HDIM) * NTOK + quad * 8;

    int j = 0;
    for (int kb = 0; kb < NBLK; kb++) {
        if (!((um >> kb) & 1u)) continue;
        if ((j++ & 3) != s) continue;

        // ---- QK^T: 16q x 64k, K frags direct from global ----
        f32x4 sacc[4] = {};
        #pragma unroll
        for (int t = 0; t < 4; t++) {
            const size_t krow = (size_t)(kb * 64 + t * 16 + fr) * DMODEL;
            short8 kb0 = *(const short8*)(Kh + krow);
            short8 kb1 = *(const short8*)(Kh + krow + 32);
            sacc[t] = __builtin_amdgcn_mfma_f32_16x16x32_bf16(qa0, kb0, sacc[t], 0, 0, 0);
            sacc[t] = __builtin_amdgcn_mfma_f32_16x16x32_bf16(qa1, kb1, sacc[t], 0, 0, 0);
        }

        // ---- inter online softmax, per-query selected-block gating ----
        #pragma unroll
        for (int r = 0; r < 4; r++) {
            const bool sel = (kb == qi1[r]) | (kb == qi2[r]);   // quad-uniform
            float v0 = sacc[0][r] * 0.125f, v1 = sacc[1][r] * 0.125f;
            float v2 = sacc[2][r] * 0.125f, v3 = sacc[3][r] * 0.125f;
            float mx = qmax16(fmaxf(fmaxf(v0, v1), fmaxf(v2, v3)));
            float mnew = sel ? fmaxf(mrun[r], mx) : mrun[r];
            float f = sel ? __expf(mrun[r] - mnew) : 1.0f;
            float e0 = sel ? __expf(v0 - mnew) : 0.f;
            float e1 = sel ? __expf(v1 - mnew) : 0.f;
            float e2 = sel ? __expf(v2 - mnew) : 0.f;
            float e3 = sel ? __expf(v3 - mnew) : 0.f;
            float es = qsum16(e0 + e1 + e2 + e3);
            lrun[r] = lrun[r] * f + es;
            mrun[r] = mnew;
            #pragma unroll
            for (int dn = 0; dn < 4; dn++) Oint[dn][r] *= f;
            const int prow = quad * 4 + r;
            Ps[s][prow][ 0 + fr] = __float2bfloat16(e0);
            Ps[s][prow][16 + fr] = __float2bfloat16(e1);
            Ps[s][prow][32 + fr] = __float2bfloat16(e2);
            Ps[s][prow][48 + fr] = __float2bfloat16(e3);
        }

        // ---- PV: O += P @ V, V frags direct from global ----
        short8 pa0 = *(const short8*)(&Ps[s][fr][quad * 8]);
        short8 pa1 = *(const short8*)(&Ps[s][fr][32 + quad * 8]);
        #pragma unroll
        for (int dn = 0; dn < 4; dn++) {
            const size_t vrow = (size_t)(dn * 16 + fr) * NTOK + kb * 64;
            short8 v0 = *(const short8*)(Vh + vrow);
            short8 v1 = *(const short8*)(Vh + vrow + 32);
            Oint[dn] = __builtin_amdgcn_mfma_f32_16x16x32_bf16(pa0, v0, Oint[dn], 0, 0, 0);
            Oint[dn] = __builtin_amdgcn_mfma_f32_16x16x32_bf16(pa1, v1, Oint[dn], 0, 0, 0);
        }
    }

    // ---- intra tile (kb == g), owned by split (popcount(um) % 4) ----
    if ((j & 3) == s) {
        f32x4 sacc[4] = {};
        #pragma unroll
        for (int t = 0; t < 4; t++) {
            const size_t krow = (size_t)(g * 64 + t * 16 + fr) * DMODEL;
            short8 kb0 = *(const short8*)(Kh + krow);
            short8 kb1 = *(const short8*)(Kh + krow + 32);
            sacc[t] = __builtin_amdgcn_mfma_f32_16x16x32_bf16(qa0, kb0, sacc[t], 0, 0, 0);
            sacc[t] = __builtin_amdgcn_mfma_f32_16x16x32_bf16(qa1, kb1, sacc[t], 0, 0, 0);
        }
        f32x4 Ointr[4] = {};
        #pragma unroll
        for (int r = 0; r < 4; r++) {
            const int qloc = qt * 16 + quad * 4 + r;   // query row in chunk
            float vv[4];
            #pragma unroll
            for (int t = 0; t < 4; t++) {
                const int col = t * 16 + fr;
                float v = sacc[t][r] * 0.125f;
                vv[t] = (col <= qloc) ? v : -INFINITY;
            }
            float mx = qmax16(fmaxf(fmaxf(vv[0], vv[1]), fmaxf(vv[2], vv[3])));
            float e0 = __expf(vv[0] - mx), e1 = __expf(vv[1] - mx);
            float e2 = __expf(vv[2] - mx), e3 = __expf(vv[3] - mx);
            float lsum = qsum16(e0 + e1 + e2 + e3);
            const int prow = quad * 4 + r;
            if (fr == 0) liS[prow] = lsum;
            Ps[s][prow][ 0 + fr] = __float2bfloat16(e0);
            Ps[s][prow][16 + fr] = __float2bfloat16(e1);
            Ps[s][prow][32 + fr] = __float2bfloat16(e2);
            Ps[s][prow][48 + fr] = __float2bfloat16(e3);
        }
        short8 pa0 = *(const short8*)(&Ps[s][fr][quad * 8]);
        short8 pa1 = *(const short8*)(&Ps[s][fr][32 + quad * 8]);
        f32x4 Ointr2[4] = {};
        #pragma unroll
        for (int dn = 0; dn < 4; dn++) {
            const size_t vrow = (size_t)(dn * 16 + fr) * NTOK + g * 64;
            short8 v0 = *(const short8*)(Vh + vrow);
            short8 v1 = *(const short8*)(Vh + vrow + 32);
            Ointr2[dn] = __builtin_amdgcn_mfma_f32_16x16x32_bf16(pa0, v0, Ointr[dn], 0, 0, 0);
            Ointr2[dn] = __builtin_amdgcn_mfma_f32_16x16x32_bf16(pa1, v1, Ointr2[dn], 0, 0, 0);
        }
        #pragma unroll
        for (int r = 0; r < 4; r++)
        #pragma unroll
        for (int dn = 0; dn < 4; dn++)
            OIs[quad * 4 + r][dn * 16 + fr] = Ointr2[dn][r];
    }

    // ---- publish split partials ----
    #pragma unroll
    for (int r = 0; r < 4; r++) {
        if (fr == 0) { mS[s][quad * 4 + r] = mrun[r]; lS[s][quad * 4 + r] = lrun[r]; }
        #pragma unroll
        for (int dn = 0; dn < 4; dn++)
            OS[s][quad * 4 + r][dn * 16 + fr] = Oint[dn][r];
    }
    __syncthreads();

    // ---- merge splits + gated blend, write oh bf16 ----
    {
        const int q = tid >> 4;
        const int db = (tid & 15) * 4;
        float M = fmaxf(fmaxf(mS[0][q], mS[1][q]), fmaxf(mS[2][q], mS[3][q]));
        float L = 0.f;
        float o0 = 0.f, o1 = 0.f, o2 = 0.f, o3 = 0.f;
        #pragma unroll
        for (int ss = 0; ss < 4; ss++) {
            float p = __expf(mS[ss][q] - M);
            L += lS[ss][q] * p;
            o0 += OS[ss][q][db + 0] * p;
            o1 += OS[ss][q][db + 1] * p;
            o2 += OS[ss][q][db + 2] * p;
            o3 += OS[ss][q][db + 3] * p;
        }
        const float2 gt = sgate[q];
        const float wi = gt.x / L;
        const float wl = gt.y / liS[q];
        unsigned short out4[4];
        out4[0] = __builtin_bit_cast(unsigned short, __float2bfloat16(wi * o0 + wl * OIs[q][db + 0]));
        out4[1] = __builtin_bit_cast(unsigned short, __float2bfloat16(wi * o1 + wl * OIs[q][db + 1]));
        out4[2] = __builtin_bit_cast(unsigned short, __float2bfloat16(wi * o2 + wl * OIs[q][db + 2]));
        out4[3] = __builtin_bit_cast(unsigned short, __float2bfloat16(wi * o3 + wl * OIs[q][db + 3]));
        const int n = g * 64 + qt * 16 + q;
        *(uint2*)(oh + (size_t)n * DMODEL + h * HDIM + db) = *(uint2*)out4;
    }
}

// ---------------------------------------------------------------------------
// F: Wo GEMM: C = oh x (Woh + Wol)^T, 64x64 tile, BK=64, f32 store.
// 8 waves (512 thr); double-buffered counted-vmcnt pipeline (3 loads/wave).
// Scalar shared pointers only (pointer arrays into LDS fail to compile).
// ---------------------------------------------------------------------------
__global__ __launch_bounds__(512) void gemm_wo(
    const __hip_bfloat16* __restrict__ Ah,
    const __hip_bfloat16* __restrict__ Bh, const __hip_bfloat16* __restrict__ Bl,
    float* __restrict__ C)
{
    __shared__ alignas(16) char smem[49152];
    __hip_bfloat16* As0 = (__hip_bfloat16*)smem;
    __hip_bfloat16* Bh0 = (__hip_bfloat16*)(smem + 8192);
    __hip_bfloat16* Bl0 = (__hip_bfloat16*)(smem + 16384);
    __hip_bfloat16* As1 = (__hip_bfloat16*)(smem + 24576);
    __hip_bfloat16* Bh1 = (__hip_bfloat16*)(smem + 32768);
    __hip_bfloat16* Bl1 = (__hip_bfloat16*)(smem + 40960);

    const int n0 = blockIdx.x * 64;
    const int m0 = blockIdx.y * 64;

    const int tid  = threadIdx.x;
    const int wave = tid >> 6;          // 0..7
    const int lane = tid & 63;
    const int wm = (wave >> 1) * 16;    // {0,16,32,48}
    const int wn = (wave & 1) * 32;     // {0,32}
    const int fr = lane & 15;
    const int quad = lane >> 4;

    f32x4 acc[2] = {};

    stage64w8(Ah + (size_t)m0 * DMODEL, As0, wave, lane);
    stage64w8(Bh + (size_t)n0 * DMODEL, Bh0, wave, lane);
    stage64w8(Bl + (size_t)n0 * DMODEL, Bl0, wave, lane);
    asm volatile("s_waitcnt vmcnt(0)" ::: "memory");
    __builtin_amdgcn_sched_barrier(0);
    __builtin_amdgcn_s_barrier();

    for (int kt = 0; kt < 16; kt++) {
        const int cur = kt & 1;
        __hip_bfloat16* Ac  = cur ? As1 : As0;
        __hip_bfloat16* Bhc = cur ? Bh1 : Bh0;
        __hip_bfloat16* Blc = cur ? Bl1 : Bl0;
        if (kt < 15) {
            __hip_bfloat16* An  = cur ? As0 : As1;
            __hip_bfloat16* Bhn = cur ? Bh0 : Bh1;
            __hip_bfloat16* Bln = cur ? Bl0 : Bl1;
            stage64w8(Ah + (size_t)m0 * DMODEL + (kt + 1) * 64, An, wave, lane);
            stage64w8(Bh + (size_t)n0 * DMODEL + (kt + 1) * 64, Bhn, wave, lane);
            stage64w8(Bl + (size_t)n0 * DMODEL + (kt + 1) * 64, Bln, wave, lane);
            asm volatile("s_waitcnt vmcnt(3)" ::: "memory");
        } else {
            // tail: tile-15 loads may still be in flight — full drain
            asm volatile("s_waitcnt vmcnt(0)" ::: "memory");
        }
        __builtin_amdgcn_sched_barrier(0);
        __builtin_amdgcn_s_barrier();
        __builtin_amdgcn_sched_barrier(0);

        #pragma unroll
        for (int hk = 0; hk < 2; hk++) {
            const int ch = hk * 4 + quad;
            short8 a0  = ldsfrag(Ac, wm + fr, ch);
            short8 b0h = ldsfrag(Bhc, wn + fr, ch);
            short8 b1h = ldsfrag(Bhc, wn + 16 + fr, ch);
            short8 b0l = ldsfrag(Blc, wn + fr, ch);
            short8 b1l = ldsfrag(Blc, wn + 16 + fr, ch);
            acc[0] = __builtin_amdgcn_mfma_f32_16x16x32_bf16(a0, b0l, acc[0], 0, 0, 0);
            acc[1] = __builtin_amdgcn_mfma_f32_16x16x32_bf16(a0, b1l, acc[1], 0, 0, 0);
            acc[0] = __builtin_amdgcn_mfma_f32_16x16x32_bf16(a0, b0h, acc[0], 0, 0, 0);
            acc[1] = __builtin_amdgcn_mfma_f32_16x16x32_bf16(a0, b1h, acc[1], 0, 0, 0);
        }
        __builtin_amdgcn_sched_barrier(0);
        __builtin_amdgcn_s_barrier();
        __builtin_amdgcn_sched_barrier(0);
    }

    #pragma unroll
    for (int tn = 0; tn < 2; tn++)
    #pragma unroll
    for (int r = 0; r < 4; r++) {
        int row = m0 + wm + quad * 4 + r;
        int col = n0 + wn + tn * 16 + fr;
        C[(size_t)row * DMODEL + col] = acc[tn][r];
    }
}

// ---------------------------------------------------------------------------
extern "C" void kernel_launch(void* const* d_in, const int* in_sizes, int n_in,
                              void* d_out, int out_size, void* d_ws, size_t ws_size,
                              hipStream_t stream)
{
    const float* x  = (const float*)d_in[0];
    const float* Wq = (const float*)d_in[1];
    const float* Wk = (const float*)d_in[2];
    const float* Wv = (const float*)d_in[3];
    const float* Wg = (const float*)d_in[4];
    const float* Wo = (const float*)d_in[5];

    const size_t M1 = (size_t)NTOK * DMODEL;   // 1M elems

    // workspace layout (~24.7 MB)
    float* S       = (float*)d_ws;                    // 1 MB (scores [1024][256])
    float* xm      = S + (size_t)NTOK * 256;          // 64 KB
    float* kc      = xm + NBLK * DMODEL;              // 64 KB
    float2* gate   = (float2*)(kc + NBLK * DMODEL);   // 128 KB
    __hip_bfloat16* xh  = (__hip_bfloat16*)(gate + NTOK * NHEAD);   // 2 MB
    __hip_bfloat16* xl  = xh + M1;     // 2 MB
    __hip_bfloat16* Wqh = xl + M1;     // 2 MB
    __hip_bfloat16* Wkh = Wqh + M1;    // 2 MB
    __hip_bfloat16* Wvh = Wkh + M1;    // 2 MB
    __hip_bfloat16* Woh = Wvh + M1;    // 2 MB
    __hip_bfloat16* Wol = Woh + M1;    // 2 MB
    __hip_bfloat16* oh  = Wol + M1;    // 2 MB
    __hip_bfloat16* Uh  = oh + M1;     // 512 KB ([256][1024])
    __hip_bfloat16* Ul  = Uh + 256 * DMODEL;  // 512 KB
    __hip_bfloat16* Qb  = Ul + 256 * DMODEL;  // 2 MB  bf16 [n][D]
    __hip_bfloat16* Kb  = Qb + M1;            // 2 MB  bf16 [n][D]
    __hip_bfloat16* Vt  = Kb + M1;            // 2 MB  bf16 [f][n] (transposed)
    __hip_bfloat16* Wgh = Vt + M1;            // 64 KB ([32][1024])
    __hip_bfloat16* Wgl = Wgh + 32 * DMODEL;  // 64 KB

    prep_kernel<<<5216, 256, 0, stream>>>(
        x, Wq, Wk, Wv, Wo, Wg, xh, xl, Wqh, Wkh, Wvh, Woh, Wol, Wgh, Wgl, xm);

    kc_gemm_kernel<<<1024, 256, 0, stream>>>(xm, Wk, kc);
    u_kernel<<<128, 256, 0, stream>>>(kc, Wq, Uh, Ul);

    qkv_score_kernel<<<272, 256, 0, stream>>>(
        xh, xl, Wqh, Wkh, Wvh, Uh, Ul, Wgh, Wgl, Qb, Kb, Vt, S, gate);

    attn_mfma_kernel<<<NBLK * NHEAD * 4, 256, 0, stream>>>(Qb, Kb, Vt, S, gate, oh);

    dim3 gwo(16, 16);
    gemm_wo<<<gwo, 512, 0, stream>>>(oh, Woh, Wol, (float*)d_out);
}